// Round 1
// baseline (5856.940 us; speedup 1.0000x reference)
//
#include <hip/hip_runtime.h>

#define NV 50000
#define NE 800000
#define NB 8
#define NH 128
#define NLAT 64
#define NTD 16
#define NL 4

__device__ __forceinline__ float silu_f(float x){ return x / (1.0f + __expf(-x)); }

// ---------------- setup: time embedding + cond-proj constants ----------------
// h0[v] = zcp[batch[v]] + tconst  (z has only 8 rows; t_emb is node-constant)
__global__ void k_setup(const float* __restrict__ z, const float* __restrict__ t,
                        const float* __restrict__ te_w1, const float* __restrict__ te_b1,
                        const float* __restrict__ te_w2, const float* __restrict__ te_b2,
                        const float* __restrict__ cp_w, const float* __restrict__ cp_b,
                        float* __restrict__ tconst, float* __restrict__ zcp)
{
    __shared__ float hid[NTD];
    __shared__ float emb[NTD];
    int tid = threadIdx.x;
    float ts = t[0];
    if (tid < NTD) hid[tid] = silu_f(ts * te_w1[tid] + te_b1[tid]);
    __syncthreads();
    if (tid < NTD){
        float a = te_b2[tid];
        for (int j = 0; j < NTD; j++) a += hid[j] * te_w2[j*NTD + tid];
        emb[tid] = a;
    }
    __syncthreads();
    float tc = cp_b[tid];
    for (int j = 0; j < NTD; j++) tc += emb[j] * cp_w[(NLAT + j)*NH + tid];
    tconst[tid] = tc;
    for (int b = 0; b < NB; b++){
        float a = 0.f;
        for (int k = 0; k < NLAT; k++) a += z[b*NLAT + k] * cp_w[k*NH + tid];
        zcp[b*NH + tid] = a;
    }
}

// ---------------- h0 init ----------------
__global__ void k_init(const int* __restrict__ batch, const float* __restrict__ zcp,
                       const float* __restrict__ tconst, float* __restrict__ h)
{
    int idx = blockIdx.x*256 + threadIdx.x;   // exactly NV*NH = 6.4M
    int v = idx >> 7, d = idx & 127;
    h[idx] = zcp[batch[v]*NH + d] + tconst[d];
}

// ---------------- x_t ----------------
__global__ void k_xt(const float* __restrict__ pos0, const float* __restrict__ pos1,
                     const float* __restrict__ t, float* __restrict__ xt)
{
    int idx = blockIdx.x*256 + threadIdx.x;
    if (idx < NV*3){
        float ts = t[0];
        xt[idx] = (1.f - ts)*pos0[idx] + ts*pos1[idx];
    }
}

// ---------------- CSR build ----------------
__global__ void k_hist(const int* __restrict__ dst, int* __restrict__ cnt)
{
    int e = blockIdx.x*256 + threadIdx.x;
    if (e < NE) atomicAdd(&cnt[dst[e]], 1);
}

__global__ void k_scan(int* __restrict__ cursor)   // in: deg, out: exclusive prefix
{
    __shared__ int part[1024];
    int t = threadIdx.x;
    const int CH = 49;                              // 49*1024 >= NV
    int base = t*CH;
    int s = 0;
    for (int j = 0; j < CH; j++){ int idx = base + j; if (idx < NV) s += cursor[idx]; }
    part[t] = s;
    __syncthreads();
    for (int off = 1; off < 1024; off <<= 1){
        int a = part[t];
        int b = (t >= off) ? part[t - off] : 0;
        __syncthreads();
        part[t] = a + b;
        __syncthreads();
    }
    int run = (t == 0) ? 0 : part[t-1];
    for (int j = 0; j < CH; j++){
        int idx = base + j;
        if (idx < NV){ int d = cursor[idx]; cursor[idx] = run; run += d; }
    }
}

__global__ void k_scatter(const int* __restrict__ dst, int* __restrict__ cursor,
                          int* __restrict__ csr_eid, int* __restrict__ csr_dst)
{
    int e = blockIdx.x*256 + threadIdx.x;
    if (e < NE){
        int i = dst[e];
        int p = atomicAdd(&cursor[i], 1);
        csr_eid[p] = e;
        csr_dst[p] = i;
    }
}

// ---------------- pre-projection: pre_d = h@W1[0:128], pre_s = h@W1[128:256] ----------------
__global__ __launch_bounds__(256) void k_pre(const float* __restrict__ h,
                                             const float* __restrict__ w_d,
                                             const float* __restrict__ w_s,
                                             float* __restrict__ pre_d,
                                             float* __restrict__ pre_s)
{
    __shared__ __align__(16) float a_t[128*68];
    int tid = threadIdx.x;
    // stage A transposed: a_t[k][row]
    {
        int r = tid >> 2, dq = tid & 3;
        int node = blockIdx.x*64 + r;
        bool valid = node < NV;
        const float* hrow = h + (size_t)node*NH + dq*4;
        #pragma unroll
        for (int i = 0; i < 8; i++){
            int d = i*16 + dq*4;
            float4 v = valid ? *(const float4*)(hrow + i*16) : make_float4(0.f,0.f,0.f,0.f);
            a_t[(d+0)*68 + r] = v.x;
            a_t[(d+1)*68 + r] = v.y;
            a_t[(d+2)*68 + r] = v.z;
            a_t[(d+3)*68 + r] = v.w;
        }
    }
    __syncthreads();
    const float* w = blockIdx.y ? w_s : w_d;
    float* out = blockIdx.y ? pre_s : pre_d;
    int tc = tid & 15, tr = tid >> 4;      // d0 = tc*8, e0 = tr*4
    float acc[4][8];
    #pragma unroll
    for (int i = 0; i < 4; i++)
        #pragma unroll
        for (int j = 0; j < 8; j++) acc[i][j] = 0.f;
    const float* wb = w + tc*8;
    for (int k = 0; k < 128; k++){
        float4 a4 = *(const float4*)&a_t[k*68 + tr*4];
        float4 w0 = *(const float4*)(wb + k*128);
        float4 w1 = *(const float4*)(wb + k*128 + 4);
        float av[4] = {a4.x, a4.y, a4.z, a4.w};
        float wv[8] = {w0.x, w0.y, w0.z, w0.w, w1.x, w1.y, w1.z, w1.w};
        #pragma unroll
        for (int i = 0; i < 4; i++)
            #pragma unroll
            for (int j = 0; j < 8; j++) acc[i][j] += av[i]*wv[j];
    }
    #pragma unroll
    for (int i = 0; i < 4; i++){
        int node = blockIdx.x*64 + tr*4 + i;
        if (node < NV){
            float4 o0 = make_float4(acc[i][0], acc[i][1], acc[i][2], acc[i][3]);
            float4 o1 = make_float4(acc[i][4], acc[i][5], acc[i][6], acc[i][7]);
            *(float4*)(out + (size_t)node*NH + tc*8)     = o0;
            *(float4*)(out + (size_t)node*NH + tc*8 + 4) = o1;
        }
    }
}

// ---------------- edge kernel: hid = silu(pre_d[i]+pre_s[j]+dx*W1c+b1); m = silu(hid@W2+b2); agg += m ----------------
__global__ __launch_bounds__(256) void k_edge(
    const float* __restrict__ pre_d, const float* __restrict__ pre_s,
    const float* __restrict__ xt,
    const int* __restrict__ csr_eid, const int* __restrict__ csr_dst,
    const int* __restrict__ srcrow,
    const float* __restrict__ w1c,    // 3x128 (rows 256..258 of ew1[l])
    const float* __restrict__ b1,
    const float* __restrict__ w2,     // 128x128
    const float* __restrict__ b2,
    float* __restrict__ agg)
{
    __shared__ __align__(16) float hid_t[128*68];
    __shared__ int nid[64];
    int tid = threadIdx.x;
    int p0 = blockIdx.x * 64;                       // NE % 64 == 0
    {
        int e = tid >> 2, dq = tid & 3;
        int p = p0 + e;
        int eid   = csr_eid[p];
        int inode = csr_dst[p];
        int j     = srcrow[eid];
        if (dq == 0) nid[e] = inode;
        float dx0 = xt[inode*3+0] - xt[j*3+0];
        float dx1 = xt[inode*3+1] - xt[j*3+1];
        float dx2 = xt[inode*3+2] - xt[j*3+2];
        const float* pd = pre_d + (size_t)inode*NH + dq*4;
        const float* ps = pre_s + (size_t)j*NH + dq*4;
        #pragma unroll
        for (int i = 0; i < 8; i++){
            int d = i*16 + dq*4;
            float4 a  = *(const float4*)(pd + i*16);
            float4 b  = *(const float4*)(ps + i*16);
            float4 c0 = *(const float4*)(w1c + d);
            float4 c1 = *(const float4*)(w1c + 128 + d);
            float4 c2 = *(const float4*)(w1c + 256 + d);
            float4 bv = *(const float4*)(b1 + d);
            float h0 = silu_f(a.x + b.x + bv.x + dx0*c0.x + dx1*c1.x + dx2*c2.x);
            float h1 = silu_f(a.y + b.y + bv.y + dx0*c0.y + dx1*c1.y + dx2*c2.y);
            float h2 = silu_f(a.z + b.z + bv.z + dx0*c0.z + dx1*c1.z + dx2*c2.z);
            float h3 = silu_f(a.w + b.w + bv.w + dx0*c0.w + dx1*c1.w + dx2*c2.w);
            hid_t[(d+0)*68 + e] = h0;
            hid_t[(d+1)*68 + e] = h1;
            hid_t[(d+2)*68 + e] = h2;
            hid_t[(d+3)*68 + e] = h3;
        }
    }
    __syncthreads();
    int tc = tid & 15, tr = tid >> 4;     // d0 = tc*8, edges tr*4..tr*4+3
    float acc[4][8];
    #pragma unroll
    for (int i = 0; i < 4; i++)
        #pragma unroll
        for (int j = 0; j < 8; j++) acc[i][j] = 0.f;
    const float* wb = w2 + tc*8;
    for (int k = 0; k < 128; k++){
        float4 a4 = *(const float4*)&hid_t[k*68 + tr*4];
        float4 w0 = *(const float4*)(wb + k*128);
        float4 w1 = *(const float4*)(wb + k*128 + 4);
        float av[4] = {a4.x, a4.y, a4.z, a4.w};
        float wv[8] = {w0.x, w0.y, w0.z, w0.w, w1.x, w1.y, w1.z, w1.w};
        #pragma unroll
        for (int i = 0; i < 4; i++)
            #pragma unroll
            for (int j = 0; j < 8; j++) acc[i][j] += av[i]*wv[j];
    }
    float4 b20 = *(const float4*)(b2 + tc*8);
    float4 b21 = *(const float4*)(b2 + tc*8 + 4);
    float bs[8] = {b20.x, b20.y, b20.z, b20.w, b21.x, b21.y, b21.z, b21.w};
    // run-length merged atomic scatter (edges are dst-sorted)
    float run[8];
    int curn = nid[tr*4];
    #pragma unroll
    for (int j = 0; j < 8; j++) run[j] = silu_f(acc[0][j] + bs[j]);
    #pragma unroll
    for (int i = 1; i < 4; i++){
        int n = nid[tr*4 + i];
        if (n == curn){
            #pragma unroll
            for (int j = 0; j < 8; j++) run[j] += silu_f(acc[i][j] + bs[j]);
        } else {
            float* ag = agg + (size_t)curn*NH + tc*8;
            #pragma unroll
            for (int j = 0; j < 8; j++) atomicAdd(&ag[j], run[j]);
            curn = n;
            #pragma unroll
            for (int j = 0; j < 8; j++) run[j] = silu_f(acc[i][j] + bs[j]);
        }
    }
    float* ag = agg + (size_t)curn*NH + tc*8;
    #pragma unroll
    for (int j = 0; j < 8; j++) atomicAdd(&ag[j], run[j]);
}

// ---------------- node kernel: h = LN(h + MLP([h|agg])) * g + b ----------------
__global__ __launch_bounds__(256) void k_node(
    const float* __restrict__ h, const float* __restrict__ agg,
    const float* __restrict__ w1, const float* __restrict__ b1,   // 256x128
    const float* __restrict__ w2, const float* __restrict__ b2,   // 128x128
    const float* __restrict__ g, const float* __restrict__ bta,
    float* __restrict__ hout)
{
    __shared__ __align__(16) float h_t [128*36];
    __shared__ __align__(16) float x_t2[128*36];   // agg first, then x
    __shared__ __align__(16) float t1_t[128*36];
    __shared__ float mu_s[32], rs_s[32];
    int tid = threadIdx.x;
    int tile0 = blockIdx.x*32;
    {
        int r = tid >> 3, dq = tid & 7;            // r: node 0..31, dims dq*4 + i*32
        int node = tile0 + r;
        bool valid = node < NV;
        const float* hr = h   + (size_t)node*NH + dq*4;
        const float* ar = agg + (size_t)node*NH + dq*4;
        #pragma unroll
        for (int i = 0; i < 4; i++){
            int d = i*32 + dq*4;
            float4 v = valid ? *(const float4*)(hr + i*32) : make_float4(0.f,0.f,0.f,0.f);
            float4 a = valid ? *(const float4*)(ar + i*32) : make_float4(0.f,0.f,0.f,0.f);
            h_t [(d+0)*36 + r] = v.x; h_t [(d+1)*36 + r] = v.y;
            h_t [(d+2)*36 + r] = v.z; h_t [(d+3)*36 + r] = v.w;
            x_t2[(d+0)*36 + r] = a.x; x_t2[(d+1)*36 + r] = a.y;
            x_t2[(d+2)*36 + r] = a.z; x_t2[(d+3)*36 + r] = a.w;
        }
    }
    __syncthreads();
    int tc = tid & 31, tr = tid >> 5;   // d0 = tc*4, n0 = tr*4
    int d0 = tc*4, n0 = tr*4;
    float acc[4][4];
    #pragma unroll
    for (int i = 0; i < 4; i++)
        #pragma unroll
        for (int j = 0; j < 4; j++) acc[i][j] = 0.f;
    for (int k = 0; k < 128; k++){
        float4 a4 = *(const float4*)&h_t[k*36 + n0];
        float4 w4 = *(const float4*)(w1 + k*128 + d0);
        float av[4] = {a4.x,a4.y,a4.z,a4.w};
        float wv[4] = {w4.x,w4.y,w4.z,w4.w};
        #pragma unroll
        for (int i = 0; i < 4; i++)
            #pragma unroll
            for (int j = 0; j < 4; j++) acc[i][j] += av[i]*wv[j];
    }
    for (int k = 0; k < 128; k++){
        float4 a4 = *(const float4*)&x_t2[k*36 + n0];
        float4 w4 = *(const float4*)(w1 + (128+k)*128 + d0);
        float av[4] = {a4.x,a4.y,a4.z,a4.w};
        float wv[4] = {w4.x,w4.y,w4.z,w4.w};
        #pragma unroll
        for (int i = 0; i < 4; i++)
            #pragma unroll
            for (int j = 0; j < 4; j++) acc[i][j] += av[i]*wv[j];
    }
    float4 b14 = *(const float4*)(b1 + d0);
    float bv1[4] = {b14.x, b14.y, b14.z, b14.w};
    #pragma unroll
    for (int i = 0; i < 4; i++)
        #pragma unroll
        for (int j = 0; j < 4; j++)
            t1_t[(d0+j)*36 + (n0+i)] = silu_f(acc[i][j] + bv1[j]);
    __syncthreads();
    float acc2[4][4];
    #pragma unroll
    for (int i = 0; i < 4; i++)
        #pragma unroll
        for (int j = 0; j < 4; j++) acc2[i][j] = 0.f;
    for (int k = 0; k < 128; k++){
        float4 a4 = *(const float4*)&t1_t[k*36 + n0];
        float4 w4 = *(const float4*)(w2 + k*128 + d0);
        float av[4] = {a4.x,a4.y,a4.z,a4.w};
        float wv[4] = {w4.x,w4.y,w4.z,w4.w};
        #pragma unroll
        for (int i = 0; i < 4; i++)
            #pragma unroll
            for (int j = 0; j < 4; j++) acc2[i][j] += av[i]*wv[j];
    }
    float4 b24 = *(const float4*)(b2 + d0);
    float bv2[4] = {b24.x, b24.y, b24.z, b24.w};
    #pragma unroll
    for (int i = 0; i < 4; i++)
        #pragma unroll
        for (int j = 0; j < 4; j++)
            x_t2[(d0+j)*36 + (n0+i)] = h_t[(d0+j)*36 + (n0+i)] + acc2[i][j] + bv2[j];
    __syncthreads();
    if (tid < 32){
        float s = 0.f, sq = 0.f;
        for (int d = 0; d < 128; d++){
            float x = x_t2[d*36 + tid];
            s += x; sq += x*x;
        }
        float mu = s * (1.f/128.f);
        float var = sq * (1.f/128.f) - mu*mu;
        mu_s[tid] = mu;
        rs_s[tid] = rsqrtf(var + 1e-5f);
    }
    __syncthreads();
    #pragma unroll
    for (int i = 0; i < 4; i++){
        int node = tile0 + n0 + i;
        if (node < NV){
            float mu = mu_s[n0+i], rs = rs_s[n0+i];
            float4 o;
            o.x = g[d0+0]*(x_t2[(d0+0)*36 + n0+i] - mu)*rs + bta[d0+0];
            o.y = g[d0+1]*(x_t2[(d0+1)*36 + n0+i] - mu)*rs + bta[d0+1];
            o.z = g[d0+2]*(x_t2[(d0+2)*36 + n0+i] - mu)*rs + bta[d0+2];
            o.w = g[d0+3]*(x_t2[(d0+3)*36 + n0+i] - mu)*rs + bta[d0+3];
            *(float4*)(hout + (size_t)node*NH + d0) = o;
        }
    }
}

// ---------------- output projection + MSE ----------------
__global__ __launch_bounds__(256) void k_out(const float* __restrict__ h,
                                             const float* __restrict__ opw, const float* __restrict__ opb,
                                             const float* __restrict__ pos0, const float* __restrict__ pos1,
                                             float* __restrict__ out)
{
    int v = blockIdx.x*256 + threadIdx.x;
    float sse = 0.f;
    if (v < NV){
        float v0 = opb[0], v1 = opb[1], v2 = opb[2];
        const float* hr = h + (size_t)v*NH;
        for (int k = 0; k < 128; k += 4){
            float4 hv = *(const float4*)(hr + k);
            v0 += hv.x*opw[(k+0)*3+0] + hv.y*opw[(k+1)*3+0] + hv.z*opw[(k+2)*3+0] + hv.w*opw[(k+3)*3+0];
            v1 += hv.x*opw[(k+0)*3+1] + hv.y*opw[(k+1)*3+1] + hv.z*opw[(k+2)*3+1] + hv.w*opw[(k+3)*3+1];
            v2 += hv.x*opw[(k+0)*3+2] + hv.y*opw[(k+1)*3+2] + hv.z*opw[(k+2)*3+2] + hv.w*opw[(k+3)*3+2];
        }
        float d0 = v0 - (pos1[v*3+0] - pos0[v*3+0]);
        float d1 = v1 - (pos1[v*3+1] - pos0[v*3+1]);
        float d2 = v2 - (pos1[v*3+2] - pos0[v*3+2]);
        sse = d0*d0 + d1*d1 + d2*d2;
    }
    for (int off = 32; off > 0; off >>= 1) sse += __shfl_down(sse, off, 64);
    __shared__ float red[4];
    if ((threadIdx.x & 63) == 0) red[threadIdx.x >> 6] = sse;
    __syncthreads();
    if (threadIdx.x == 0){
        float tot = red[0] + red[1] + red[2] + red[3];
        atomicAdd(out, tot * (1.0f/150000.0f));
    }
}

extern "C" void kernel_launch(void* const* d_in, const int* in_sizes, int n_in,
                              void* d_out, int out_size, void* d_ws, size_t ws_size,
                              hipStream_t stream)
{
    const float* pos0  = (const float*)d_in[0];
    const float* pos1  = (const float*)d_in[1];
    const float* z     = (const float*)d_in[2];
    const float* t     = (const float*)d_in[3];
    const int*   ei    = (const int*)d_in[4];
    const int*   batch = (const int*)d_in[5];
    const float* te_w1 = (const float*)d_in[6];
    const float* te_b1 = (const float*)d_in[7];
    const float* te_w2 = (const float*)d_in[8];
    const float* te_b2 = (const float*)d_in[9];
    const float* cp_w  = (const float*)d_in[10];
    const float* cp_b  = (const float*)d_in[11];
    const float* ew1   = (const float*)d_in[12];
    const float* eb1   = (const float*)d_in[13];
    const float* ew2   = (const float*)d_in[14];
    const float* eb2   = (const float*)d_in[15];
    const float* nw1   = (const float*)d_in[16];
    const float* nb1   = (const float*)d_in[17];
    const float* nw2   = (const float*)d_in[18];
    const float* nb2   = (const float*)d_in[19];
    const float* ln_g  = (const float*)d_in[20];
    const float* ln_b  = (const float*)d_in[21];
    const float* op_w  = (const float*)d_in[22];
    const float* op_b  = (const float*)d_in[23];

    float* ws     = (float*)d_ws;
    float* tconst = ws;                       // 128
    float* zcp    = ws + 128;                 // 1024
    float* xt     = ws + 1152;                // 150016
    float* h      = ws + 151168;              // 6.4M
    float* pre_d  = h     + (size_t)NV*NH;
    float* pre_s  = pre_d + (size_t)NV*NH;
    float* agg    = pre_s + (size_t)NV*NH;
    int*   ibase  = (int*)(agg + (size_t)NV*NH);
    int*   cursor  = ibase;                   // NV (deg -> rowptr -> cursor)
    int*   csr_eid = ibase + 50016;
    int*   csr_dst = csr_eid + NE;

    const int* srcrow = ei;        // edge_index[0] = src j
    const int* dstrow = ei + NE;   // edge_index[1] = dst i

    hipMemsetAsync(cursor, 0, (size_t)NV*4, stream);
    k_setup<<<1, 128, 0, stream>>>(z, t, te_w1, te_b1, te_w2, te_b2, cp_w, cp_b, tconst, zcp);
    k_init<<<(NV*NH)/256, 256, 0, stream>>>(batch, zcp, tconst, h);
    k_xt<<<(NV*3 + 255)/256, 256, 0, stream>>>(pos0, pos1, t, xt);
    k_hist<<<NE/256, 256, 0, stream>>>(dstrow, cursor);
    k_scan<<<1, 1024, 0, stream>>>(cursor);
    k_scatter<<<NE/256, 256, 0, stream>>>(dstrow, cursor, csr_eid, csr_dst);

    for (int l = 0; l < NL; l++){
        const float* ew1l = ew1 + (size_t)l*259*128;
        const float* ew2l = ew2 + (size_t)l*128*128;
        k_pre<<<dim3((NV + 63)/64, 2), 256, 0, stream>>>(h, ew1l, ew1l + 128*128, pre_d, pre_s);
        hipMemsetAsync(agg, 0, (size_t)NV*NH*4, stream);
        k_edge<<<NE/64, 256, 0, stream>>>(pre_d, pre_s, xt, csr_eid, csr_dst, srcrow,
                                          ew1l + 256*128, eb1 + l*128, ew2l, eb2 + l*128, agg);
        k_node<<<(NV + 31)/32, 256, 0, stream>>>(h, agg,
                                                 nw1 + (size_t)l*256*128, nb1 + l*128,
                                                 nw2 + (size_t)l*128*128, nb2 + l*128,
                                                 ln_g + l*128, ln_b + l*128, h);
    }

    hipMemsetAsync(d_out, 0, 4, stream);
    k_out<<<(NV + 255)/256, 256, 0, stream>>>(h, op_w, op_b, pos0, pos1, (float*)d_out);
}

// Round 3
// 2435.527 us; speedup vs baseline: 2.4048x; 2.4048x over previous
//
#include <hip/hip_runtime.h>

#define NV 50000
#define NE 800000
#define NB 8
#define NH 128
#define NLAT 64
#define NTD 16
#define NL 4
#define SK 136   // LDS row stride (bf16 elems) for MFMA tiles

typedef __attribute__((ext_vector_type(8))) short short8;
typedef __attribute__((ext_vector_type(4))) float f32x4;

__device__ __forceinline__ float silu_f(float x){ return x / (1.0f + __expf(-x)); }

__device__ __forceinline__ unsigned short f2bf(float x){
    unsigned u = __float_as_uint(x);
    unsigned r = (u >> 16) & 1;
    u += 0x7fffu + r;
    return (unsigned short)(u >> 16);
}
__device__ __forceinline__ unsigned f2bf_pk(float a, float b){
    return (unsigned)f2bf(a) | ((unsigned)f2bf(b) << 16);
}

// ---------------- setup: time embedding + cond-proj constants ----------------
__global__ void k_setup(const float* __restrict__ z, const float* __restrict__ t,
                        const float* __restrict__ te_w1, const float* __restrict__ te_b1,
                        const float* __restrict__ te_w2, const float* __restrict__ te_b2,
                        const float* __restrict__ cp_w, const float* __restrict__ cp_b,
                        float* __restrict__ tconst, float* __restrict__ zcp)
{
    __shared__ float hid[NTD];
    __shared__ float emb[NTD];
    int tid = threadIdx.x;
    float ts = t[0];
    if (tid < NTD) hid[tid] = silu_f(ts * te_w1[tid] + te_b1[tid]);
    __syncthreads();
    if (tid < NTD){
        float a = te_b2[tid];
        for (int j = 0; j < NTD; j++) a += hid[j] * te_w2[j*NTD + tid];
        emb[tid] = a;
    }
    __syncthreads();
    float tc = cp_b[tid];
    for (int j = 0; j < NTD; j++) tc += emb[j] * cp_w[(NLAT + j)*NH + tid];
    tconst[tid] = tc;
    for (int b = 0; b < NB; b++){
        float a = 0.f;
        for (int k = 0; k < NLAT; k++) a += z[b*NLAT + k] * cp_w[k*NH + tid];
        zcp[b*NH + tid] = a;
    }
}

__global__ void k_init(const int* __restrict__ batch, const float* __restrict__ zcp,
                       const float* __restrict__ tconst, float* __restrict__ h)
{
    int idx = blockIdx.x*256 + threadIdx.x;
    int v = idx >> 7, d = idx & 127;
    h[idx] = zcp[batch[v]*NH + d] + tconst[d];
}

__global__ void k_xt(const float* __restrict__ pos0, const float* __restrict__ pos1,
                     const float* __restrict__ t, float* __restrict__ xt)
{
    int idx = blockIdx.x*256 + threadIdx.x;
    if (idx < NV*3){
        float ts = t[0];
        xt[idx] = (1.f - ts)*pos0[idx] + ts*pos1[idx];
    }
}

// ---------------- CSR build ----------------
__global__ void k_hist(const int* __restrict__ dst, int* __restrict__ cnt)
{
    int e = blockIdx.x*256 + threadIdx.x;
    if (e < NE) atomicAdd(&cnt[dst[e]], 1);
}

__global__ void k_scan(int* __restrict__ cursor, int* __restrict__ rowptr)
{
    __shared__ int part[1024];
    int t = threadIdx.x;
    const int CH = 49;
    int base = t*CH;
    int s = 0;
    for (int j = 0; j < CH; j++){ int idx = base + j; if (idx < NV) s += cursor[idx]; }
    part[t] = s;
    __syncthreads();
    for (int off = 1; off < 1024; off <<= 1){
        int a = part[t];
        int b = (t >= off) ? part[t - off] : 0;
        __syncthreads();
        part[t] = a + b;
        __syncthreads();
    }
    int run = (t == 0) ? 0 : part[t-1];
    for (int j = 0; j < CH; j++){
        int idx = base + j;
        if (idx < NV){
            int d = cursor[idx];
            cursor[idx] = run;
            rowptr[idx] = run;
            run += d;
        }
    }
    if (t == 1023) rowptr[NV] = NE;
}

__global__ void k_scatter(const int* __restrict__ dst, int* __restrict__ cursor,
                          int* __restrict__ csr_eid, int* __restrict__ csr_dst)
{
    int e = blockIdx.x*256 + threadIdx.x;
    if (e < NE){
        int i = dst[e];
        int p = atomicAdd(&cursor[i], 1);
        csr_eid[p] = e;
        csr_dst[p] = i;
    }
}

// ---------------- pack W2 -> bf16 transposed [l][n][k] ----------------
__global__ void k_pack_w2(const float* __restrict__ ew2, unsigned short* __restrict__ w2t)
{
    int idx = blockIdx.x*256 + threadIdx.x;        // 4*128*128 = 65536
    int l = idx >> 14, rem = idx & 16383;
    int n = rem >> 7, k = rem & 127;
    w2t[idx] = f2bf(ew2[l*16384 + k*128 + n]);
}

// ---------------- pre-projection: pre_d = h@W1[0:128], pre_s = h@W1[128:256] ----------------
__global__ __launch_bounds__(256) void k_pre(const float* __restrict__ h,
                                             const float* __restrict__ w_d,
                                             const float* __restrict__ w_s,
                                             float* __restrict__ pre_d,
                                             float* __restrict__ pre_s)
{
    __shared__ __align__(16) float a_t[128*68];
    int tid = threadIdx.x;
    {
        int r = tid >> 2, dq = tid & 3;
        int node = blockIdx.x*64 + r;
        bool valid = node < NV;
        const float* hrow = h + (size_t)node*NH + dq*4;
        #pragma unroll
        for (int i = 0; i < 8; i++){
            int d = i*16 + dq*4;
            float4 v = valid ? *(const float4*)(hrow + i*16) : make_float4(0.f,0.f,0.f,0.f);
            a_t[(d+0)*68 + r] = v.x;
            a_t[(d+1)*68 + r] = v.y;
            a_t[(d+2)*68 + r] = v.z;
            a_t[(d+3)*68 + r] = v.w;
        }
    }
    __syncthreads();
    const float* w = blockIdx.y ? w_s : w_d;
    float* out = blockIdx.y ? pre_s : pre_d;
    int tc = tid & 15, tr = tid >> 4;
    float acc[4][8];
    #pragma unroll
    for (int i = 0; i < 4; i++)
        #pragma unroll
        for (int j = 0; j < 8; j++) acc[i][j] = 0.f;
    const float* wb = w + tc*8;
    for (int k = 0; k < 128; k++){
        float4 a4 = *(const float4*)&a_t[k*68 + tr*4];
        float4 w0 = *(const float4*)(wb + k*128);
        float4 w1 = *(const float4*)(wb + k*128 + 4);
        float av[4] = {a4.x, a4.y, a4.z, a4.w};
        float wv[8] = {w0.x, w0.y, w0.z, w0.w, w1.x, w1.y, w1.z, w1.w};
        #pragma unroll
        for (int i = 0; i < 4; i++)
            #pragma unroll
            for (int j = 0; j < 8; j++) acc[i][j] += av[i]*wv[j];
    }
    #pragma unroll
    for (int i = 0; i < 4; i++){
        int node = blockIdx.x*64 + tr*4 + i;
        if (node < NV){
            float4 o0 = make_float4(acc[i][0], acc[i][1], acc[i][2], acc[i][3]);
            float4 o1 = make_float4(acc[i][4], acc[i][5], acc[i][6], acc[i][7]);
            *(float4*)(out + (size_t)node*NH + tc*8)     = o0;
            *(float4*)(out + (size_t)node*NH + tc*8 + 4) = o1;
        }
    }
}

// ---------------- fused edge kernel (MFMA) + in-block segmented aggregation ----------------
// hid = silu(pre_d[i]+pre_s[j]+dx*W1c+b1); m = silu(hid@W2+b2); agg[v] += sum over v's edges
__global__ __launch_bounds__(256) void k_edge_mfma(
    const float* __restrict__ pre_d, const float* __restrict__ pre_s,
    const float* __restrict__ xt,
    const int* __restrict__ csr_eid, const int* __restrict__ csr_dst,
    const int* __restrict__ srcrow, const int* __restrict__ rowptr,
    const float* __restrict__ w1c, const float* __restrict__ b1,
    const unsigned short* __restrict__ w2t, const float* __restrict__ b2,
    float* __restrict__ agg)
{
    __shared__ __align__(16) unsigned short hids[64*SK];   // 17.4 KB
    __shared__ __align__(16) unsigned short wts[128*SK];   // 34.8 KB, reused as fp32 m_lds
    __shared__ int nid[64];
    __shared__ int flagL, flagR;
    int tid = threadIdx.x;
    int p0 = blockIdx.x * 64;                       // NE % 64 == 0

    // stage W2t (bf16 [n][k]) into LDS: 16384 shorts, 64 shorts (8x uint4) per thread
    {
        int r = tid >> 1, hf = tid & 1;
        const uint4* s4 = (const uint4*)(w2t + r*128 + hf*64);
        uint4* d4 = (uint4*)&wts[r*SK + hf*64];
        #pragma unroll
        for (int j = 0; j < 8; j++) d4[j] = s4[j];
    }
    // hid phase: 4 threads per edge, 32 dims each
    {
        int el = tid >> 2, q = tid & 3;
        int p = p0 + el;
        int eid = csr_eid[p];
        int iN  = csr_dst[p];
        int jN  = srcrow[eid];
        if (q == 0) nid[el] = iN;
        float dx0 = xt[iN*3+0] - xt[jN*3+0];
        float dx1 = xt[iN*3+1] - xt[jN*3+1];
        float dx2 = xt[iN*3+2] - xt[jN*3+2];
        const float* pd = pre_d + (size_t)iN*NH + q*32;
        const float* ps = pre_s + (size_t)jN*NH + q*32;
        #pragma unroll
        for (int i2 = 0; i2 < 8; i2++){
            int d = q*32 + i2*4;
            float4 a  = *(const float4*)(pd + i2*4);
            float4 b  = *(const float4*)(ps + i2*4);
            float4 c0 = *(const float4*)(w1c + d);
            float4 c1 = *(const float4*)(w1c + 128 + d);
            float4 c2 = *(const float4*)(w1c + 256 + d);
            float4 bb = *(const float4*)(b1 + d);
            float h0 = silu_f(a.x + b.x + bb.x + dx0*c0.x + dx1*c1.x + dx2*c2.x);
            float h1 = silu_f(a.y + b.y + bb.y + dx0*c0.y + dx1*c1.y + dx2*c2.y);
            float h2 = silu_f(a.z + b.z + bb.z + dx0*c0.z + dx1*c1.z + dx2*c2.z);
            float h3 = silu_f(a.w + b.w + bb.w + dx0*c0.w + dx1*c1.w + dx2*c2.w);
            uint2 pk;
            pk.x = f2bf_pk(h0, h1);
            pk.y = f2bf_pk(h2, h3);
            *(uint2*)&hids[el*SK + d] = pk;
        }
    }
    __syncthreads();
    if (tid == 0){
        flagL = (rowptr[nid[0]] < p0) ? 1 : 0;
        flagR = (rowptr[nid[63] + 1] > p0 + 64) ? 1 : 0;
    }

    // GEMM: wave w owns edge rows [w*16, w*16+16), all 128 out dims, K=128
    int w = tid >> 6, l = tid & 63;
    int lr = l & 15, lq = l >> 4;
    f32x4 acc[8];
    #pragma unroll
    for (int nt = 0; nt < 8; nt++) acc[nt] = (f32x4){0.f, 0.f, 0.f, 0.f};
    #pragma unroll
    for (int kc = 0; kc < 4; kc++){
        short8 af = *(const short8*)&hids[(w*16 + lr)*SK + kc*32 + lq*8];
        #pragma unroll
        for (int nt = 0; nt < 8; nt++){
            short8 bf = *(const short8*)&wts[(nt*16 + lr)*SK + kc*32 + lq*8];
            acc[nt] = __builtin_amdgcn_mfma_f32_16x16x32_bf16(af, bf, acc[nt], 0, 0, 0);
        }
    }
    __syncthreads();   // all waves done reading wts -> safe to overwrite with m_lds

    // epilogue: m = silu(acc + b2) -> m_lds (fp32, stride 132, in wts space)
    float* m_lds = (float*)wts;   // 64*132*4 = 33792 B <= 34816 B
    #pragma unroll
    for (int nt = 0; nt < 8; nt++){
        int col = nt*16 + lr;
        float bv = b2[col];
        #pragma unroll
        for (int r = 0; r < 4; r++){
            int row = w*16 + lq*4 + r;
            m_lds[row*132 + col] = silu_f(acc[nt][r] + bv);
        }
    }
    __syncthreads();

    // segmented row-sum: 128 threads, one dim each; runs of equal dst node.
    // interior runs -> direct store; boundary runs (continue outside block) -> atomicAdd
    if (tid < 128){
        int d = tid;
        float run = m_lds[0*132 + d];
        int curn = nid[0];
        int runStart = 0;
        for (int row = 1; row < 64; row++){
            int n = nid[row];
            float v = m_lds[row*132 + d];
            if (n == curn){
                run += v;
            } else {
                if (runStart == 0 && flagL) atomicAdd(&agg[(size_t)curn*NH + d], run);
                else                        agg[(size_t)curn*NH + d] = run;
                curn = n; run = v; runStart = row;
            }
        }
        if ((runStart == 0 && flagL) || flagR) atomicAdd(&agg[(size_t)curn*NH + d], run);
        else                                   agg[(size_t)curn*NH + d] = run;
    }
}

// ---------------- node kernel: h = LN(h + MLP([h|agg])) * g + b ----------------
__global__ __launch_bounds__(256) void k_node(
    const float* __restrict__ h, const float* __restrict__ agg,
    const float* __restrict__ w1, const float* __restrict__ b1,
    const float* __restrict__ w2, const float* __restrict__ b2,
    const float* __restrict__ g, const float* __restrict__ bta,
    float* __restrict__ hout)
{
    __shared__ __align__(16) float h_t [128*36];
    __shared__ __align__(16) float x_t2[128*36];
    __shared__ __align__(16) float t1_t[128*36];
    __shared__ float mu_s[32], rs_s[32];
    int tid = threadIdx.x;
    int tile0 = blockIdx.x*32;
    {
        int r = tid >> 3, dq = tid & 7;
        int node = tile0 + r;
        bool valid = node < NV;
        const float* hr = h   + (size_t)node*NH + dq*4;
        const float* ar = agg + (size_t)node*NH + dq*4;
        #pragma unroll
        for (int i = 0; i < 4; i++){
            int d = i*32 + dq*4;
            float4 v = valid ? *(const float4*)(hr + i*32) : make_float4(0.f,0.f,0.f,0.f);
            float4 a = valid ? *(const float4*)(ar + i*32) : make_float4(0.f,0.f,0.f,0.f);
            h_t [(d+0)*36 + r] = v.x; h_t [(d+1)*36 + r] = v.y;
            h_t [(d+2)*36 + r] = v.z; h_t [(d+3)*36 + r] = v.w;
            x_t2[(d+0)*36 + r] = a.x; x_t2[(d+1)*36 + r] = a.y;
            x_t2[(d+2)*36 + r] = a.z; x_t2[(d+3)*36 + r] = a.w;
        }
    }
    __syncthreads();
    int tc = tid & 31, tr = tid >> 5;
    int d0 = tc*4, n0 = tr*4;
    float acc[4][4];
    #pragma unroll
    for (int i = 0; i < 4; i++)
        #pragma unroll
        for (int j = 0; j < 4; j++) acc[i][j] = 0.f;
    for (int k = 0; k < 128; k++){
        float4 a4 = *(const float4*)&h_t[k*36 + n0];
        float4 w4 = *(const float4*)(w1 + k*128 + d0);
        float av[4] = {a4.x,a4.y,a4.z,a4.w};
        float wv[4] = {w4.x,w4.y,w4.z,w4.w};
        #pragma unroll
        for (int i = 0; i < 4; i++)
            #pragma unroll
            for (int j = 0; j < 4; j++) acc[i][j] += av[i]*wv[j];
    }
    for (int k = 0; k < 128; k++){
        float4 a4 = *(const float4*)&x_t2[k*36 + n0];
        float4 w4 = *(const float4*)(w1 + (128+k)*128 + d0);
        float av[4] = {a4.x,a4.y,a4.z,a4.w};
        float wv[4] = {w4.x,w4.y,w4.z,w4.w};
        #pragma unroll
        for (int i = 0; i < 4; i++)
            #pragma unroll
            for (int j = 0; j < 4; j++) acc[i][j] += av[i]*wv[j];
    }
    float4 b14 = *(const float4*)(b1 + d0);
    float bv1[4] = {b14.x, b14.y, b14.z, b14.w};
    #pragma unroll
    for (int i = 0; i < 4; i++)
        #pragma unroll
        for (int j = 0; j < 4; j++)
            t1_t[(d0+j)*36 + (n0+i)] = silu_f(acc[i][j] + bv1[j]);
    __syncthreads();
    float acc2[4][4];
    #pragma unroll
    for (int i = 0; i < 4; i++)
        #pragma unroll
        for (int j = 0; j < 4; j++) acc2[i][j] = 0.f;
    for (int k = 0; k < 128; k++){
        float4 a4 = *(const float4*)&t1_t[k*36 + n0];
        float4 w4 = *(const float4*)(w2 + k*128 + d0);
        float av[4] = {a4.x,a4.y,a4.z,a4.w};
        float wv[4] = {w4.x,w4.y,w4.z,w4.w};
        #pragma unroll
        for (int i = 0; i < 4; i++)
            #pragma unroll
            for (int j = 0; j < 4; j++) acc2[i][j] += av[i]*wv[j];
    }
    float4 b24 = *(const float4*)(b2 + d0);
    float bv2[4] = {b24.x, b24.y, b24.z, b24.w};
    #pragma unroll
    for (int i = 0; i < 4; i++)
        #pragma unroll
        for (int j = 0; j < 4; j++)
            x_t2[(d0+j)*36 + (n0+i)] = h_t[(d0+j)*36 + (n0+i)] + acc2[i][j] + bv2[j];
    __syncthreads();
    if (tid < 32){
        float s = 0.f, sq = 0.f;
        for (int d = 0; d < 128; d++){
            float x = x_t2[d*36 + tid];
            s += x; sq += x*x;
        }
        float mu = s * (1.f/128.f);
        float var = sq * (1.f/128.f) - mu*mu;
        mu_s[tid] = mu;
        rs_s[tid] = rsqrtf(var + 1e-5f);
    }
    __syncthreads();
    #pragma unroll
    for (int i = 0; i < 4; i++){
        int node = tile0 + n0 + i;
        if (node < NV){
            float mu = mu_s[n0+i], rs = rs_s[n0+i];
            float4 o;
            o.x = g[d0+0]*(x_t2[(d0+0)*36 + n0+i] - mu)*rs + bta[d0+0];
            o.y = g[d0+1]*(x_t2[(d0+1)*36 + n0+i] - mu)*rs + bta[d0+1];
            o.z = g[d0+2]*(x_t2[(d0+2)*36 + n0+i] - mu)*rs + bta[d0+2];
            o.w = g[d0+3]*(x_t2[(d0+3)*36 + n0+i] - mu)*rs + bta[d0+3];
            *(float4*)(hout + (size_t)node*NH + d0) = o;
        }
    }
}

// ---------------- output projection + MSE ----------------
__global__ __launch_bounds__(256) void k_out(const float* __restrict__ h,
                                             const float* __restrict__ opw, const float* __restrict__ opb,
                                             const float* __restrict__ pos0, const float* __restrict__ pos1,
                                             float* __restrict__ out)
{
    int v = blockIdx.x*256 + threadIdx.x;
    float sse = 0.f;
    if (v < NV){
        float v0 = opb[0], v1 = opb[1], v2 = opb[2];
        const float* hr = h + (size_t)v*NH;
        for (int k = 0; k < 128; k += 4){
            float4 hv = *(const float4*)(hr + k);
            v0 += hv.x*opw[(k+0)*3+0] + hv.y*opw[(k+1)*3+0] + hv.z*opw[(k+2)*3+0] + hv.w*opw[(k+3)*3+0];
            v1 += hv.x*opw[(k+0)*3+1] + hv.y*opw[(k+1)*3+1] + hv.z*opw[(k+2)*3+1] + hv.w*opw[(k+3)*3+1];
            v2 += hv.x*opw[(k+0)*3+2] + hv.y*opw[(k+1)*3+2] + hv.z*opw[(k+2)*3+2] + hv.w*opw[(k+3)*3+2];
        }
        float d0 = v0 - (pos1[v*3+0] - pos0[v*3+0]);
        float d1 = v1 - (pos1[v*3+1] - pos0[v*3+1]);
        float d2 = v2 - (pos1[v*3+2] - pos0[v*3+2]);
        sse = d0*d0 + d1*d1 + d2*d2;
    }
    for (int off = 32; off > 0; off >>= 1) sse += __shfl_down(sse, off, 64);
    __shared__ float red[4];
    if ((threadIdx.x & 63) == 0) red[threadIdx.x >> 6] = sse;
    __syncthreads();
    if (threadIdx.x == 0){
        float tot = red[0] + red[1] + red[2] + red[3];
        atomicAdd(out, tot * (1.0f/150000.0f));
    }
}

extern "C" void kernel_launch(void* const* d_in, const int* in_sizes, int n_in,
                              void* d_out, int out_size, void* d_ws, size_t ws_size,
                              hipStream_t stream)
{
    const float* pos0  = (const float*)d_in[0];
    const float* pos1  = (const float*)d_in[1];
    const float* z     = (const float*)d_in[2];
    const float* t     = (const float*)d_in[3];
    const int*   ei    = (const int*)d_in[4];
    const int*   batch = (const int*)d_in[5];
    const float* te_w1 = (const float*)d_in[6];
    const float* te_b1 = (const float*)d_in[7];
    const float* te_w2 = (const float*)d_in[8];
    const float* te_b2 = (const float*)d_in[9];
    const float* cp_w  = (const float*)d_in[10];
    const float* cp_b  = (const float*)d_in[11];
    const float* ew1   = (const float*)d_in[12];
    const float* eb1   = (const float*)d_in[13];
    const float* ew2   = (const float*)d_in[14];
    const float* eb2   = (const float*)d_in[15];
    const float* nw1   = (const float*)d_in[16];
    const float* nb1   = (const float*)d_in[17];
    const float* nw2   = (const float*)d_in[18];
    const float* nb2   = (const float*)d_in[19];
    const float* ln_g  = (const float*)d_in[20];
    const float* ln_b  = (const float*)d_in[21];
    const float* op_w  = (const float*)d_in[22];
    const float* op_b  = (const float*)d_in[23];

    float* ws     = (float*)d_ws;
    float* tconst = ws;                        // 128
    float* zcp    = ws + 128;                  // 1024
    float* xt     = ws + 1152;                 // 150016
    float* h      = ws + 151168;
    float* pre_d  = h     + (size_t)NV*NH;
    float* pre_s  = pre_d + (size_t)NV*NH;
    float* agg    = pre_s + (size_t)NV*NH;
    int*   ibase  = (int*)(agg + (size_t)NV*NH);
    int*   rowptr  = ibase;                    // NV+1 (padded to 50016)
    int*   cursor  = ibase + 50016;            // NV
    int*   csr_eid = ibase + 100032;           // NE
    int*   csr_dst = csr_eid + NE;             // NE
    unsigned short* w2t = (unsigned short*)(csr_dst + NE);   // 4*128*128 bf16

    const int* srcrow = ei;        // edge_index[0] = src j
    const int* dstrow = ei + NE;   // edge_index[1] = dst i

    hipMemsetAsync(cursor, 0, (size_t)NV*4, stream);
    k_setup<<<1, 128, 0, stream>>>(z, t, te_w1, te_b1, te_w2, te_b2, cp_w, cp_b, tconst, zcp);
    k_init<<<(NV*NH)/256, 256, 0, stream>>>(batch, zcp, tconst, h);
    k_xt<<<(NV*3 + 255)/256, 256, 0, stream>>>(pos0, pos1, t, xt);
    k_hist<<<NE/256, 256, 0, stream>>>(dstrow, cursor);
    k_scan<<<1, 1024, 0, stream>>>(cursor, rowptr);
    k_scatter<<<NE/256, 256, 0, stream>>>(dstrow, cursor, csr_eid, csr_dst);
    k_pack_w2<<<(4*128*128)/256, 256, 0, stream>>>(ew2, w2t);

    for (int l = 0; l < NL; l++){
        const float* ew1l = ew1 + (size_t)l*259*128;
        k_pre<<<dim3((NV + 63)/64, 2), 256, 0, stream>>>(h, ew1l, ew1l + 128*128, pre_d, pre_s);
        hipMemsetAsync(agg, 0, (size_t)NV*NH*4, stream);
        k_edge_mfma<<<NE/64, 256, 0, stream>>>(pre_d, pre_s, xt, csr_eid, csr_dst, srcrow, rowptr,
                                               ew1l + 256*128, eb1 + l*128,
                                               w2t + (size_t)l*16384, eb2 + l*128, agg);
        k_node<<<(NV + 31)/32, 256, 0, stream>>>(h, agg,
                                                 nw1 + (size_t)l*256*128, nb1 + l*128,
                                                 nw2 + (size_t)l*128*128, nb2 + l*128,
                                                 ln_g + l*128, ln_b + l*128, h);
    }

    hipMemsetAsync(d_out, 0, 4, stream);
    k_out<<<(NV + 255)/256, 256, 0, stream>>>(h, op_w, op_b, pos0, pos1, (float*)d_out);
}

// Round 4
// 1617.996 us; speedup vs baseline: 3.6199x; 1.5053x over previous
//
#include <hip/hip_runtime.h>

#define NV 50000
#define NE 800000
#define NB 8
#define NH 128
#define NLAT 64
#define NTD 16
#define NL 4
#define SK 136   // LDS row stride (bf16 elems) for MFMA A tiles
#define MS 132   // LDS row stride (bf16 elems) for m tile

typedef __attribute__((ext_vector_type(8))) short short8;
typedef __attribute__((ext_vector_type(4))) float f32x4;

__device__ __forceinline__ float silu_f(float x){ return x / (1.0f + __expf(-x)); }

__device__ __forceinline__ unsigned short f2bf(float x){
    unsigned u = __float_as_uint(x);
    unsigned r = (u >> 16) & 1;
    u += 0x7fffu + r;
    return (unsigned short)(u >> 16);
}
__device__ __forceinline__ unsigned f2bf_pk(float a, float b){
    return (unsigned)f2bf(a) | ((unsigned)f2bf(b) << 16);
}
__device__ __forceinline__ float bflo(unsigned u){ return __uint_as_float(u << 16); }
__device__ __forceinline__ float bfhi(unsigned u){ return __uint_as_float(u & 0xffff0000u); }
__device__ __forceinline__ float bfu(unsigned short s){ return __uint_as_float(((unsigned)s) << 16); }

// ---------------- setup: time embedding + cond-proj constants ----------------
__global__ void k_setup(const float* __restrict__ z, const float* __restrict__ t,
                        const float* __restrict__ te_w1, const float* __restrict__ te_b1,
                        const float* __restrict__ te_w2, const float* __restrict__ te_b2,
                        const float* __restrict__ cp_w, const float* __restrict__ cp_b,
                        float* __restrict__ tconst, float* __restrict__ zcp)
{
    __shared__ float hid[NTD];
    __shared__ float emb[NTD];
    int tid = threadIdx.x;
    float ts = t[0];
    if (tid < NTD) hid[tid] = silu_f(ts * te_w1[tid] + te_b1[tid]);
    __syncthreads();
    if (tid < NTD){
        float a = te_b2[tid];
        for (int j = 0; j < NTD; j++) a += hid[j] * te_w2[j*NTD + tid];
        emb[tid] = a;
    }
    __syncthreads();
    float tc = cp_b[tid];
    for (int j = 0; j < NTD; j++) tc += emb[j] * cp_w[(NLAT + j)*NH + tid];
    tconst[tid] = tc;
    for (int b = 0; b < NB; b++){
        float a = 0.f;
        for (int k = 0; k < NLAT; k++) a += z[b*NLAT + k] * cp_w[k*NH + tid];
        zcp[b*NH + tid] = a;
    }
}

__global__ void k_init(const int* __restrict__ batch, const float* __restrict__ zcp,
                       const float* __restrict__ tconst, float* __restrict__ h)
{
    int idx = blockIdx.x*256 + threadIdx.x;
    int v = idx >> 7, d = idx & 127;
    h[idx] = zcp[batch[v]*NH + d] + tconst[d];
}

__global__ void k_xt(const float* __restrict__ pos0, const float* __restrict__ pos1,
                     const float* __restrict__ t, float* __restrict__ xt)
{
    int idx = blockIdx.x*256 + threadIdx.x;
    if (idx < NV*3){
        float ts = t[0];
        xt[idx] = (1.f - ts)*pos0[idx] + ts*pos1[idx];
    }
}

// ---------------- CSR build ----------------
__global__ void k_hist(const int* __restrict__ dst, int* __restrict__ cnt)
{
    int e = blockIdx.x*256 + threadIdx.x;
    if (e < NE) atomicAdd(&cnt[dst[e]], 1);
}

__global__ void k_scan(int* __restrict__ cursor, int* __restrict__ rowptr)
{
    __shared__ int part[1024];
    int t = threadIdx.x;
    const int CH = 49;
    int base = t*CH;
    int s = 0;
    for (int j = 0; j < CH; j++){ int idx = base + j; if (idx < NV) s += cursor[idx]; }
    part[t] = s;
    __syncthreads();
    for (int off = 1; off < 1024; off <<= 1){
        int a = part[t];
        int b = (t >= off) ? part[t - off] : 0;
        __syncthreads();
        part[t] = a + b;
        __syncthreads();
    }
    int run = (t == 0) ? 0 : part[t-1];
    for (int j = 0; j < CH; j++){
        int idx = base + j;
        if (idx < NV){
            int d = cursor[idx];
            cursor[idx] = run;
            rowptr[idx] = run;
            run += d;
        }
    }
    if (t == 1023) rowptr[NV] = NE;
}

__global__ void k_scatter(const int* __restrict__ dst, int* __restrict__ cursor,
                          int* __restrict__ csr_eid, int* __restrict__ csr_dst)
{
    int e = blockIdx.x*256 + threadIdx.x;
    if (e < NE){
        int i = dst[e];
        int p = atomicAdd(&cursor[i], 1);
        csr_eid[p] = e;
        csr_dst[p] = i;
    }
}

// ---------------- pack edge weights -> bf16 [l][{Wd,Ws,W2}][n][k] ----------------
__global__ void k_pack_wpk(const float* __restrict__ ew1, const float* __restrict__ ew2,
                           unsigned short* __restrict__ wpk)
{
    int idx = blockIdx.x*256 + threadIdx.x;        // 4*3*16384 = 196608
    int lm = idx >> 14;        // 0..11
    int l = lm / 3, m = lm % 3;
    int r = idx & 16383;
    int n = r >> 7, k = r & 127;
    float v = (m < 2) ? ew1[l*33152 + (m*128 + k)*128 + n]
                      : ew2[l*16384 + k*128 + n];
    wpk[idx] = f2bf(v);
}

// ---------------- pre-projection (MFMA, bf16 out, dx-term + b1 folded) ----------------
// y==0: pre_di[v] = bf16( h[v]@Wd + xt[v]@W1c + b1 )
// y==1: pre_sj[v] = bf16( h[v]@Ws - xt[v]@W1c )
__global__ __launch_bounds__(256) void k_pre_mfma(
    const float* __restrict__ h, const float* __restrict__ xt,
    const unsigned short* __restrict__ wpk_l,   // layer base: Wd at +0, Ws at +16384
    const float* __restrict__ w1c, const float* __restrict__ b1,
    unsigned short* __restrict__ pre_di, unsigned short* __restrict__ pre_sj)
{
    __shared__ __align__(16) unsigned short asd[64*SK];
    __shared__ float xts[64*4];
    int tid = threadIdx.x;
    int tile0 = blockIdx.x*64;
    int branch = blockIdx.y;

    // stage A (h tile, fp32 -> bf16), 4 threads/row, 32 dims each
    {
        int r = tid >> 2, dq = tid & 3;
        int node = tile0 + r;
        bool valid = node < NV;
        const float4* hrow = (const float4*)(h + (size_t)node*NH + dq*32);
        #pragma unroll
        for (int c = 0; c < 4; c++){
            float4 v0 = valid ? hrow[c*2]     : make_float4(0.f,0.f,0.f,0.f);
            float4 v1 = valid ? hrow[c*2 + 1] : make_float4(0.f,0.f,0.f,0.f);
            uint4 o;
            o.x = f2bf_pk(v0.x, v0.y);
            o.y = f2bf_pk(v0.z, v0.w);
            o.z = f2bf_pk(v1.x, v1.y);
            o.w = f2bf_pk(v1.z, v1.w);
            *(uint4*)&asd[r*SK + dq*32 + c*8] = o;
        }
    }
    if (tid < 64){
        int node = tile0 + tid;
        bool valid = node < NV;
        xts[tid*4+0] = valid ? xt[node*3+0] : 0.f;
        xts[tid*4+1] = valid ? xt[node*3+1] : 0.f;
        xts[tid*4+2] = valid ? xt[node*3+2] : 0.f;
        xts[tid*4+3] = 0.f;
    }

    // persistent B fragments from global (per wave: 32 cols)
    int w = tid >> 6, l = tid & 63;
    int lr = l & 15, lq = l >> 4;
    const unsigned short* wb = wpk_l + branch*16384;
    short8 bfr[2][4];
    #pragma unroll
    for (int nt = 0; nt < 2; nt++)
        #pragma unroll
        for (int kc = 0; kc < 4; kc++)
            bfr[nt][kc] = *(const short8*)(wb + (w*32 + nt*16 + lr)*128 + kc*32 + lq*8);

    __syncthreads();

    f32x4 acc[4][2];
    #pragma unroll
    for (int mt = 0; mt < 4; mt++)
        #pragma unroll
        for (int nt = 0; nt < 2; nt++) acc[mt][nt] = (f32x4){0.f,0.f,0.f,0.f};
    #pragma unroll
    for (int kc = 0; kc < 4; kc++){
        #pragma unroll
        for (int mt = 0; mt < 4; mt++){
            short8 af = *(const short8*)&asd[(mt*16 + lr)*SK + kc*32 + lq*8];
            #pragma unroll
            for (int nt = 0; nt < 2; nt++)
                acc[mt][nt] = __builtin_amdgcn_mfma_f32_16x16x32_bf16(af, bfr[nt][kc], acc[mt][nt], 0, 0, 0);
        }
    }

    unsigned short* out = branch ? pre_sj : pre_di;
    #pragma unroll
    for (int nt = 0; nt < 2; nt++){
        int col = w*32 + nt*16 + lr;
        float c0 = w1c[col], c1 = w1c[128 + col], c2 = w1c[256 + col];
        float bb = branch ? 0.f : b1[col];
        #pragma unroll
        for (int mt = 0; mt < 4; mt++){
            #pragma unroll
            for (int r = 0; r < 4; r++){
                int row = mt*16 + lq*4 + r;
                int node = tile0 + row;
                if (node < NV){
                    float qv = xts[row*4+0]*c0 + xts[row*4+1]*c1 + xts[row*4+2]*c2;
                    float val = acc[mt][nt][r] + (branch ? -qv : qv + bb);
                    out[(size_t)node*NH + col] = f2bf(val);
                }
            }
        }
    }
}

// ---------------- fused edge kernel: hid = silu(pre_di[i]+pre_sj[j]); m = silu(hid@W2+b2); seg-sum -> agg ----------------
__global__ __launch_bounds__(256) void k_edge_mfma(
    const unsigned short* __restrict__ pre_di, const unsigned short* __restrict__ pre_sj,
    const int* __restrict__ csr_eid, const int* __restrict__ csr_dst,
    const int* __restrict__ srcrow, const int* __restrict__ rowptr,
    const unsigned short* __restrict__ w2t,   // [n][k] bf16
    const float* __restrict__ b2,
    float* __restrict__ agg)
{
    __shared__ __align__(16) unsigned short hids[64*SK];   // 17.4 KB; reused as bf16 m tile
    __shared__ int nid[64];
    __shared__ int flagL, flagR;
    int tid = threadIdx.x;
    int p0 = blockIdx.x * 64;                       // NE % 64 == 0

    if (tid == 0){
        int iN0  = csr_dst[p0];
        int iN63 = csr_dst[p0 + 63];
        flagL = (rowptr[iN0] < p0) ? 1 : 0;
        flagR = (rowptr[iN63 + 1] > p0 + 64) ? 1 : 0;
    }

    // hid phase: 4 threads/edge, 32 dims each: silu(pre_di[i] + pre_sj[j]) -> bf16 LDS
    {
        int el = tid >> 2, q = tid & 3;
        int p = p0 + el;
        int eid = csr_eid[p];
        int iN  = csr_dst[p];
        int jN  = srcrow[eid];
        if (q == 0) nid[el] = iN;
        const uint4* gd = (const uint4*)(pre_di + (size_t)iN*NH + q*32);
        const uint4* gs = (const uint4*)(pre_sj + (size_t)jN*NH + q*32);
        #pragma unroll
        for (int c = 0; c < 4; c++){
            uint4 a = gd[c], b = gs[c];
            unsigned au[4] = {a.x, a.y, a.z, a.w};
            unsigned bu[4] = {b.x, b.y, b.z, b.w};
            uint4 o;
            unsigned ov[4];
            #pragma unroll
            for (int g = 0; g < 4; g++){
                float lo = silu_f(bflo(au[g]) + bflo(bu[g]));
                float hi = silu_f(bfhi(au[g]) + bfhi(bu[g]));
                ov[g] = f2bf_pk(lo, hi);
            }
            o.x = ov[0]; o.y = ov[1]; o.z = ov[2]; o.w = ov[3];
            *(uint4*)&hids[el*SK + q*32 + c*8] = o;
        }
    }

    // persistent B fragments (W2, per wave: 32 cols)
    int w = tid >> 6, l = tid & 63;
    int lr = l & 15, lq = l >> 4;
    short8 bfr[2][4];
    #pragma unroll
    for (int nt = 0; nt < 2; nt++)
        #pragma unroll
        for (int kc = 0; kc < 4; kc++)
            bfr[nt][kc] = *(const short8*)(w2t + (w*32 + nt*16 + lr)*128 + kc*32 + lq*8);

    __syncthreads();

    f32x4 acc[4][2];
    #pragma unroll
    for (int mt = 0; mt < 4; mt++)
        #pragma unroll
        for (int nt = 0; nt < 2; nt++) acc[mt][nt] = (f32x4){0.f,0.f,0.f,0.f};
    #pragma unroll
    for (int kc = 0; kc < 4; kc++){
        #pragma unroll
        for (int mt = 0; mt < 4; mt++){
            short8 af = *(const short8*)&hids[(mt*16 + lr)*SK + kc*32 + lq*8];
            #pragma unroll
            for (int nt = 0; nt < 2; nt++)
                acc[mt][nt] = __builtin_amdgcn_mfma_f32_16x16x32_bf16(af, bfr[nt][kc], acc[mt][nt], 0, 0, 0);
        }
    }
    __syncthreads();   // all waves done reading hids -> reuse as m tile

    // epilogue: m = silu(acc + b2) -> bf16 LDS (stride MS)
    unsigned short* m_lds = hids;
    #pragma unroll
    for (int nt = 0; nt < 2; nt++){
        int col = w*32 + nt*16 + lr;
        float bv = b2[col];
        #pragma unroll
        for (int mt = 0; mt < 4; mt++){
            #pragma unroll
            for (int r = 0; r < 4; r++){
                int row = mt*16 + lq*4 + r;
                m_lds[row*MS + col] = f2bf(silu_f(acc[mt][nt][r] + bv));
            }
        }
    }
    __syncthreads();

    // segmented row-sum: 128 threads, one dim each
    if (tid < 128){
        int d = tid;
        float run = bfu(m_lds[0*MS + d]);
        int curn = nid[0];
        int runStart = 0;
        for (int row = 1; row < 64; row++){
            int n = nid[row];
            float v = bfu(m_lds[row*MS + d]);
            if (n == curn){
                run += v;
            } else {
                if (runStart == 0 && flagL) atomicAdd(&agg[(size_t)curn*NH + d], run);
                else                        agg[(size_t)curn*NH + d] = run;
                curn = n; run = v; runStart = row;
            }
        }
        if ((runStart == 0 && flagL) || flagR) atomicAdd(&agg[(size_t)curn*NH + d], run);
        else                                   agg[(size_t)curn*NH + d] = run;
    }
}

// ---------------- node kernel: h = LN(h + MLP([h|agg])) * g + b ----------------
__global__ __launch_bounds__(256) void k_node(
    const float* __restrict__ h, const float* __restrict__ agg,
    const float* __restrict__ w1, const float* __restrict__ b1,
    const float* __restrict__ w2, const float* __restrict__ b2,
    const float* __restrict__ g, const float* __restrict__ bta,
    float* __restrict__ hout)
{
    __shared__ __align__(16) float h_t [128*36];
    __shared__ __align__(16) float x_t2[128*36];
    __shared__ __align__(16) float t1_t[128*36];
    __shared__ float mu_s[32], rs_s[32];
    int tid = threadIdx.x;
    int tile0 = blockIdx.x*32;
    {
        int r = tid >> 3, dq = tid & 7;
        int node = tile0 + r;
        bool valid = node < NV;
        const float* hr = h   + (size_t)node*NH + dq*4;
        const float* ar = agg + (size_t)node*NH + dq*4;
        #pragma unroll
        for (int i = 0; i < 4; i++){
            int d = i*32 + dq*4;
            float4 v = valid ? *(const float4*)(hr + i*32) : make_float4(0.f,0.f,0.f,0.f);
            float4 a = valid ? *(const float4*)(ar + i*32) : make_float4(0.f,0.f,0.f,0.f);
            h_t [(d+0)*36 + r] = v.x; h_t [(d+1)*36 + r] = v.y;
            h_t [(d+2)*36 + r] = v.z; h_t [(d+3)*36 + r] = v.w;
            x_t2[(d+0)*36 + r] = a.x; x_t2[(d+1)*36 + r] = a.y;
            x_t2[(d+2)*36 + r] = a.z; x_t2[(d+3)*36 + r] = a.w;
        }
    }
    __syncthreads();
    int tc = tid & 31, tr = tid >> 5;
    int d0 = tc*4, n0 = tr*4;
    float acc[4][4];
    #pragma unroll
    for (int i = 0; i < 4; i++)
        #pragma unroll
        for (int j = 0; j < 4; j++) acc[i][j] = 0.f;
    for (int k = 0; k < 128; k++){
        float4 a4 = *(const float4*)&h_t[k*36 + n0];
        float4 w4 = *(const float4*)(w1 + k*128 + d0);
        float av[4] = {a4.x,a4.y,a4.z,a4.w};
        float wv[4] = {w4.x,w4.y,w4.z,w4.w};
        #pragma unroll
        for (int i = 0; i < 4; i++)
            #pragma unroll
            for (int j = 0; j < 4; j++) acc[i][j] += av[i]*wv[j];
    }
    for (int k = 0; k < 128; k++){
        float4 a4 = *(const float4*)&x_t2[k*36 + n0];
        float4 w4 = *(const float4*)(w1 + (128+k)*128 + d0);
        float av[4] = {a4.x,a4.y,a4.z,a4.w};
        float wv[4] = {w4.x,w4.y,w4.z,w4.w};
        #pragma unroll
        for (int i = 0; i < 4; i++)
            #pragma unroll
            for (int j = 0; j < 4; j++) acc[i][j] += av[i]*wv[j];
    }
    float4 b14 = *(const float4*)(b1 + d0);
    float bv1[4] = {b14.x, b14.y, b14.z, b14.w};
    #pragma unroll
    for (int i = 0; i < 4; i++)
        #pragma unroll
        for (int j = 0; j < 4; j++)
            t1_t[(d0+j)*36 + (n0+i)] = silu_f(acc[i][j] + bv1[j]);
    __syncthreads();
    float acc2[4][4];
    #pragma unroll
    for (int i = 0; i < 4; i++)
        #pragma unroll
        for (int j = 0; j < 4; j++) acc2[i][j] = 0.f;
    for (int k = 0; k < 128; k++){
        float4 a4 = *(const float4*)&t1_t[k*36 + n0];
        float4 w4 = *(const float4*)(w2 + k*128 + d0);
        float av[4] = {a4.x,a4.y,a4.z,a4.w};
        float wv[4] = {w4.x,w4.y,w4.z,w4.w};
        #pragma unroll
        for (int i = 0; i < 4; i++)
            #pragma unroll
            for (int j = 0; j < 4; j++) acc2[i][j] += av[i]*wv[j];
    }
    float4 b24 = *(const float4*)(b2 + d0);
    float bv2[4] = {b24.x, b24.y, b24.z, b24.w};
    #pragma unroll
    for (int i = 0; i < 4; i++)
        #pragma unroll
        for (int j = 0; j < 4; j++)
            x_t2[(d0+j)*36 + (n0+i)] = h_t[(d0+j)*36 + (n0+i)] + acc2[i][j] + bv2[j];
    __syncthreads();
    if (tid < 32){
        float s = 0.f, sq = 0.f;
        for (int d = 0; d < 128; d++){
            float x = x_t2[d*36 + tid];
            s += x; sq += x*x;
        }
        float mu = s * (1.f/128.f);
        float var = sq * (1.f/128.f) - mu*mu;
        mu_s[tid] = mu;
        rs_s[tid] = rsqrtf(var + 1e-5f);
    }
    __syncthreads();
    #pragma unroll
    for (int i = 0; i < 4; i++){
        int node = tile0 + n0 + i;
        if (node < NV){
            float mu = mu_s[n0+i], rs = rs_s[n0+i];
            float4 o;
            o.x = g[d0+0]*(x_t2[(d0+0)*36 + n0+i] - mu)*rs + bta[d0+0];
            o.y = g[d0+1]*(x_t2[(d0+1)*36 + n0+i] - mu)*rs + bta[d0+1];
            o.z = g[d0+2]*(x_t2[(d0+2)*36 + n0+i] - mu)*rs + bta[d0+2];
            o.w = g[d0+3]*(x_t2[(d0+3)*36 + n0+i] - mu)*rs + bta[d0+3];
            *(float4*)(hout + (size_t)node*NH + d0) = o;
        }
    }
}

// ---------------- output projection + MSE ----------------
__global__ __launch_bounds__(256) void k_out(const float* __restrict__ h,
                                             const float* __restrict__ opw, const float* __restrict__ opb,
                                             const float* __restrict__ pos0, const float* __restrict__ pos1,
                                             float* __restrict__ out)
{
    int v = blockIdx.x*256 + threadIdx.x;
    float sse = 0.f;
    if (v < NV){
        float v0 = opb[0], v1 = opb[1], v2 = opb[2];
        const float* hr = h + (size_t)v*NH;
        for (int k = 0; k < 128; k += 4){
            float4 hv = *(const float4*)(hr + k);
            v0 += hv.x*opw[(k+0)*3+0] + hv.y*opw[(k+1)*3+0] + hv.z*opw[(k+2)*3+0] + hv.w*opw[(k+3)*3+0];
            v1 += hv.x*opw[(k+0)*3+1] + hv.y*opw[(k+1)*3+1] + hv.z*opw[(k+2)*3+1] + hv.w*opw[(k+3)*3+1];
            v2 += hv.x*opw[(k+0)*3+2] + hv.y*opw[(k+1)*3+2] + hv.z*opw[(k+2)*3+2] + hv.w*opw[(k+3)*3+2];
        }
        float d0 = v0 - (pos1[v*3+0] - pos0[v*3+0]);
        float d1 = v1 - (pos1[v*3+1] - pos0[v*3+1]);
        float d2 = v2 - (pos1[v*3+2] - pos0[v*3+2]);
        sse = d0*d0 + d1*d1 + d2*d2;
    }
    for (int off = 32; off > 0; off >>= 1) sse += __shfl_down(sse, off, 64);
    __shared__ float red[4];
    if ((threadIdx.x & 63) == 0) red[threadIdx.x >> 6] = sse;
    __syncthreads();
    if (threadIdx.x == 0){
        float tot = red[0] + red[1] + red[2] + red[3];
        atomicAdd(out, tot * (1.0f/150000.0f));
    }
}

extern "C" void kernel_launch(void* const* d_in, const int* in_sizes, int n_in,
                              void* d_out, int out_size, void* d_ws, size_t ws_size,
                              hipStream_t stream)
{
    const float* pos0  = (const float*)d_in[0];
    const float* pos1  = (const float*)d_in[1];
    const float* z     = (const float*)d_in[2];
    const float* t     = (const float*)d_in[3];
    const int*   ei    = (const int*)d_in[4];
    const int*   batch = (const int*)d_in[5];
    const float* te_w1 = (const float*)d_in[6];
    const float* te_b1 = (const float*)d_in[7];
    const float* te_w2 = (const float*)d_in[8];
    const float* te_b2 = (const float*)d_in[9];
    const float* cp_w  = (const float*)d_in[10];
    const float* cp_b  = (const float*)d_in[11];
    const float* ew1   = (const float*)d_in[12];
    const float* eb1   = (const float*)d_in[13];
    const float* ew2   = (const float*)d_in[14];
    const float* eb2   = (const float*)d_in[15];
    const float* nw1   = (const float*)d_in[16];
    const float* nb1   = (const float*)d_in[17];
    const float* nw2   = (const float*)d_in[18];
    const float* nb2   = (const float*)d_in[19];
    const float* ln_g  = (const float*)d_in[20];
    const float* ln_b  = (const float*)d_in[21];
    const float* op_w  = (const float*)d_in[22];
    const float* op_b  = (const float*)d_in[23];

    float* ws     = (float*)d_ws;
    float* tconst = ws;                        // 128
    float* zcp    = ws + 128;                  // 1024
    float* xt     = ws + 1152;                 // 150016 (NV*3 padded)
    float* h      = ws + 151168;               // NV*NH fp32
    float* agg    = h + (size_t)NV*NH;         // NV*NH fp32
    int*   ibase  = (int*)(agg + (size_t)NV*NH);
    int*   rowptr  = ibase;                    // 50016
    int*   cursor  = ibase + 50016;            // 50016
    int*   csr_eid = ibase + 100032;           // NE
    int*   csr_dst = csr_eid + NE;             // NE
    unsigned short* pre_di = (unsigned short*)(csr_dst + NE);   // NV*NH bf16
    unsigned short* pre_sj = pre_di + (size_t)NV*NH;            // NV*NH bf16
    unsigned short* wpk    = pre_sj + (size_t)NV*NH;            // 4*3*16384 bf16

    const int* srcrow = ei;        // edge_index[0] = src j
    const int* dstrow = ei + NE;   // edge_index[1] = dst i

    hipMemsetAsync(cursor, 0, (size_t)NV*4, stream);
    k_setup<<<1, 128, 0, stream>>>(z, t, te_w1, te_b1, te_w2, te_b2, cp_w, cp_b, tconst, zcp);
    k_init<<<(NV*NH)/256, 256, 0, stream>>>(batch, zcp, tconst, h);
    k_xt<<<(NV*3 + 255)/256, 256, 0, stream>>>(pos0, pos1, t, xt);
    k_hist<<<NE/256, 256, 0, stream>>>(dstrow, cursor);
    k_scan<<<1, 1024, 0, stream>>>(cursor, rowptr);
    k_scatter<<<NE/256, 256, 0, stream>>>(dstrow, cursor, csr_eid, csr_dst);
    k_pack_wpk<<<(4*3*16384)/256, 256, 0, stream>>>(ew1, ew2, wpk);

    for (int l = 0; l < NL; l++){
        const float* ew1l = ew1 + (size_t)l*259*128;
        const unsigned short* wpk_l = wpk + (size_t)l*3*16384;
        k_pre_mfma<<<dim3((NV + 63)/64, 2), 256, 0, stream>>>(h, xt, wpk_l,
                                                              ew1l + 256*128, eb1 + l*128,
                                                              pre_di, pre_sj);
        hipMemsetAsync(agg, 0, (size_t)NV*NH*4, stream);
        k_edge_mfma<<<NE/64, 256, 0, stream>>>(pre_di, pre_sj, csr_eid, csr_dst, srcrow, rowptr,
                                               wpk_l + 2*16384, eb2 + l*128, agg);
        k_node<<<(NV + 31)/32, 256, 0, stream>>>(h, agg,
                                                 nw1 + (size_t)l*256*128, nb1 + l*128,
                                                 nw2 + (size_t)l*128*128, nb2 + l*128,
                                                 ln_g + l*128, ln_b + l*128, h);
    }

    hipMemsetAsync(d_out, 0, 4, stream);
    k_out<<<(NV + 255)/256, 256, 0, stream>>>(h, op_w, op_b, pos0, pos1, (float*)d_out);
}

// Round 5
// 1207.660 us; speedup vs baseline: 4.8498x; 1.3398x over previous
//
#include <hip/hip_runtime.h>

#define NV 50000
#define NE 800000
#define NB 8
#define NH 128
#define NLAT 64
#define NTD 16
#define NL 4
#define SK 136   // LDS row stride (bf16 elems) for MFMA A tiles
#define MS 132   // LDS row stride (bf16 elems) for m tile

typedef __attribute__((ext_vector_type(8))) short short8;
typedef __attribute__((ext_vector_type(4))) float f32x4;

__device__ __forceinline__ float silu_f(float x){
    float e = __expf(-x);
    return x * __builtin_amdgcn_rcpf(1.0f + e);
}

__device__ __forceinline__ unsigned short f2bf(float x){
    unsigned u = __float_as_uint(x);
    unsigned r = (u >> 16) & 1;
    u += 0x7fffu + r;
    return (unsigned short)(u >> 16);
}
__device__ __forceinline__ unsigned f2bf_pk(float a, float b){
    return (unsigned)f2bf(a) | ((unsigned)f2bf(b) << 16);
}
__device__ __forceinline__ float bflo(unsigned u){ return __uint_as_float(u << 16); }
__device__ __forceinline__ float bfhi(unsigned u){ return __uint_as_float(u & 0xffff0000u); }
__device__ __forceinline__ float bfu(unsigned short s){ return __uint_as_float(((unsigned)s) << 16); }

// ---------------- setup: time embedding + cond-proj constants ----------------
__global__ void k_setup(const float* __restrict__ z, const float* __restrict__ t,
                        const float* __restrict__ te_w1, const float* __restrict__ te_b1,
                        const float* __restrict__ te_w2, const float* __restrict__ te_b2,
                        const float* __restrict__ cp_w, const float* __restrict__ cp_b,
                        float* __restrict__ tconst, float* __restrict__ zcp)
{
    __shared__ float hid[NTD];
    __shared__ float emb[NTD];
    int tid = threadIdx.x;
    float ts = t[0];
    if (tid < NTD) hid[tid] = silu_f(ts * te_w1[tid] + te_b1[tid]);
    __syncthreads();
    if (tid < NTD){
        float a = te_b2[tid];
        for (int j = 0; j < NTD; j++) a += hid[j] * te_w2[j*NTD + tid];
        emb[tid] = a;
    }
    __syncthreads();
    float tc = cp_b[tid];
    for (int j = 0; j < NTD; j++) tc += emb[j] * cp_w[(NLAT + j)*NH + tid];
    tconst[tid] = tc;
    for (int b = 0; b < NB; b++){
        float a = 0.f;
        for (int k = 0; k < NLAT; k++) a += z[b*NLAT + k] * cp_w[k*NH + tid];
        zcp[b*NH + tid] = a;
    }
}

__global__ void k_init(const int* __restrict__ batch, const float* __restrict__ zcp,
                       const float* __restrict__ tconst, float* __restrict__ h)
{
    int idx = blockIdx.x*256 + threadIdx.x;
    int v = idx >> 7, d = idx & 127;
    h[idx] = zcp[batch[v]*NH + d] + tconst[d];
}

__global__ void k_xt(const float* __restrict__ pos0, const float* __restrict__ pos1,
                     const float* __restrict__ t, float* __restrict__ xt)
{
    int idx = blockIdx.x*256 + threadIdx.x;
    if (idx < NV*3){
        float ts = t[0];
        xt[idx] = (1.f - ts)*pos0[idx] + ts*pos1[idx];
    }
}

// ---------------- CSR build ----------------
__global__ void k_hist(const int* __restrict__ dst, int* __restrict__ cnt)
{
    int e = blockIdx.x*256 + threadIdx.x;
    if (e < NE) atomicAdd(&cnt[dst[e]], 1);
}

__global__ void k_scan(int* __restrict__ cursor, int* __restrict__ rowptr)
{
    __shared__ int part[1024];
    int t = threadIdx.x;
    const int CH = 49;
    int base = t*CH;
    int s = 0;
    for (int j = 0; j < CH; j++){ int idx = base + j; if (idx < NV) s += cursor[idx]; }
    part[t] = s;
    __syncthreads();
    for (int off = 1; off < 1024; off <<= 1){
        int a = part[t];
        int b = (t >= off) ? part[t - off] : 0;
        __syncthreads();
        part[t] = a + b;
        __syncthreads();
    }
    int run = (t == 0) ? 0 : part[t-1];
    for (int j = 0; j < CH; j++){
        int idx = base + j;
        if (idx < NV){
            int d = cursor[idx];
            cursor[idx] = run;
            rowptr[idx] = run;
            run += d;
        }
    }
    if (t == 1023) rowptr[NV] = NE;
}

__global__ void k_scatter(const int* __restrict__ dst, int* __restrict__ cursor,
                          int* __restrict__ csr_eid, int* __restrict__ csr_dst)
{
    int e = blockIdx.x*256 + threadIdx.x;
    if (e < NE){
        int i = dst[e];
        int p = atomicAdd(&cursor[i], 1);
        csr_eid[p] = e;
        csr_dst[p] = i;
    }
}

// ---------------- pack weights -> bf16 [l][{eWd,eWs,eW2,nW1d,nW1a,nW2}][n][k] ----------------
__global__ void k_pack_wpk(const float* __restrict__ ew1, const float* __restrict__ ew2,
                           const float* __restrict__ nw1, const float* __restrict__ nw2,
                           unsigned short* __restrict__ wpk)
{
    int idx = blockIdx.x*256 + threadIdx.x;        // 4*6*16384
    int lm = idx >> 14;
    int l = lm / 6, m = lm % 6;
    int r = idx & 16383;
    int n = r >> 7, k = r & 127;
    float v;
    if (m < 2)       v = ew1[l*33152 + (m*128 + k)*128 + n];
    else if (m == 2) v = ew2[l*16384 + k*128 + n];
    else if (m < 5)  v = nw1[l*32768 + ((m-3)*128 + k)*128 + n];
    else             v = nw2[l*16384 + k*128 + n];
    wpk[idx] = f2bf(v);
}

// ---------------- pre-projection (MFMA, bf16 out, dx-term + b1 folded) ----------------
__global__ __launch_bounds__(256) void k_pre_mfma(
    const float* __restrict__ h, const float* __restrict__ xt,
    const unsigned short* __restrict__ wpk_l,   // Wd at +0, Ws at +16384
    const float* __restrict__ w1c, const float* __restrict__ b1,
    unsigned short* __restrict__ pre_di, unsigned short* __restrict__ pre_sj)
{
    __shared__ __align__(16) unsigned short asd[64*SK];
    __shared__ float xts[64*4];
    int tid = threadIdx.x;
    int tile0 = blockIdx.x*64;
    int branch = blockIdx.y;

    {
        int r = tid >> 2, dq = tid & 3;
        int node = tile0 + r;
        bool valid = node < NV;
        const float4* hrow = (const float4*)(h + (size_t)node*NH + dq*32);
        #pragma unroll
        for (int c = 0; c < 4; c++){
            float4 v0 = valid ? hrow[c*2]     : make_float4(0.f,0.f,0.f,0.f);
            float4 v1 = valid ? hrow[c*2 + 1] : make_float4(0.f,0.f,0.f,0.f);
            uint4 o;
            o.x = f2bf_pk(v0.x, v0.y);
            o.y = f2bf_pk(v0.z, v0.w);
            o.z = f2bf_pk(v1.x, v1.y);
            o.w = f2bf_pk(v1.z, v1.w);
            *(uint4*)&asd[r*SK + dq*32 + c*8] = o;
        }
    }
    if (tid < 64){
        int node = tile0 + tid;
        bool valid = node < NV;
        xts[tid*4+0] = valid ? xt[node*3+0] : 0.f;
        xts[tid*4+1] = valid ? xt[node*3+1] : 0.f;
        xts[tid*4+2] = valid ? xt[node*3+2] : 0.f;
        xts[tid*4+3] = 0.f;
    }

    int w = tid >> 6, l = tid & 63;
    int lr = l & 15, lq = l >> 4;
    const unsigned short* wb = wpk_l + branch*16384;
    short8 bfr[2][4];
    #pragma unroll
    for (int nt = 0; nt < 2; nt++)
        #pragma unroll
        for (int kc = 0; kc < 4; kc++)
            bfr[nt][kc] = *(const short8*)(wb + (w*32 + nt*16 + lr)*128 + kc*32 + lq*8);

    __syncthreads();

    f32x4 acc[4][2];
    #pragma unroll
    for (int mt = 0; mt < 4; mt++)
        #pragma unroll
        for (int nt = 0; nt < 2; nt++) acc[mt][nt] = (f32x4){0.f,0.f,0.f,0.f};
    #pragma unroll
    for (int kc = 0; kc < 4; kc++){
        #pragma unroll
        for (int mt = 0; mt < 4; mt++){
            short8 af = *(const short8*)&asd[(mt*16 + lr)*SK + kc*32 + lq*8];
            #pragma unroll
            for (int nt = 0; nt < 2; nt++)
                acc[mt][nt] = __builtin_amdgcn_mfma_f32_16x16x32_bf16(af, bfr[nt][kc], acc[mt][nt], 0, 0, 0);
        }
    }

    unsigned short* out = branch ? pre_sj : pre_di;
    #pragma unroll
    for (int nt = 0; nt < 2; nt++){
        int col = w*32 + nt*16 + lr;
        float c0 = w1c[col], c1 = w1c[128 + col], c2 = w1c[256 + col];
        float bb = branch ? 0.f : b1[col];
        #pragma unroll
        for (int mt = 0; mt < 4; mt++){
            #pragma unroll
            for (int r = 0; r < 4; r++){
                int row = mt*16 + lq*4 + r;
                int node = tile0 + row;
                if (node < NV){
                    float qv = xts[row*4+0]*c0 + xts[row*4+1]*c1 + xts[row*4+2]*c2;
                    float val = acc[mt][nt][r] + (branch ? -qv : qv + bb);
                    out[(size_t)node*NH + col] = f2bf(val);
                }
            }
        }
    }
}

// ---------------- fused edge kernel: hid = silu(pre_di[i]+pre_sj[j]); m = silu(hid@W2+b2); seg-sum -> agg ----------------
__global__ __launch_bounds__(256) void k_edge_mfma(
    const unsigned short* __restrict__ pre_di, const unsigned short* __restrict__ pre_sj,
    const int* __restrict__ csr_eid, const int* __restrict__ csr_dst,
    const int* __restrict__ srcrow, const int* __restrict__ rowptr,
    const unsigned short* __restrict__ w2t,   // [n][k] bf16
    const float* __restrict__ b2,
    float* __restrict__ agg)
{
    __shared__ __align__(16) unsigned short hids[64*SK];   // 17.4 KB; reused as bf16 m tile
    __shared__ int nid[64];
    __shared__ int flagL, flagR;
    int tid = threadIdx.x;
    int p0 = blockIdx.x * 64;                       // NE % 64 == 0

    if (tid == 0){
        int iN0  = csr_dst[p0];
        int iN63 = csr_dst[p0 + 63];
        flagL = (rowptr[iN0] < p0) ? 1 : 0;
        flagR = (rowptr[iN63 + 1] > p0 + 64) ? 1 : 0;
    }

    // hid phase: 4 threads/edge, 32 dims each
    {
        int el = tid >> 2, q = tid & 3;
        int p = p0 + el;
        int eid = csr_eid[p];
        int iN  = csr_dst[p];
        int jN  = srcrow[eid];
        if (q == 0) nid[el] = iN;
        const uint4* gd = (const uint4*)(pre_di + (size_t)iN*NH + q*32);
        const uint4* gs = (const uint4*)(pre_sj + (size_t)jN*NH + q*32);
        #pragma unroll
        for (int c = 0; c < 4; c++){
            uint4 a = gd[c], b = gs[c];
            unsigned au[4] = {a.x, a.y, a.z, a.w};
            unsigned bu[4] = {b.x, b.y, b.z, b.w};
            uint4 o;
            unsigned ov[4];
            #pragma unroll
            for (int g = 0; g < 4; g++){
                float lo = silu_f(bflo(au[g]) + bflo(bu[g]));
                float hi = silu_f(bfhi(au[g]) + bfhi(bu[g]));
                ov[g] = f2bf_pk(lo, hi);
            }
            o.x = ov[0]; o.y = ov[1]; o.z = ov[2]; o.w = ov[3];
            *(uint4*)&hids[el*SK + q*32 + c*8] = o;
        }
    }

    int w = tid >> 6, l = tid & 63;
    int lr = l & 15, lq = l >> 4;
    short8 bfr[2][4];
    #pragma unroll
    for (int nt = 0; nt < 2; nt++)
        #pragma unroll
        for (int kc = 0; kc < 4; kc++)
            bfr[nt][kc] = *(const short8*)(w2t + (w*32 + nt*16 + lr)*128 + kc*32 + lq*8);

    __syncthreads();

    f32x4 acc[4][2];
    #pragma unroll
    for (int mt = 0; mt < 4; mt++)
        #pragma unroll
        for (int nt = 0; nt < 2; nt++) acc[mt][nt] = (f32x4){0.f,0.f,0.f,0.f};
    #pragma unroll
    for (int kc = 0; kc < 4; kc++){
        #pragma unroll
        for (int mt = 0; mt < 4; mt++){
            short8 af = *(const short8*)&hids[(mt*16 + lr)*SK + kc*32 + lq*8];
            #pragma unroll
            for (int nt = 0; nt < 2; nt++)
                acc[mt][nt] = __builtin_amdgcn_mfma_f32_16x16x32_bf16(af, bfr[nt][kc], acc[mt][nt], 0, 0, 0);
        }
    }
    __syncthreads();   // all waves done reading hids -> reuse as m tile

    // epilogue: m = silu(acc + b2) -> bf16 LDS (stride MS)
    unsigned short* m_lds = hids;
    #pragma unroll
    for (int nt = 0; nt < 2; nt++){
        int col = w*32 + nt*16 + lr;
        float bv = b2[col];
        #pragma unroll
        for (int mt = 0; mt < 4; mt++){
            #pragma unroll
            for (int r = 0; r < 4; r++){
                int row = mt*16 + lq*4 + r;
                m_lds[row*MS + col] = f2bf(silu_f(acc[mt][nt][r] + bv));
            }
        }
    }
    __syncthreads();

    // segmented row-sum: 256 threads; half covers rows [half*32, half*32+32)
    {
        int half = tid >> 7, d = tid & 127;
        int r0 = half*32, r1 = r0 + 32;
        int junc = (nid[31] == nid[32]);
        float run = bfu(m_lds[r0*MS + d]);
        int curn = nid[r0];
        int runStart = r0;
        for (int row = r0+1; row < r1; row++){
            int n = nid[row];
            float v = bfu(m_lds[row*MS + d]);
            if (n == curn){
                run += v;
            } else {
                bool at = (half == 0) ? (runStart == 0 && flagL)
                                      : (runStart == 32 && junc);
                if (at) atomicAdd(&agg[(size_t)curn*NH + d], run);
                else    agg[(size_t)curn*NH + d] = run;
                curn = n; run = v; runStart = row;
            }
        }
        bool at = (half == 0) ? ((runStart == 0 && flagL) || junc)
                              : ((runStart == 32 && junc) || flagR);
        if (at) atomicAdd(&agg[(size_t)curn*NH + d], run);
        else    agg[(size_t)curn*NH + d] = run;
    }
}

// ---------------- node kernel (MFMA): h = LN(h + MLP([h|agg])) * g + b ----------------
__global__ __launch_bounds__(256) void k_node_mfma(
    float* __restrict__ h, const float* __restrict__ agg,
    const unsigned short* __restrict__ wn,   // [3][128][128] bf16: W1d, W1a, W2
    const float* __restrict__ b1, const float* __restrict__ b2,
    const float* __restrict__ g, const float* __restrict__ bta)
{
    __shared__ __align__(16) unsigned short abuf[2*64*SK];   // a1 | a2; later x fp32 (stride 132)
    __shared__ float ps[64][4], pq[64][4];
    __shared__ float mu_s[64], rs_s[64];
    int tid = threadIdx.x;
    int tile0 = blockIdx.x*64;
    unsigned short* a1 = abuf;
    unsigned short* a2 = abuf + 64*SK;

    // stage h and agg tiles as bf16
    {
        int r = tid >> 2, dq = tid & 3;
        int node = tile0 + r;
        bool valid = node < NV;
        const float4* hrow = (const float4*)(h   + (size_t)node*NH + dq*32);
        const float4* arow = (const float4*)(agg + (size_t)node*NH + dq*32);
        #pragma unroll
        for (int c = 0; c < 4; c++){
            float4 v0 = valid ? hrow[c*2]     : make_float4(0.f,0.f,0.f,0.f);
            float4 v1 = valid ? hrow[c*2 + 1] : make_float4(0.f,0.f,0.f,0.f);
            float4 u0 = valid ? arow[c*2]     : make_float4(0.f,0.f,0.f,0.f);
            float4 u1 = valid ? arow[c*2 + 1] : make_float4(0.f,0.f,0.f,0.f);
            uint4 o;
            o.x = f2bf_pk(v0.x, v0.y); o.y = f2bf_pk(v0.z, v0.w);
            o.z = f2bf_pk(v1.x, v1.y); o.w = f2bf_pk(v1.z, v1.w);
            *(uint4*)&a1[r*SK + dq*32 + c*8] = o;
            uint4 p;
            p.x = f2bf_pk(u0.x, u0.y); p.y = f2bf_pk(u0.z, u0.w);
            p.z = f2bf_pk(u1.x, u1.y); p.w = f2bf_pk(u1.z, u1.w);
            *(uint4*)&a2[r*SK + dq*32 + c*8] = p;
        }
    }

    int w = tid >> 6, l = tid & 63;
    int lr = l & 15, lq = l >> 4;
    int colb = w*32;

    __syncthreads();

    f32x4 acc[4][2];
    #pragma unroll
    for (int mt = 0; mt < 4; mt++)
        #pragma unroll
        for (int nt = 0; nt < 2; nt++) acc[mt][nt] = (f32x4){0.f,0.f,0.f,0.f};

    // GEMM1a: h @ W1d
    {
        short8 bfr[2][4];
        #pragma unroll
        for (int nt = 0; nt < 2; nt++)
            #pragma unroll
            for (int kc = 0; kc < 4; kc++)
                bfr[nt][kc] = *(const short8*)(wn + (colb + nt*16 + lr)*128 + kc*32 + lq*8);
        #pragma unroll
        for (int kc = 0; kc < 4; kc++)
            #pragma unroll
            for (int mt = 0; mt < 4; mt++){
                short8 af = *(const short8*)&a1[(mt*16 + lr)*SK + kc*32 + lq*8];
                #pragma unroll
                for (int nt = 0; nt < 2; nt++)
                    acc[mt][nt] = __builtin_amdgcn_mfma_f32_16x16x32_bf16(af, bfr[nt][kc], acc[mt][nt], 0, 0, 0);
            }
    }
    // GEMM1b: agg @ W1a
    {
        short8 bfr[2][4];
        #pragma unroll
        for (int nt = 0; nt < 2; nt++)
            #pragma unroll
            for (int kc = 0; kc < 4; kc++)
                bfr[nt][kc] = *(const short8*)(wn + 16384 + (colb + nt*16 + lr)*128 + kc*32 + lq*8);
        #pragma unroll
        for (int kc = 0; kc < 4; kc++)
            #pragma unroll
            for (int mt = 0; mt < 4; mt++){
                short8 af = *(const short8*)&a2[(mt*16 + lr)*SK + kc*32 + lq*8];
                #pragma unroll
                for (int nt = 0; nt < 2; nt++)
                    acc[mt][nt] = __builtin_amdgcn_mfma_f32_16x16x32_bf16(af, bfr[nt][kc], acc[mt][nt], 0, 0, 0);
            }
    }
    __syncthreads();   // done reading a1/a2

    // t1 = silu(acc + b1) -> bf16 into a1 space
    #pragma unroll
    for (int nt = 0; nt < 2; nt++){
        int col = colb + nt*16 + lr;
        float bv = b1[col];
        #pragma unroll
        for (int mt = 0; mt < 4; mt++)
            #pragma unroll
            for (int r = 0; r < 4; r++){
                int row = mt*16 + lq*4 + r;
                a1[row*SK + col] = f2bf(silu_f(acc[mt][nt][r] + bv));
            }
    }
    __syncthreads();

    // GEMM2: t1 @ W2
    f32x4 acc2[4][2];
    #pragma unroll
    for (int mt = 0; mt < 4; mt++)
        #pragma unroll
        for (int nt = 0; nt < 2; nt++) acc2[mt][nt] = (f32x4){0.f,0.f,0.f,0.f};
    {
        short8 bfr[2][4];
        #pragma unroll
        for (int nt = 0; nt < 2; nt++)
            #pragma unroll
            for (int kc = 0; kc < 4; kc++)
                bfr[nt][kc] = *(const short8*)(wn + 2*16384 + (colb + nt*16 + lr)*128 + kc*32 + lq*8);
        #pragma unroll
        for (int kc = 0; kc < 4; kc++)
            #pragma unroll
            for (int mt = 0; mt < 4; mt++){
                short8 af = *(const short8*)&a1[(mt*16 + lr)*SK + kc*32 + lq*8];
                #pragma unroll
                for (int nt = 0; nt < 2; nt++)
                    acc2[mt][nt] = __builtin_amdgcn_mfma_f32_16x16x32_bf16(af, bfr[nt][kc], acc2[mt][nt], 0, 0, 0);
            }
    }
    __syncthreads();   // done reading t1 -> reuse abuf as fp32 x tile

    // x = h + acc2 + b2 -> fp32 LDS (stride 132)
    float* xls = (float*)abuf;
    #pragma unroll
    for (int nt = 0; nt < 2; nt++){
        int col = colb + nt*16 + lr;
        float bv = b2[col];
        #pragma unroll
        for (int mt = 0; mt < 4; mt++)
            #pragma unroll
            for (int r = 0; r < 4; r++){
                int row = mt*16 + lq*4 + r;
                int node = tile0 + row;
                float hv = (node < NV) ? h[(size_t)node*NH + col] : 0.f;
                xls[row*132 + col] = hv + acc2[mt][nt][r] + bv;
            }
    }
    __syncthreads();

    // LN partials: thread (r, part) sums 32 dims
    {
        int r = tid >> 2, part = tid & 3;
        float s = 0.f, q = 0.f;
        #pragma unroll 8
        for (int i = 0; i < 32; i++){
            float x = xls[r*132 + part*32 + i];
            s += x; q += x*x;
        }
        ps[r][part] = s; pq[r][part] = q;
    }
    __syncthreads();
    if (tid < 64){
        float s = ps[tid][0] + ps[tid][1] + ps[tid][2] + ps[tid][3];
        float q = pq[tid][0] + pq[tid][1] + pq[tid][2] + pq[tid][3];
        float mu = s * (1.f/128.f);
        float var = q * (1.f/128.f) - mu*mu;
        mu_s[tid] = mu;
        rs_s[tid] = rsqrtf(var + 1e-5f);
    }
    __syncthreads();
    {
        int r = tid >> 2, part = tid & 3;
        int node = tile0 + r;
        if (node < NV){
            float mu = mu_s[r], rs = rs_s[r];
            #pragma unroll
            for (int c = 0; c < 8; c++){
                int d = part*32 + c*4;
                float4 o;
                o.x = g[d+0]*(xls[r*132 + d+0] - mu)*rs + bta[d+0];
                o.y = g[d+1]*(xls[r*132 + d+1] - mu)*rs + bta[d+1];
                o.z = g[d+2]*(xls[r*132 + d+2] - mu)*rs + bta[d+2];
                o.w = g[d+3]*(xls[r*132 + d+3] - mu)*rs + bta[d+3];
                *(float4*)(h + (size_t)node*NH + d) = o;
            }
        }
    }
}

// ---------------- output projection + MSE ----------------
__global__ __launch_bounds__(256) void k_out(const float* __restrict__ h,
                                             const float* __restrict__ opw, const float* __restrict__ opb,
                                             const float* __restrict__ pos0, const float* __restrict__ pos1,
                                             float* __restrict__ out)
{
    int v = blockIdx.x*256 + threadIdx.x;
    float sse = 0.f;
    if (v < NV){
        float v0 = opb[0], v1 = opb[1], v2 = opb[2];
        const float* hr = h + (size_t)v*NH;
        for (int k = 0; k < 128; k += 4){
            float4 hv = *(const float4*)(hr + k);
            v0 += hv.x*opw[(k+0)*3+0] + hv.y*opw[(k+1)*3+0] + hv.z*opw[(k+2)*3+0] + hv.w*opw[(k+3)*3+0];
            v1 += hv.x*opw[(k+0)*3+1] + hv.y*opw[(k+1)*3+1] + hv.z*opw[(k+2)*3+1] + hv.w*opw[(k+3)*3+1];
            v2 += hv.x*opw[(k+0)*3+2] + hv.y*opw[(k+1)*3+2] + hv.z*opw[(k+2)*3+2] + hv.w*opw[(k+3)*3+2];
        }
        float d0 = v0 - (pos1[v*3+0] - pos0[v*3+0]);
        float d1 = v1 - (pos1[v*3+1] - pos0[v*3+1]);
        float d2 = v2 - (pos1[v*3+2] - pos0[v*3+2]);
        sse = d0*d0 + d1*d1 + d2*d2;
    }
    for (int off = 32; off > 0; off >>= 1) sse += __shfl_down(sse, off, 64);
    __shared__ float red[4];
    if ((threadIdx.x & 63) == 0) red[threadIdx.x >> 6] = sse;
    __syncthreads();
    if (threadIdx.x == 0){
        float tot = red[0] + red[1] + red[2] + red[3];
        atomicAdd(out, tot * (1.0f/150000.0f));
    }
}

extern "C" void kernel_launch(void* const* d_in, const int* in_sizes, int n_in,
                              void* d_out, int out_size, void* d_ws, size_t ws_size,
                              hipStream_t stream)
{
    const float* pos0  = (const float*)d_in[0];
    const float* pos1  = (const float*)d_in[1];
    const float* z     = (const float*)d_in[2];
    const float* t     = (const float*)d_in[3];
    const int*   ei    = (const int*)d_in[4];
    const int*   batch = (const int*)d_in[5];
    const float* te_w1 = (const float*)d_in[6];
    const float* te_b1 = (const float*)d_in[7];
    const float* te_w2 = (const float*)d_in[8];
    const float* te_b2 = (const float*)d_in[9];
    const float* cp_w  = (const float*)d_in[10];
    const float* cp_b  = (const float*)d_in[11];
    const float* ew1   = (const float*)d_in[12];
    const float* eb1   = (const float*)d_in[13];
    const float* ew2   = (const float*)d_in[14];
    const float* eb2   = (const float*)d_in[15];
    const float* nw1   = (const float*)d_in[16];
    const float* nb1   = (const float*)d_in[17];
    const float* nw2   = (const float*)d_in[18];
    const float* nb2   = (const float*)d_in[19];
    const float* ln_g  = (const float*)d_in[20];
    const float* ln_b  = (const float*)d_in[21];
    const float* op_w  = (const float*)d_in[22];
    const float* op_b  = (const float*)d_in[23];

    float* ws     = (float*)d_ws;
    float* tconst = ws;                        // 128
    float* zcp    = ws + 128;                  // 1024
    float* xt     = ws + 1152;                 // 150016 (NV*3 padded)
    float* h      = ws + 151168;               // NV*NH fp32
    float* agg    = h + (size_t)NV*NH;         // NV*NH fp32
    int*   ibase  = (int*)(agg + (size_t)NV*NH);
    int*   rowptr  = ibase;                    // 50016
    int*   cursor  = ibase + 50016;            // 50016
    int*   csr_eid = ibase + 100032;           // NE
    int*   csr_dst = csr_eid + NE;             // NE
    unsigned short* pre_di = (unsigned short*)(csr_dst + NE);   // NV*NH bf16
    unsigned short* pre_sj = pre_di + (size_t)NV*NH;            // NV*NH bf16
    unsigned short* wpk    = pre_sj + (size_t)NV*NH;            // 4*6*16384 bf16

    const int* srcrow = ei;        // edge_index[0] = src j
    const int* dstrow = ei + NE;   // edge_index[1] = dst i

    hipMemsetAsync(cursor, 0, (size_t)NV*4, stream);
    k_setup<<<1, 128, 0, stream>>>(z, t, te_w1, te_b1, te_w2, te_b2, cp_w, cp_b, tconst, zcp);
    k_init<<<(NV*NH)/256, 256, 0, stream>>>(batch, zcp, tconst, h);
    k_xt<<<(NV*3 + 255)/256, 256, 0, stream>>>(pos0, pos1, t, xt);
    k_hist<<<NE/256, 256, 0, stream>>>(dstrow, cursor);
    k_scan<<<1, 1024, 0, stream>>>(cursor, rowptr);
    k_scatter<<<NE/256, 256, 0, stream>>>(dstrow, cursor, csr_eid, csr_dst);
    k_pack_wpk<<<(4*6*16384)/256, 256, 0, stream>>>(ew1, ew2, nw1, nw2, wpk);

    for (int l = 0; l < NL; l++){
        const float* ew1l = ew1 + (size_t)l*259*128;
        const unsigned short* wpk_l = wpk + (size_t)l*6*16384;
        k_pre_mfma<<<dim3((NV + 63)/64, 2), 256, 0, stream>>>(h, xt, wpk_l,
                                                              ew1l + 256*128, eb1 + l*128,
                                                              pre_di, pre_sj);
        hipMemsetAsync(agg, 0, (size_t)NV*NH*4, stream);
        k_edge_mfma<<<NE/64, 256, 0, stream>>>(pre_di, pre_sj, csr_eid, csr_dst, srcrow, rowptr,
                                               wpk_l + 2*16384, eb2 + l*128, agg);
        k_node_mfma<<<(NV + 63)/64, 256, 0, stream>>>(h, agg, wpk_l + 3*16384,
                                                      nb1 + l*128, nb2 + l*128,
                                                      ln_g + l*128, ln_b + l*128);
    }

    hipMemsetAsync(d_out, 0, 4, stream);
    k_out<<<(NV + 255)/256, 256, 0, stream>>>(h, op_w, op_b, pos0, pos1, (float*)d_out);
}

// Round 6
// 1073.828 us; speedup vs baseline: 5.4543x; 1.1246x over previous
//
#include <hip/hip_runtime.h>

#define NV 50000
#define NE 800000
#define NB 8
#define NH 128
#define NLAT 64
#define NTD 16
#define NL 4
#define SK 136   // LDS row stride (bf16 elems) for MFMA A tiles
#define MT 68    // LDS stride (bf16 elems) for transposed m tile: m_t[d][row], row 0..63

typedef __attribute__((ext_vector_type(8))) short short8;
typedef __attribute__((ext_vector_type(4))) float f32x4;

__device__ __forceinline__ float silu_f(float x){
    float e = __expf(-x);
    return x * __builtin_amdgcn_rcpf(1.0f + e);
}

__device__ __forceinline__ unsigned short f2bf(float x){
    unsigned u = __float_as_uint(x);
    unsigned r = (u >> 16) & 1;
    u += 0x7fffu + r;
    return (unsigned short)(u >> 16);
}
__device__ __forceinline__ unsigned f2bf_pk(float a, float b){
    return (unsigned)f2bf(a) | ((unsigned)f2bf(b) << 16);
}
__device__ __forceinline__ float bflo(unsigned u){ return __uint_as_float(u << 16); }
__device__ __forceinline__ float bfhi(unsigned u){ return __uint_as_float(u & 0xffff0000u); }

// ---------------- setup: time embedding + cond-proj constants ----------------
__global__ void k_setup(const float* __restrict__ z, const float* __restrict__ t,
                        const float* __restrict__ te_w1, const float* __restrict__ te_b1,
                        const float* __restrict__ te_w2, const float* __restrict__ te_b2,
                        const float* __restrict__ cp_w, const float* __restrict__ cp_b,
                        float* __restrict__ tconst, float* __restrict__ zcp)
{
    __shared__ float hid[NTD];
    __shared__ float emb[NTD];
    int tid = threadIdx.x;
    float ts = t[0];
    if (tid < NTD) hid[tid] = silu_f(ts * te_w1[tid] + te_b1[tid]);
    __syncthreads();
    if (tid < NTD){
        float a = te_b2[tid];
        for (int j = 0; j < NTD; j++) a += hid[j] * te_w2[j*NTD + tid];
        emb[tid] = a;
    }
    __syncthreads();
    float tc = cp_b[tid];
    for (int j = 0; j < NTD; j++) tc += emb[j] * cp_w[(NLAT + j)*NH + tid];
    tconst[tid] = tc;
    for (int b = 0; b < NB; b++){
        float a = 0.f;
        for (int k = 0; k < NLAT; k++) a += z[b*NLAT + k] * cp_w[k*NH + tid];
        zcp[b*NH + tid] = a;
    }
}

__global__ void k_init(const int* __restrict__ batch, const float* __restrict__ zcp,
                       const float* __restrict__ tconst, float* __restrict__ h)
{
    int idx = blockIdx.x*256 + threadIdx.x;
    int v = idx >> 7, d = idx & 127;
    h[idx] = zcp[batch[v]*NH + d] + tconst[d];
}

__global__ void k_xt(const float* __restrict__ pos0, const float* __restrict__ pos1,
                     const float* __restrict__ t, float* __restrict__ xt)
{
    int idx = blockIdx.x*256 + threadIdx.x;
    if (idx < NV*3){
        float ts = t[0];
        xt[idx] = (1.f - ts)*pos0[idx] + ts*pos1[idx];
    }
}

// ---------------- CSR build ----------------
__global__ void k_hist(const int* __restrict__ dst, int* __restrict__ cnt)
{
    int e = blockIdx.x*256 + threadIdx.x;
    if (e < NE) atomicAdd(&cnt[dst[e]], 1);
}

// multi-block scan: (1) per-block sums
__global__ void k_scan1(const int* __restrict__ deg, int* __restrict__ bsum)
{
    __shared__ int s[256];
    int tid = threadIdx.x;
    int idx = blockIdx.x*256 + tid;
    s[tid] = (idx < NV) ? deg[idx] : 0;
    __syncthreads();
    for (int off = 128; off > 0; off >>= 1){
        if (tid < off) s[tid] += s[tid + off];
        __syncthreads();
    }
    if (tid == 0) bsum[blockIdx.x] = s[0];
}

// (2) exclusive scan of 196 block sums, in place
__global__ void k_scan2(int* __restrict__ bsum)
{
    __shared__ int s[256];
    int tid = threadIdx.x;
    int v = (tid < 196) ? bsum[tid] : 0;
    s[tid] = v;
    __syncthreads();
    for (int off = 1; off < 256; off <<= 1){
        int a = s[tid];
        int b = (tid >= off) ? s[tid - off] : 0;
        __syncthreads();
        s[tid] = a + b;
        __syncthreads();
    }
    if (tid < 196) bsum[tid] = (tid == 0) ? 0 : s[tid - 1];
}

// (3) per-element exclusive prefix -> rowptr & cursor  (deg/cursor alias: read-then-write, same idx)
__global__ void k_scan3(const int* deg, const int* __restrict__ bsum,
                        int* __restrict__ rowptr, int* cursor)
{
    __shared__ int s[256];
    int tid = threadIdx.x;
    int idx = blockIdx.x*256 + tid;
    int v = (idx < NV) ? deg[idx] : 0;
    s[tid] = v;
    __syncthreads();
    for (int off = 1; off < 256; off <<= 1){
        int a = s[tid];
        int b = (tid >= off) ? s[tid - off] : 0;
        __syncthreads();
        s[tid] = a + b;
        __syncthreads();
    }
    int excl = bsum[blockIdx.x] + ((tid == 0) ? 0 : s[tid - 1]);
    if (idx < NV){
        rowptr[idx] = excl;
        cursor[idx] = excl;
    }
    if (idx == NV - 1) rowptr[NV] = NE;
}

__global__ void k_scatter(const int* __restrict__ dst, int* __restrict__ cursor,
                          int* __restrict__ csr_eid, int* __restrict__ csr_dst)
{
    int e = blockIdx.x*256 + threadIdx.x;
    if (e < NE){
        int i = dst[e];
        int p = atomicAdd(&cursor[i], 1);
        csr_eid[p] = e;
        csr_dst[p] = i;
    }
}

// ---------------- pack weights -> bf16 [l][{eWd,eWs,eW2,nW1d,nW1a,nW2}][n][k] ----------------
__global__ void k_pack_wpk(const float* __restrict__ ew1, const float* __restrict__ ew2,
                           const float* __restrict__ nw1, const float* __restrict__ nw2,
                           unsigned short* __restrict__ wpk)
{
    int idx = blockIdx.x*256 + threadIdx.x;        // 4*6*16384
    int lm = idx >> 14;
    int l = lm / 6, m = lm % 6;
    int r = idx & 16383;
    int n = r >> 7, k = r & 127;
    float v;
    if (m < 2)       v = ew1[l*33152 + (m*128 + k)*128 + n];
    else if (m == 2) v = ew2[l*16384 + k*128 + n];
    else if (m < 5)  v = nw1[l*32768 + ((m-3)*128 + k)*128 + n];
    else             v = nw2[l*16384 + k*128 + n];
    wpk[idx] = f2bf(v);
}

// ---------------- pre-projection (MFMA, bf16 out, dx-term + b1 folded, coalesced out) ----------------
__global__ __launch_bounds__(256) void k_pre_mfma(
    const float* __restrict__ h, const float* __restrict__ xt,
    const unsigned short* __restrict__ wpk_l,   // Wd at +0, Ws at +16384
    const float* __restrict__ w1c, const float* __restrict__ b1,
    unsigned short* __restrict__ pre_di, unsigned short* __restrict__ pre_sj)
{
    __shared__ __align__(16) unsigned short asd[64*SK];
    __shared__ float xts[64*4];
    int tid = threadIdx.x;
    int tile0 = blockIdx.x*64;
    int branch = blockIdx.y;

    {
        int r = tid >> 2, dq = tid & 3;
        int node = tile0 + r;
        bool valid = node < NV;
        const float4* hrow = (const float4*)(h + (size_t)node*NH + dq*32);
        #pragma unroll
        for (int c = 0; c < 4; c++){
            float4 v0 = valid ? hrow[c*2]     : make_float4(0.f,0.f,0.f,0.f);
            float4 v1 = valid ? hrow[c*2 + 1] : make_float4(0.f,0.f,0.f,0.f);
            uint4 o;
            o.x = f2bf_pk(v0.x, v0.y);
            o.y = f2bf_pk(v0.z, v0.w);
            o.z = f2bf_pk(v1.x, v1.y);
            o.w = f2bf_pk(v1.z, v1.w);
            *(uint4*)&asd[r*SK + dq*32 + c*8] = o;
        }
    }
    if (tid < 64){
        int node = tile0 + tid;
        bool valid = node < NV;
        xts[tid*4+0] = valid ? xt[node*3+0] : 0.f;
        xts[tid*4+1] = valid ? xt[node*3+1] : 0.f;
        xts[tid*4+2] = valid ? xt[node*3+2] : 0.f;
        xts[tid*4+3] = 0.f;
    }

    int w = tid >> 6, l = tid & 63;
    int lr = l & 15, lq = l >> 4;
    const unsigned short* wb = wpk_l + branch*16384;
    short8 bfr[2][4];
    #pragma unroll
    for (int nt = 0; nt < 2; nt++)
        #pragma unroll
        for (int kc = 0; kc < 4; kc++)
            bfr[nt][kc] = *(const short8*)(wb + (w*32 + nt*16 + lr)*128 + kc*32 + lq*8);

    __syncthreads();

    f32x4 acc[4][2];
    #pragma unroll
    for (int mt = 0; mt < 4; mt++)
        #pragma unroll
        for (int nt = 0; nt < 2; nt++) acc[mt][nt] = (f32x4){0.f,0.f,0.f,0.f};
    #pragma unroll
    for (int kc = 0; kc < 4; kc++){
        #pragma unroll
        for (int mt = 0; mt < 4; mt++){
            short8 af = *(const short8*)&asd[(mt*16 + lr)*SK + kc*32 + lq*8];
            #pragma unroll
            for (int nt = 0; nt < 2; nt++)
                acc[mt][nt] = __builtin_amdgcn_mfma_f32_16x16x32_bf16(af, bfr[nt][kc], acc[mt][nt], 0, 0, 0);
        }
    }
    __syncthreads();   // done reading A tile -> reuse asd as output tile

    // epilogue into LDS [row][col]
    #pragma unroll
    for (int nt = 0; nt < 2; nt++){
        int col = w*32 + nt*16 + lr;
        float c0 = w1c[col], c1 = w1c[128 + col], c2 = w1c[256 + col];
        float bb = branch ? 0.f : b1[col];
        #pragma unroll
        for (int mt = 0; mt < 4; mt++){
            #pragma unroll
            for (int r = 0; r < 4; r++){
                int row = mt*16 + lq*4 + r;
                float qv = xts[row*4+0]*c0 + xts[row*4+1]*c1 + xts[row*4+2]*c2;
                float val = acc[mt][nt][r] + (branch ? -qv : qv + bb);
                asd[row*SK + col] = f2bf(val);
            }
        }
    }
    __syncthreads();

    // coalesced store: thread (r, dq) stores 32 cols of node tile0+r
    {
        unsigned short* out = branch ? pre_sj : pre_di;
        int r = tid >> 2, dq = tid & 3;
        int node = tile0 + r;
        if (node < NV){
            #pragma unroll
            for (int c = 0; c < 4; c++){
                uint4 vv = *(const uint4*)&asd[r*SK + dq*32 + c*8];
                *(uint4*)(out + (size_t)node*NH + dq*32 + c*8) = vv;
            }
        }
    }
}

// ---------------- fused edge kernel: hid = silu(pre_di[i]+pre_sj[j]); m = silu(hid@W2+b2); seg-sum -> agg ----------------
__global__ __launch_bounds__(256) void k_edge_mfma(
    const unsigned short* __restrict__ pre_di, const unsigned short* __restrict__ pre_sj,
    const int* __restrict__ csr_eid, const int* __restrict__ csr_dst,
    const int* __restrict__ srcrow, const int* __restrict__ rowptr,
    const unsigned short* __restrict__ w2t,   // [n][k] bf16
    const float* __restrict__ b2,
    float* __restrict__ agg)
{
    __shared__ __align__(16) unsigned short hids[64*SK];   // 17.4 KB; reused as transposed m tile
    __shared__ int nid[64];
    __shared__ int flagL, flagR;
    __shared__ unsigned long long brkmask_s;
    int tid = threadIdx.x;
    int p0 = blockIdx.x * 64;                       // NE % 64 == 0

    if (tid == 0){
        int iN0  = csr_dst[p0];
        int iN63 = csr_dst[p0 + 63];
        flagL = (rowptr[iN0] < p0) ? 1 : 0;
        flagR = (rowptr[iN63 + 1] > p0 + 64) ? 1 : 0;
    }

    // hid phase: 4 threads/edge, 32 dims each
    {
        int el = tid >> 2, q = tid & 3;
        int p = p0 + el;
        int eid = csr_eid[p];
        int iN  = csr_dst[p];
        int jN  = srcrow[eid];
        if (q == 0) nid[el] = iN;
        const uint4* gd = (const uint4*)(pre_di + (size_t)iN*NH + q*32);
        const uint4* gs = (const uint4*)(pre_sj + (size_t)jN*NH + q*32);
        #pragma unroll
        for (int c = 0; c < 4; c++){
            uint4 a = gd[c], b = gs[c];
            unsigned au[4] = {a.x, a.y, a.z, a.w};
            unsigned bu[4] = {b.x, b.y, b.z, b.w};
            uint4 o;
            unsigned ov[4];
            #pragma unroll
            for (int g = 0; g < 4; g++){
                float lo = silu_f(bflo(au[g]) + bflo(bu[g]));
                float hi = silu_f(bfhi(au[g]) + bfhi(bu[g]));
                ov[g] = f2bf_pk(lo, hi);
            }
            o.x = ov[0]; o.y = ov[1]; o.z = ov[2]; o.w = ov[3];
            *(uint4*)&hids[el*SK + q*32 + c*8] = o;
        }
    }

    int w = tid >> 6, l = tid & 63;
    int lr = l & 15, lq = l >> 4;
    short8 bfr[2][4];
    #pragma unroll
    for (int nt = 0; nt < 2; nt++)
        #pragma unroll
        for (int kc = 0; kc < 4; kc++)
            bfr[nt][kc] = *(const short8*)(w2t + (w*32 + nt*16 + lr)*128 + kc*32 + lq*8);

    __syncthreads();

    // wave 0: segment-boundary bitmask from nid (bit r = row r starts a new run)
    if (tid < 64){
        bool b = (tid > 0) && (nid[tid] != nid[tid - 1]);
        unsigned long long mask = __ballot(b);
        if (tid == 0) brkmask_s = mask;
    }

    f32x4 acc[4][2];
    #pragma unroll
    for (int mt = 0; mt < 4; mt++)
        #pragma unroll
        for (int nt = 0; nt < 2; nt++) acc[mt][nt] = (f32x4){0.f,0.f,0.f,0.f};
    #pragma unroll
    for (int kc = 0; kc < 4; kc++){
        #pragma unroll
        for (int mt = 0; mt < 4; mt++){
            short8 af = *(const short8*)&hids[(mt*16 + lr)*SK + kc*32 + lq*8];
            #pragma unroll
            for (int nt = 0; nt < 2; nt++)
                acc[mt][nt] = __builtin_amdgcn_mfma_f32_16x16x32_bf16(af, bfr[nt][kc], acc[mt][nt], 0, 0, 0);
        }
    }
    __syncthreads();   // all waves done reading hids (and brkmask_s written) -> reuse as m_t

    // epilogue: m = silu(acc + b2) -> transposed bf16 LDS m_t[d][row], stride MT, packed 4 rows
    unsigned short* m_t = hids;    // 128 * MT = 8704 elems = 17408 B (exact fit)
    #pragma unroll
    for (int nt = 0; nt < 2; nt++){
        int col = w*32 + nt*16 + lr;
        float bv = b2[col];
        #pragma unroll
        for (int mt = 0; mt < 4; mt++){
            float v0 = silu_f(acc[mt][nt][0] + bv);
            float v1 = silu_f(acc[mt][nt][1] + bv);
            float v2 = silu_f(acc[mt][nt][2] + bv);
            float v3 = silu_f(acc[mt][nt][3] + bv);
            uint2 pk;
            pk.x = f2bf_pk(v0, v1);
            pk.y = f2bf_pk(v2, v3);
            *(uint2*)&m_t[col*MT + mt*16 + lq*4] = pk;
        }
    }
    __syncthreads();

    // segmented row-sum: 256 threads = 2 halves x 128 dims; vectorized b64 reads + boundary mask
    {
        int half = tid >> 7, d = tid & 127;
        int r0 = half * 32;
        unsigned long long mask = brkmask_s;
        bool junc = !((mask >> 32) & 1ull);          // run continues across row 31->32
        unsigned long long m2 = mask;
        if (half) m2 &= ~(1ull << 32);               // first row of half never flushes
        bool fL = (flagL != 0), fR = (flagR != 0);

        float run = 0.f;
        int curn = nid[r0];
        bool firstRun = true;
        const unsigned short* mrow = m_t + d*MT;

        #pragma unroll
        for (int g = 0; g < 8; g++){
            int row = r0 + g*4;
            uint2 v = *(const uint2*)&mrow[row];
            float f0 = bflo(v.x), f1 = bfhi(v.x);
            float f2 = bflo(v.y), f3 = bfhi(v.y);
            unsigned gm = (unsigned)((m2 >> row) & 0xFull);
            if (gm == 0u){
                run += (f0 + f1) + (f2 + f3);
            } else {
                float fv[4] = {f0, f1, f2, f3};
                #pragma unroll
                for (int r = 0; r < 4; r++){
                    if (gm & (1u << r)){
                        bool at = firstRun && (half == 0 ? fL : junc);
                        if (at) atomicAdd(&agg[(size_t)curn*NH + d], run);
                        else    agg[(size_t)curn*NH + d] = run;
                        firstRun = false;
                        run = 0.f;
                        curn = nid[row + r];
                    }
                    run += fv[r];
                }
            }
        }
        bool at = (half == 0) ? ((firstRun && fL) || junc)
                              : ((firstRun && junc) || fR);
        if (at) atomicAdd(&agg[(size_t)curn*NH + d], run);
        else    agg[(size_t)curn*NH + d] = run;
    }
}

// ---------------- node kernel (MFMA): h = LN(h + MLP([h|agg])) * g + b ----------------
__global__ __launch_bounds__(256) void k_node_mfma(
    float* __restrict__ h, const float* __restrict__ agg,
    const unsigned short* __restrict__ wn,   // [3][128][128] bf16: W1d, W1a, W2
    const float* __restrict__ b1, const float* __restrict__ b2,
    const float* __restrict__ g, const float* __restrict__ bta)
{
    __shared__ __align__(16) unsigned short abuf[2*64*SK];   // a1 | a2; later x fp32 (stride 132)
    __shared__ float ps[64][4], pq[64][4];
    __shared__ float mu_s[64], rs_s[64];
    int tid = threadIdx.x;
    int tile0 = blockIdx.x*64;
    unsigned short* a1 = abuf;
    unsigned short* a2 = abuf + 64*SK;

    {
        int r = tid >> 2, dq = tid & 3;
        int node = tile0 + r;
        bool valid = node < NV;
        const float4* hrow = (const float4*)(h   + (size_t)node*NH + dq*32);
        const float4* arow = (const float4*)(agg + (size_t)node*NH + dq*32);
        #pragma unroll
        for (int c = 0; c < 4; c++){
            float4 v0 = valid ? hrow[c*2]     : make_float4(0.f,0.f,0.f,0.f);
            float4 v1 = valid ? hrow[c*2 + 1] : make_float4(0.f,0.f,0.f,0.f);
            float4 u0 = valid ? arow[c*2]     : make_float4(0.f,0.f,0.f,0.f);
            float4 u1 = valid ? arow[c*2 + 1] : make_float4(0.f,0.f,0.f,0.f);
            uint4 o;
            o.x = f2bf_pk(v0.x, v0.y); o.y = f2bf_pk(v0.z, v0.w);
            o.z = f2bf_pk(v1.x, v1.y); o.w = f2bf_pk(v1.z, v1.w);
            *(uint4*)&a1[r*SK + dq*32 + c*8] = o;
            uint4 p;
            p.x = f2bf_pk(u0.x, u0.y); p.y = f2bf_pk(u0.z, u0.w);
            p.z = f2bf_pk(u1.x, u1.y); p.w = f2bf_pk(u1.z, u1.w);
            *(uint4*)&a2[r*SK + dq*32 + c*8] = p;
        }
    }

    int w = tid >> 6, l = tid & 63;
    int lr = l & 15, lq = l >> 4;
    int colb = w*32;

    __syncthreads();

    f32x4 acc[4][2];
    #pragma unroll
    for (int mt = 0; mt < 4; mt++)
        #pragma unroll
        for (int nt = 0; nt < 2; nt++) acc[mt][nt] = (f32x4){0.f,0.f,0.f,0.f};

    {
        short8 bfr[2][4];
        #pragma unroll
        for (int nt = 0; nt < 2; nt++)
            #pragma unroll
            for (int kc = 0; kc < 4; kc++)
                bfr[nt][kc] = *(const short8*)(wn + (colb + nt*16 + lr)*128 + kc*32 + lq*8);
        #pragma unroll
        for (int kc = 0; kc < 4; kc++)
            #pragma unroll
            for (int mt = 0; mt < 4; mt++){
                short8 af = *(const short8*)&a1[(mt*16 + lr)*SK + kc*32 + lq*8];
                #pragma unroll
                for (int nt = 0; nt < 2; nt++)
                    acc[mt][nt] = __builtin_amdgcn_mfma_f32_16x16x32_bf16(af, bfr[nt][kc], acc[mt][nt], 0, 0, 0);
            }
    }
    {
        short8 bfr[2][4];
        #pragma unroll
        for (int nt = 0; nt < 2; nt++)
            #pragma unroll
            for (int kc = 0; kc < 4; kc++)
                bfr[nt][kc] = *(const short8*)(wn + 16384 + (colb + nt*16 + lr)*128 + kc*32 + lq*8);
        #pragma unroll
        for (int kc = 0; kc < 4; kc++)
            #pragma unroll
            for (int mt = 0; mt < 4; mt++){
                short8 af = *(const short8*)&a2[(mt*16 + lr)*SK + kc*32 + lq*8];
                #pragma unroll
                for (int nt = 0; nt < 2; nt++)
                    acc[mt][nt] = __builtin_amdgcn_mfma_f32_16x16x32_bf16(af, bfr[nt][kc], acc[mt][nt], 0, 0, 0);
            }
    }
    __syncthreads();

    #pragma unroll
    for (int nt = 0; nt < 2; nt++){
        int col = colb + nt*16 + lr;
        float bv = b1[col];
        #pragma unroll
        for (int mt = 0; mt < 4; mt++)
            #pragma unroll
            for (int r = 0; r < 4; r++){
                int row = mt*16 + lq*4 + r;
                a1[row*SK + col] = f2bf(silu_f(acc[mt][nt][r] + bv));
            }
    }
    __syncthreads();

    f32x4 acc2[4][2];
    #pragma unroll
    for (int mt = 0; mt < 4; mt++)
        #pragma unroll
        for (int nt = 0; nt < 2; nt++) acc2[mt][nt] = (f32x4){0.f,0.f,0.f,0.f};
    {
        short8 bfr[2][4];
        #pragma unroll
        for (int nt = 0; nt < 2; nt++)
            #pragma unroll
            for (int kc = 0; kc < 4; kc++)
                bfr[nt][kc] = *(const short8*)(wn + 2*16384 + (colb + nt*16 + lr)*128 + kc*32 + lq*8);
        #pragma unroll
        for (int kc = 0; kc < 4; kc++)
            #pragma unroll
            for (int mt = 0; mt < 4; mt++){
                short8 af = *(const short8*)&a1[(mt*16 + lr)*SK + kc*32 + lq*8];
                #pragma unroll
                for (int nt = 0; nt < 2; nt++)
                    acc2[mt][nt] = __builtin_amdgcn_mfma_f32_16x16x32_bf16(af, bfr[nt][kc], acc2[mt][nt], 0, 0, 0);
            }
    }
    __syncthreads();

    float* xls = (float*)abuf;
    #pragma unroll
    for (int nt = 0; nt < 2; nt++){
        int col = colb + nt*16 + lr;
        float bv = b2[col];
        #pragma unroll
        for (int mt = 0; mt < 4; mt++)
            #pragma unroll
            for (int r = 0; r < 4; r++){
                int row = mt*16 + lq*4 + r;
                int node = tile0 + row;
                float hv = (node < NV) ? h[(size_t)node*NH + col] : 0.f;
                xls[row*132 + col] = hv + acc2[mt][nt][r] + bv;
            }
    }
    __syncthreads();

    {
        int r = tid >> 2, part = tid & 3;
        float s = 0.f, q = 0.f;
        #pragma unroll 8
        for (int i = 0; i < 32; i++){
            float x = xls[r*132 + part*32 + i];
            s += x; q += x*x;
        }
        ps[r][part] = s; pq[r][part] = q;
    }
    __syncthreads();
    if (tid < 64){
        float s = ps[tid][0] + ps[tid][1] + ps[tid][2] + ps[tid][3];
        float q = pq[tid][0] + pq[tid][1] + pq[tid][2] + pq[tid][3];
        float mu = s * (1.f/128.f);
        float var = q * (1.f/128.f) - mu*mu;
        mu_s[tid] = mu;
        rs_s[tid] = rsqrtf(var + 1e-5f);
    }
    __syncthreads();
    {
        int r = tid >> 2, part = tid & 3;
        int node = tile0 + r;
        if (node < NV){
            float mu = mu_s[r], rs = rs_s[r];
            #pragma unroll
            for (int c = 0; c < 8; c++){
                int d = part*32 + c*4;
                float4 o;
                o.x = g[d+0]*(xls[r*132 + d+0] - mu)*rs + bta[d+0];
                o.y = g[d+1]*(xls[r*132 + d+1] - mu)*rs + bta[d+1];
                o.z = g[d+2]*(xls[r*132 + d+2] - mu)*rs + bta[d+2];
                o.w = g[d+3]*(xls[r*132 + d+3] - mu)*rs + bta[d+3];
                *(float4*)(h + (size_t)node*NH + d) = o;
            }
        }
    }
}

// ---------------- output projection + MSE ----------------
__global__ __launch_bounds__(256) void k_out(const float* __restrict__ h,
                                             const float* __restrict__ opw, const float* __restrict__ opb,
                                             const float* __restrict__ pos0, const float* __restrict__ pos1,
                                             float* __restrict__ out)
{
    int v = blockIdx.x*256 + threadIdx.x;
    float sse = 0.f;
    if (v < NV){
        float v0 = opb[0], v1 = opb[1], v2 = opb[2];
        const float* hr = h + (size_t)v*NH;
        for (int k = 0; k < 128; k += 4){
            float4 hv = *(const float4*)(hr + k);
            v0 += hv.x*opw[(k+0)*3+0] + hv.y*opw[(k+1)*3+0] + hv.z*opw[(k+2)*3+0] + hv.w*opw[(k+3)*3+0];
            v1 += hv.x*opw[(k+0)*3+1] + hv.y*opw[(k+1)*3+1] + hv.z*opw[(k+2)*3+1] + hv.w*opw[(k+3)*3+1];
            v2 += hv.x*opw[(k+0)*3+2] + hv.y*opw[(k+1)*3+2] + hv.z*opw[(k+2)*3+2] + hv.w*opw[(k+3)*3+2];
        }
        float d0 = v0 - (pos1[v*3+0] - pos0[v*3+0]);
        float d1 = v1 - (pos1[v*3+1] - pos0[v*3+1]);
        float d2 = v2 - (pos1[v*3+2] - pos0[v*3+2]);
        sse = d0*d0 + d1*d1 + d2*d2;
    }
    for (int off = 32; off > 0; off >>= 1) sse += __shfl_down(sse, off, 64);
    __shared__ float red[4];
    if ((threadIdx.x & 63) == 0) red[threadIdx.x >> 6] = sse;
    __syncthreads();
    if (threadIdx.x == 0){
        float tot = red[0] + red[1] + red[2] + red[3];
        atomicAdd(out, tot * (1.0f/150000.0f));
    }
}

extern "C" void kernel_launch(void* const* d_in, const int* in_sizes, int n_in,
                              void* d_out, int out_size, void* d_ws, size_t ws_size,
                              hipStream_t stream)
{
    const float* pos0  = (const float*)d_in[0];
    const float* pos1  = (const float*)d_in[1];
    const float* z     = (const float*)d_in[2];
    const float* t     = (const float*)d_in[3];
    const int*   ei    = (const int*)d_in[4];
    const int*   batch = (const int*)d_in[5];
    const float* te_w1 = (const float*)d_in[6];
    const float* te_b1 = (const float*)d_in[7];
    const float* te_w2 = (const float*)d_in[8];
    const float* te_b2 = (const float*)d_in[9];
    const float* cp_w  = (const float*)d_in[10];
    const float* cp_b  = (const float*)d_in[11];
    const float* ew1   = (const float*)d_in[12];
    const float* eb1   = (const float*)d_in[13];
    const float* ew2   = (const float*)d_in[14];
    const float* eb2   = (const float*)d_in[15];
    const float* nw1   = (const float*)d_in[16];
    const float* nb1   = (const float*)d_in[17];
    const float* nw2   = (const float*)d_in[18];
    const float* nb2   = (const float*)d_in[19];
    const float* ln_g  = (const float*)d_in[20];
    const float* ln_b  = (const float*)d_in[21];
    const float* op_w  = (const float*)d_in[22];
    const float* op_b  = (const float*)d_in[23];

    float* ws     = (float*)d_ws;
    float* tconst = ws;                        // 128
    float* zcp    = ws + 128;                  // 1024
    float* xt     = ws + 1152;                 // 150016 (NV*3 padded)
    float* h      = ws + 151168;               // NV*NH fp32
    float* agg    = h + (size_t)NV*NH;         // NV*NH fp32
    int*   ibase  = (int*)(agg + (size_t)NV*NH);
    int*   rowptr  = ibase;                    // 50016
    int*   cursor  = ibase + 50016;            // 50016
    int*   csr_eid = ibase + 100032;           // NE
    int*   csr_dst = csr_eid + NE;             // NE
    unsigned short* pre_di = (unsigned short*)(csr_dst + NE);   // NV*NH bf16
    unsigned short* pre_sj = pre_di + (size_t)NV*NH;            // NV*NH bf16
    unsigned short* wpk    = pre_sj + (size_t)NV*NH;            // 4*6*16384 bf16
    int*   bsum   = (int*)(wpk + 4*6*16384);                    // 256 ints

    const int* srcrow = ei;        // edge_index[0] = src j
    const int* dstrow = ei + NE;   // edge_index[1] = dst i

    hipMemsetAsync(cursor, 0, (size_t)NV*4, stream);
    k_setup<<<1, 128, 0, stream>>>(z, t, te_w1, te_b1, te_w2, te_b2, cp_w, cp_b, tconst, zcp);
    k_init<<<(NV*NH)/256, 256, 0, stream>>>(batch, zcp, tconst, h);
    k_xt<<<(NV*3 + 255)/256, 256, 0, stream>>>(pos0, pos1, t, xt);
    k_hist<<<NE/256, 256, 0, stream>>>(dstrow, cursor);
    k_scan1<<<196, 256, 0, stream>>>(cursor, bsum);
    k_scan2<<<1, 256, 0, stream>>>(bsum);
    k_scan3<<<196, 256, 0, stream>>>(cursor, bsum, rowptr, cursor);
    k_scatter<<<NE/256, 256, 0, stream>>>(dstrow, cursor, csr_eid, csr_dst);
    k_pack_wpk<<<(4*6*16384)/256, 256, 0, stream>>>(ew1, ew2, nw1, nw2, wpk);

    for (int l = 0; l < NL; l++){
        const float* ew1l = ew1 + (size_t)l*259*128;
        const unsigned short* wpk_l = wpk + (size_t)l*6*16384;
        k_pre_mfma<<<dim3((NV + 63)/64, 2), 256, 0, stream>>>(h, xt, wpk_l,
                                                              ew1l + 256*128, eb1 + l*128,
                                                              pre_di, pre_sj);
        hipMemsetAsync(agg, 0, (size_t)NV*NH*4, stream);
        k_edge_mfma<<<NE/64, 256, 0, stream>>>(pre_di, pre_sj, csr_eid, csr_dst, srcrow, rowptr,
                                               wpk_l + 2*16384, eb2 + l*128, agg);
        k_node_mfma<<<(NV + 63)/64, 256, 0, stream>>>(h, agg, wpk_l + 3*16384,
                                                      nb1 + l*128, nb2 + l*128,
                                                      ln_g + l*128, ln_b + l*128);
    }

    hipMemsetAsync(d_out, 0, 4, stream);
    k_out<<<(NV + 255)/256, 256, 0, stream>>>(h, op_w, op_b, pos0, pos1, (float*)d_out);
}

// Round 7
// 1024.456 us; speedup vs baseline: 5.7171x; 1.0482x over previous
//
#include <hip/hip_runtime.h>

#define NV 50000
#define NE 800000
#define NB 8
#define NH 128
#define NLAT 64
#define NTD 16
#define NL 4
#define SK 136   // LDS row stride (bf16 elems) for MFMA A tiles
#define MT2 132  // LDS stride (bf16 elems) for transposed m tile: m_t[d][row], row 0..127

typedef __attribute__((ext_vector_type(8))) short short8;
typedef __attribute__((ext_vector_type(4))) float f32x4;

__device__ __forceinline__ float silu_f(float x){
    float e = __expf(-x);
    return x * __builtin_amdgcn_rcpf(1.0f + e);
}

__device__ __forceinline__ unsigned short f2bf(float x){
    unsigned u = __float_as_uint(x);
    unsigned r = (u >> 16) & 1;
    u += 0x7fffu + r;
    return (unsigned short)(u >> 16);
}
__device__ __forceinline__ unsigned f2bf_pk(float a, float b){
    return (unsigned)f2bf(a) | ((unsigned)f2bf(b) << 16);
}
__device__ __forceinline__ float bflo(unsigned u){ return __uint_as_float(u << 16); }
__device__ __forceinline__ float bfhi(unsigned u){ return __uint_as_float(u & 0xffff0000u); }

// ---------------- setup ----------------
__global__ void k_setup(const float* __restrict__ z, const float* __restrict__ t,
                        const float* __restrict__ te_w1, const float* __restrict__ te_b1,
                        const float* __restrict__ te_w2, const float* __restrict__ te_b2,
                        const float* __restrict__ cp_w, const float* __restrict__ cp_b,
                        float* __restrict__ tconst, float* __restrict__ zcp)
{
    __shared__ float hid[NTD];
    __shared__ float emb[NTD];
    int tid = threadIdx.x;
    float ts = t[0];
    if (tid < NTD) hid[tid] = silu_f(ts * te_w1[tid] + te_b1[tid]);
    __syncthreads();
    if (tid < NTD){
        float a = te_b2[tid];
        for (int j = 0; j < NTD; j++) a += hid[j] * te_w2[j*NTD + tid];
        emb[tid] = a;
    }
    __syncthreads();
    float tc = cp_b[tid];
    for (int j = 0; j < NTD; j++) tc += emb[j] * cp_w[(NLAT + j)*NH + tid];
    tconst[tid] = tc;
    for (int b = 0; b < NB; b++){
        float a = 0.f;
        for (int k = 0; k < NLAT; k++) a += z[b*NLAT + k] * cp_w[k*NH + tid];
        zcp[b*NH + tid] = a;
    }
}

__global__ void k_init(const int* __restrict__ batch, const float* __restrict__ zcp,
                       const float* __restrict__ tconst, float* __restrict__ h)
{
    int idx = blockIdx.x*256 + threadIdx.x;
    int v = idx >> 7, d = idx & 127;
    h[idx] = zcp[batch[v]*NH + d] + tconst[d];
}

__global__ void k_xt(const float* __restrict__ pos0, const float* __restrict__ pos1,
                     const float* __restrict__ t, float* __restrict__ xt)
{
    int idx = blockIdx.x*256 + threadIdx.x;
    if (idx < NV*3){
        float ts = t[0];
        xt[idx] = (1.f - ts)*pos0[idx] + ts*pos1[idx];
    }
}

// ---------------- CSR build ----------------
__global__ void k_hist(const int* __restrict__ dst, int* __restrict__ cnt)
{
    int e = blockIdx.x*256 + threadIdx.x;
    if (e < NE) atomicAdd(&cnt[dst[e]], 1);
}

__global__ void k_scan1(const int* __restrict__ deg, int* __restrict__ bsum)
{
    __shared__ int s[256];
    int tid = threadIdx.x;
    int idx = blockIdx.x*256 + tid;
    s[tid] = (idx < NV) ? deg[idx] : 0;
    __syncthreads();
    for (int off = 128; off > 0; off >>= 1){
        if (tid < off) s[tid] += s[tid + off];
        __syncthreads();
    }
    if (tid == 0) bsum[blockIdx.x] = s[0];
}

__global__ void k_scan2(int* __restrict__ bsum)
{
    __shared__ int s[256];
    int tid = threadIdx.x;
    int v = (tid < 196) ? bsum[tid] : 0;
    s[tid] = v;
    __syncthreads();
    for (int off = 1; off < 256; off <<= 1){
        int a = s[tid];
        int b = (tid >= off) ? s[tid - off] : 0;
        __syncthreads();
        s[tid] = a + b;
        __syncthreads();
    }
    if (tid < 196) bsum[tid] = (tid == 0) ? 0 : s[tid - 1];
}

__global__ void k_scan3(const int* deg, const int* __restrict__ bsum,
                        int* __restrict__ rowptr, int* cursor)
{
    __shared__ int s[256];
    int tid = threadIdx.x;
    int idx = blockIdx.x*256 + tid;
    int v = (idx < NV) ? deg[idx] : 0;
    s[tid] = v;
    __syncthreads();
    for (int off = 1; off < 256; off <<= 1){
        int a = s[tid];
        int b = (tid >= off) ? s[tid - off] : 0;
        __syncthreads();
        s[tid] = a + b;
        __syncthreads();
    }
    int excl = bsum[blockIdx.x] + ((tid == 0) ? 0 : s[tid - 1]);
    if (idx < NV){
        rowptr[idx] = excl;
        cursor[idx] = excl;
    }
    if (idx == NV - 1) rowptr[NV] = NE;
}

__global__ void k_scatter(const int* __restrict__ dst, int* __restrict__ cursor,
                          int* __restrict__ csr_eid, int* __restrict__ csr_dst)
{
    int e = blockIdx.x*256 + threadIdx.x;
    if (e < NE){
        int i = dst[e];
        int p = atomicAdd(&cursor[i], 1);
        csr_eid[p] = e;
        csr_dst[p] = i;
    }
}

// ---------------- pack weights -> bf16 [l][{eWd,eWs,eW2,nW1d,nW1a,nW2}][n][k] ----------------
__global__ void k_pack_wpk(const float* __restrict__ ew1, const float* __restrict__ ew2,
                           const float* __restrict__ nw1, const float* __restrict__ nw2,
                           unsigned short* __restrict__ wpk)
{
    int idx = blockIdx.x*256 + threadIdx.x;
    int lm = idx >> 14;
    int l = lm / 6, m = lm % 6;
    int r = idx & 16383;
    int n = r >> 7, k = r & 127;
    float v;
    if (m < 2)       v = ew1[l*33152 + (m*128 + k)*128 + n];
    else if (m == 2) v = ew2[l*16384 + k*128 + n];
    else if (m < 5)  v = nw1[l*32768 + ((m-3)*128 + k)*128 + n];
    else             v = nw2[l*16384 + k*128 + n];
    wpk[idx] = f2bf(v);
}

// ---------------- pre-projection (MFMA, both branches fused, bf16 out) ----------------
// pre_di[v] = bf16( h[v]@Wd + xt[v]@W1c + b1 );  pre_sj[v] = bf16( h[v]@Ws - xt[v]@W1c )
__global__ __launch_bounds__(256) void k_pre_mfma(
    const float* __restrict__ h, const float* __restrict__ xt,
    const unsigned short* __restrict__ wpk_l,   // Wd at +0, Ws at +16384
    const float* __restrict__ w1c, const float* __restrict__ b1,
    unsigned short* __restrict__ pre_di, unsigned short* __restrict__ pre_sj)
{
    __shared__ __align__(16) unsigned short asd[64*SK];    // A tile; reused as d-output tile
    __shared__ __align__(16) unsigned short obuf[64*SK];   // s-output tile
    __shared__ float xts[64*4];
    int tid = threadIdx.x;
    int tile0 = blockIdx.x*64;

    {
        int r = tid >> 2, dq = tid & 3;
        int node = tile0 + r;
        bool valid = node < NV;
        const float4* hrow = (const float4*)(h + (size_t)node*NH + dq*32);
        #pragma unroll
        for (int c = 0; c < 4; c++){
            float4 v0 = valid ? hrow[c*2]     : make_float4(0.f,0.f,0.f,0.f);
            float4 v1 = valid ? hrow[c*2 + 1] : make_float4(0.f,0.f,0.f,0.f);
            uint4 o;
            o.x = f2bf_pk(v0.x, v0.y);
            o.y = f2bf_pk(v0.z, v0.w);
            o.z = f2bf_pk(v1.x, v1.y);
            o.w = f2bf_pk(v1.z, v1.w);
            *(uint4*)&asd[r*SK + dq*32 + c*8] = o;
        }
    }
    if (tid < 64){
        int node = tile0 + tid;
        bool valid = node < NV;
        xts[tid*4+0] = valid ? xt[node*3+0] : 0.f;
        xts[tid*4+1] = valid ? xt[node*3+1] : 0.f;
        xts[tid*4+2] = valid ? xt[node*3+2] : 0.f;
        xts[tid*4+3] = 0.f;
    }

    int w = tid >> 6, l = tid & 63;
    int lr = l & 15, lq = l >> 4;

    f32x4 accd[4][2], accs[4][2];
    #pragma unroll
    for (int mt = 0; mt < 4; mt++)
        #pragma unroll
        for (int nt = 0; nt < 2; nt++){
            accd[mt][nt] = (f32x4){0.f,0.f,0.f,0.f};
            accs[mt][nt] = (f32x4){0.f,0.f,0.f,0.f};
        }

    // branch-d B frags
    short8 bfr[2][4];
    #pragma unroll
    for (int nt = 0; nt < 2; nt++)
        #pragma unroll
        for (int kc = 0; kc < 4; kc++)
            bfr[nt][kc] = *(const short8*)(wpk_l + (w*32 + nt*16 + lr)*128 + kc*32 + lq*8);

    __syncthreads();

    #pragma unroll
    for (int kc = 0; kc < 4; kc++)
        #pragma unroll
        for (int mt = 0; mt < 4; mt++){
            short8 af = *(const short8*)&asd[(mt*16 + lr)*SK + kc*32 + lq*8];
            #pragma unroll
            for (int nt = 0; nt < 2; nt++)
                accd[mt][nt] = __builtin_amdgcn_mfma_f32_16x16x32_bf16(af, bfr[nt][kc], accd[mt][nt], 0, 0, 0);
        }

    // branch-s B frags
    #pragma unroll
    for (int nt = 0; nt < 2; nt++)
        #pragma unroll
        for (int kc = 0; kc < 4; kc++)
            bfr[nt][kc] = *(const short8*)(wpk_l + 16384 + (w*32 + nt*16 + lr)*128 + kc*32 + lq*8);

    #pragma unroll
    for (int kc = 0; kc < 4; kc++)
        #pragma unroll
        for (int mt = 0; mt < 4; mt++){
            short8 af = *(const short8*)&asd[(mt*16 + lr)*SK + kc*32 + lq*8];
            #pragma unroll
            for (int nt = 0; nt < 2; nt++)
                accs[mt][nt] = __builtin_amdgcn_mfma_f32_16x16x32_bf16(af, bfr[nt][kc], accs[mt][nt], 0, 0, 0);
        }
    __syncthreads();   // done reading A tile

    // epilogues: d -> asd, s -> obuf
    #pragma unroll
    for (int nt = 0; nt < 2; nt++){
        int col = w*32 + nt*16 + lr;
        float c0 = w1c[col], c1 = w1c[128 + col], c2 = w1c[256 + col];
        float bb = b1[col];
        #pragma unroll
        for (int mt = 0; mt < 4; mt++){
            #pragma unroll
            for (int r = 0; r < 4; r++){
                int row = mt*16 + lq*4 + r;
                float qv = xts[row*4+0]*c0 + xts[row*4+1]*c1 + xts[row*4+2]*c2;
                asd [row*SK + col] = f2bf(accd[mt][nt][r] + qv + bb);
                obuf[row*SK + col] = f2bf(accs[mt][nt][r] - qv);
            }
        }
    }
    __syncthreads();

    // coalesced stores
    {
        int r = tid >> 2, dq = tid & 3;
        int node = tile0 + r;
        if (node < NV){
            #pragma unroll
            for (int c = 0; c < 4; c++){
                uint4 vd = *(const uint4*)&asd [r*SK + dq*32 + c*8];
                uint4 vs = *(const uint4*)&obuf[r*SK + dq*32 + c*8];
                *(uint4*)(pre_di + (size_t)node*NH + dq*32 + c*8) = vd;
                *(uint4*)(pre_sj + (size_t)node*NH + dq*32 + c*8) = vs;
            }
        }
    }
}

// ---------------- fused edge kernel: 128-edge tiles, XCD swizzle ----------------
__global__ __launch_bounds__(256) void k_edge_mfma(
    const unsigned short* __restrict__ pre_di, const unsigned short* __restrict__ pre_sj,
    const int* __restrict__ csr_eid, const int* __restrict__ csr_dst,
    const int* __restrict__ srcrow, const int* __restrict__ rowptr,
    const unsigned short* __restrict__ w2t,   // [n][k] bf16
    const float* __restrict__ b2,
    float* __restrict__ agg)
{
    __shared__ __align__(16) unsigned short hids[128*SK];   // 34.8 KB; reused as transposed m tile
    __shared__ int nid[128];
    __shared__ int flagL, flagR;
    __shared__ unsigned long long brk0_s, brk1_s;
    int tid = threadIdx.x;

    // XCD-aware swizzle: each XCD (b%8) gets a contiguous 1/8 of the edge stream
    int b = blockIdx.x;                 // 6250 blocks
    int mapped = (b < 6248) ? ((b & 7)*781 + (b >> 3)) : b;
    int p0 = mapped * 128;

    if (tid == 0){
        flagL = (rowptr[csr_dst[p0]] < p0) ? 1 : 0;
        flagR = (rowptr[csr_dst[p0 + 127] + 1] > p0 + 128) ? 1 : 0;
    }

    // hid phase: 2 sub-tiles of 64 edges; 4 threads/edge, 32 dims each
    #pragma unroll
    for (int sub = 0; sub < 2; sub++){
        int el = sub*64 + (tid >> 2), q = tid & 3;
        int p = p0 + el;
        int eid = csr_eid[p];
        int iN  = csr_dst[p];
        int jN  = srcrow[eid];
        if (q == 0) nid[el] = iN;
        const uint4* gd = (const uint4*)(pre_di + (size_t)iN*NH + q*32);
        const uint4* gs = (const uint4*)(pre_sj + (size_t)jN*NH + q*32);
        #pragma unroll
        for (int c = 0; c < 4; c++){
            uint4 a = gd[c], bb = gs[c];
            unsigned au[4] = {a.x, a.y, a.z, a.w};
            unsigned bu[4] = {bb.x, bb.y, bb.z, bb.w};
            unsigned ov[4];
            #pragma unroll
            for (int g = 0; g < 4; g++){
                float lo = silu_f(bflo(au[g]) + bflo(bu[g]));
                float hi = silu_f(bfhi(au[g]) + bfhi(bu[g]));
                ov[g] = f2bf_pk(lo, hi);
            }
            uint4 o; o.x = ov[0]; o.y = ov[1]; o.z = ov[2]; o.w = ov[3];
            *(uint4*)&hids[el*SK + q*32 + c*8] = o;
        }
    }

    int w = tid >> 6, l = tid & 63;
    int lr = l & 15, lq = l >> 4;
    short8 bfr[2][4];
    #pragma unroll
    for (int nt = 0; nt < 2; nt++)
        #pragma unroll
        for (int kc = 0; kc < 4; kc++)
            bfr[nt][kc] = *(const short8*)(w2t + (w*32 + nt*16 + lr)*128 + kc*32 + lq*8);

    __syncthreads();

    // segment-boundary bitmasks (wave 0: rows 0..63; wave 1: rows 64..127)
    if (tid < 64){
        bool bb = (tid > 0) && (nid[tid] != nid[tid - 1]);
        unsigned long long mask = __ballot(bb);
        if (tid == 0) brk0_s = mask;
    } else if (tid < 128){
        int lane = tid - 64;
        bool bb = (nid[64 + lane] != nid[63 + lane]);
        unsigned long long mask = __ballot(bb);
        if (lane == 0) brk1_s = mask;
    }

    f32x4 acc[8][2];
    #pragma unroll
    for (int mt = 0; mt < 8; mt++)
        #pragma unroll
        for (int nt = 0; nt < 2; nt++) acc[mt][nt] = (f32x4){0.f,0.f,0.f,0.f};
    #pragma unroll
    for (int kc = 0; kc < 4; kc++){
        #pragma unroll
        for (int mt = 0; mt < 8; mt++){
            short8 af = *(const short8*)&hids[(mt*16 + lr)*SK + kc*32 + lq*8];
            #pragma unroll
            for (int nt = 0; nt < 2; nt++)
                acc[mt][nt] = __builtin_amdgcn_mfma_f32_16x16x32_bf16(af, bfr[nt][kc], acc[mt][nt], 0, 0, 0);
        }
    }
    __syncthreads();   // hids consumed (and masks written) -> reuse as m_t

    // epilogue: m = silu(acc + b2) -> transposed bf16 m_t[d][row], stride MT2
    unsigned short* m_t = hids;    // 128 * MT2 * 2B = 33792 B
    #pragma unroll
    for (int nt = 0; nt < 2; nt++){
        int col = w*32 + nt*16 + lr;
        float bv = b2[col];
        #pragma unroll
        for (int mt = 0; mt < 8; mt++){
            float v0 = silu_f(acc[mt][nt][0] + bv);
            float v1 = silu_f(acc[mt][nt][1] + bv);
            float v2 = silu_f(acc[mt][nt][2] + bv);
            float v3 = silu_f(acc[mt][nt][3] + bv);
            uint2 pk;
            pk.x = f2bf_pk(v0, v1);
            pk.y = f2bf_pk(v2, v3);
            *(uint2*)&m_t[col*MT2 + mt*16 + lq*4] = pk;
        }
    }
    __syncthreads();

    // segmented row-sum: 2 halves x 128 dims; each walks 64 rows
    {
        int half = tid >> 7, d = tid & 127;
        int r0 = half * 64;
        bool junc = !((brk1_s) & 1ull);             // run continues across row 63->64
        unsigned long long m2 = half ? (brk1_s & ~1ull) : brk0_s;
        bool leftCont  = half ? junc : (flagL != 0);
        bool rightCont = half ? (flagR != 0) : junc;

        float run = 0.f;
        int curn = nid[r0];
        bool firstRun = true;
        const unsigned short* mrow = m_t + d*MT2;

        #pragma unroll
        for (int g = 0; g < 16; g++){
            int row = r0 + g*4;
            uint2 v = *(const uint2*)&mrow[row];
            float f0 = bflo(v.x), f1 = bfhi(v.x);
            float f2 = bflo(v.y), f3 = bfhi(v.y);
            unsigned gm = (unsigned)((m2 >> (g*4 + (half ? 0 : 0))) & 0xFull);
            // note: mask bit index is relative to half start
            if (gm == 0u){
                run += (f0 + f1) + (f2 + f3);
            } else {
                float fv[4] = {f0, f1, f2, f3};
                #pragma unroll
                for (int r = 0; r < 4; r++){
                    if (gm & (1u << r)){
                        bool at = firstRun && leftCont;
                        if (at) atomicAdd(&agg[(size_t)curn*NH + d], run);
                        else    agg[(size_t)curn*NH + d] = run;
                        firstRun = false;
                        run = 0.f;
                        curn = nid[row + r];
                    }
                    run += fv[r];
                }
            }
        }
        bool at = (firstRun && leftCont) || rightCont;
        if (at) atomicAdd(&agg[(size_t)curn*NH + d], run);
        else    agg[(size_t)curn*NH + d] = run;
    }
}

// ---------------- node kernel (MFMA): h = LN(h + MLP([h|agg])) * g + b ----------------
__global__ __launch_bounds__(256) void k_node_mfma(
    float* __restrict__ h, const float* __restrict__ agg,
    const unsigned short* __restrict__ wn,   // [3][128][128] bf16: W1d, W1a, W2
    const float* __restrict__ b1, const float* __restrict__ b2,
    const float* __restrict__ g, const float* __restrict__ bta)
{
    __shared__ __align__(16) unsigned short abuf[2*64*SK];
    __shared__ float ps[64][4], pq[64][4];
    __shared__ float mu_s[64], rs_s[64];
    int tid = threadIdx.x;
    int tile0 = blockIdx.x*64;
    unsigned short* a1 = abuf;
    unsigned short* a2 = abuf + 64*SK;

    {
        int r = tid >> 2, dq = tid & 3;
        int node = tile0 + r;
        bool valid = node < NV;
        const float4* hrow = (const float4*)(h   + (size_t)node*NH + dq*32);
        const float4* arow = (const float4*)(agg + (size_t)node*NH + dq*32);
        #pragma unroll
        for (int c = 0; c < 4; c++){
            float4 v0 = valid ? hrow[c*2]     : make_float4(0.f,0.f,0.f,0.f);
            float4 v1 = valid ? hrow[c*2 + 1] : make_float4(0.f,0.f,0.f,0.f);
            float4 u0 = valid ? arow[c*2]     : make_float4(0.f,0.f,0.f,0.f);
            float4 u1 = valid ? arow[c*2 + 1] : make_float4(0.f,0.f,0.f,0.f);
            uint4 o;
            o.x = f2bf_pk(v0.x, v0.y); o.y = f2bf_pk(v0.z, v0.w);
            o.z = f2bf_pk(v1.x, v1.y); o.w = f2bf_pk(v1.z, v1.w);
            *(uint4*)&a1[r*SK + dq*32 + c*8] = o;
            uint4 p;
            p.x = f2bf_pk(u0.x, u0.y); p.y = f2bf_pk(u0.z, u0.w);
            p.z = f2bf_pk(u1.x, u1.y); p.w = f2bf_pk(u1.z, u1.w);
            *(uint4*)&a2[r*SK + dq*32 + c*8] = p;
        }
    }

    int w = tid >> 6, l = tid & 63;
    int lr = l & 15, lq = l >> 4;
    int colb = w*32;

    __syncthreads();

    f32x4 acc[4][2];
    #pragma unroll
    for (int mt = 0; mt < 4; mt++)
        #pragma unroll
        for (int nt = 0; nt < 2; nt++) acc[mt][nt] = (f32x4){0.f,0.f,0.f,0.f};

    {
        short8 bfr[2][4];
        #pragma unroll
        for (int nt = 0; nt < 2; nt++)
            #pragma unroll
            for (int kc = 0; kc < 4; kc++)
                bfr[nt][kc] = *(const short8*)(wn + (colb + nt*16 + lr)*128 + kc*32 + lq*8);
        #pragma unroll
        for (int kc = 0; kc < 4; kc++)
            #pragma unroll
            for (int mt = 0; mt < 4; mt++){
                short8 af = *(const short8*)&a1[(mt*16 + lr)*SK + kc*32 + lq*8];
                #pragma unroll
                for (int nt = 0; nt < 2; nt++)
                    acc[mt][nt] = __builtin_amdgcn_mfma_f32_16x16x32_bf16(af, bfr[nt][kc], acc[mt][nt], 0, 0, 0);
            }
    }
    {
        short8 bfr[2][4];
        #pragma unroll
        for (int nt = 0; nt < 2; nt++)
            #pragma unroll
            for (int kc = 0; kc < 4; kc++)
                bfr[nt][kc] = *(const short8*)(wn + 16384 + (colb + nt*16 + lr)*128 + kc*32 + lq*8);
        #pragma unroll
        for (int kc = 0; kc < 4; kc++)
            #pragma unroll
            for (int mt = 0; mt < 4; mt++){
                short8 af = *(const short8*)&a2[(mt*16 + lr)*SK + kc*32 + lq*8];
                #pragma unroll
                for (int nt = 0; nt < 2; nt++)
                    acc[mt][nt] = __builtin_amdgcn_mfma_f32_16x16x32_bf16(af, bfr[nt][kc], acc[mt][nt], 0, 0, 0);
            }
    }
    __syncthreads();

    #pragma unroll
    for (int nt = 0; nt < 2; nt++){
        int col = colb + nt*16 + lr;
        float bv = b1[col];
        #pragma unroll
        for (int mt = 0; mt < 4; mt++)
            #pragma unroll
            for (int r = 0; r < 4; r++){
                int row = mt*16 + lq*4 + r;
                a1[row*SK + col] = f2bf(silu_f(acc[mt][nt][r] + bv));
            }
    }
    __syncthreads();

    f32x4 acc2[4][2];
    #pragma unroll
    for (int mt = 0; mt < 4; mt++)
        #pragma unroll
        for (int nt = 0; nt < 2; nt++) acc2[mt][nt] = (f32x4){0.f,0.f,0.f,0.f};
    {
        short8 bfr[2][4];
        #pragma unroll
        for (int nt = 0; nt < 2; nt++)
            #pragma unroll
            for (int kc = 0; kc < 4; kc++)
                bfr[nt][kc] = *(const short8*)(wn + 2*16384 + (colb + nt*16 + lr)*128 + kc*32 + lq*8);
        #pragma unroll
        for (int kc = 0; kc < 4; kc++)
            #pragma unroll
            for (int mt = 0; mt < 4; mt++){
                short8 af = *(const short8*)&a1[(mt*16 + lr)*SK + kc*32 + lq*8];
                #pragma unroll
                for (int nt = 0; nt < 2; nt++)
                    acc2[mt][nt] = __builtin_amdgcn_mfma_f32_16x16x32_bf16(af, bfr[nt][kc], acc2[mt][nt], 0, 0, 0);
            }
    }
    __syncthreads();

    float* xls = (float*)abuf;
    #pragma unroll
    for (int nt = 0; nt < 2; nt++){
        int col = colb + nt*16 + lr;
        float bv = b2[col];
        #pragma unroll
        for (int mt = 0; mt < 4; mt++)
            #pragma unroll
            for (int r = 0; r < 4; r++){
                int row = mt*16 + lq*4 + r;
                int node = tile0 + row;
                float hv = (node < NV) ? h[(size_t)node*NH + col] : 0.f;
                xls[row*132 + col] = hv + acc2[mt][nt][r] + bv;
            }
    }
    __syncthreads();

    {
        int r = tid >> 2, part = tid & 3;
        float s = 0.f, q = 0.f;
        #pragma unroll 8
        for (int i = 0; i < 32; i++){
            float x = xls[r*132 + part*32 + i];
            s += x; q += x*x;
        }
        ps[r][part] = s; pq[r][part] = q;
    }
    __syncthreads();
    if (tid < 64){
        float s = ps[tid][0] + ps[tid][1] + ps[tid][2] + ps[tid][3];
        float q = pq[tid][0] + pq[tid][1] + pq[tid][2] + pq[tid][3];
        float mu = s * (1.f/128.f);
        float var = q * (1.f/128.f) - mu*mu;
        mu_s[tid] = mu;
        rs_s[tid] = rsqrtf(var + 1e-5f);
    }
    __syncthreads();
    {
        int r = tid >> 2, part = tid & 3;
        int node = tile0 + r;
        if (node < NV){
            float mu = mu_s[r], rs = rs_s[r];
            #pragma unroll
            for (int c = 0; c < 8; c++){
                int d = part*32 + c*4;
                float4 o;
                o.x = g[d+0]*(xls[r*132 + d+0] - mu)*rs + bta[d+0];
                o.y = g[d+1]*(xls[r*132 + d+1] - mu)*rs + bta[d+1];
                o.z = g[d+2]*(xls[r*132 + d+2] - mu)*rs + bta[d+2];
                o.w = g[d+3]*(xls[r*132 + d+3] - mu)*rs + bta[d+3];
                *(float4*)(h + (size_t)node*NH + d) = o;
            }
        }
    }
}

// ---------------- output projection + MSE ----------------
__global__ __launch_bounds__(256) void k_out(const float* __restrict__ h,
                                             const float* __restrict__ opw, const float* __restrict__ opb,
                                             const float* __restrict__ pos0, const float* __restrict__ pos1,
                                             float* __restrict__ out)
{
    int v = blockIdx.x*256 + threadIdx.x;
    float sse = 0.f;
    if (v < NV){
        float v0 = opb[0], v1 = opb[1], v2 = opb[2];
        const float* hr = h + (size_t)v*NH;
        for (int k = 0; k < 128; k += 4){
            float4 hv = *(const float4*)(hr + k);
            v0 += hv.x*opw[(k+0)*3+0] + hv.y*opw[(k+1)*3+0] + hv.z*opw[(k+2)*3+0] + hv.w*opw[(k+3)*3+0];
            v1 += hv.x*opw[(k+0)*3+1] + hv.y*opw[(k+1)*3+1] + hv.z*opw[(k+2)*3+1] + hv.w*opw[(k+3)*3+1];
            v2 += hv.x*opw[(k+0)*3+2] + hv.y*opw[(k+1)*3+2] + hv.z*opw[(k+2)*3+2] + hv.w*opw[(k+3)*3+2];
        }
        float d0 = v0 - (pos1[v*3+0] - pos0[v*3+0]);
        float d1 = v1 - (pos1[v*3+1] - pos0[v*3+1]);
        float d2 = v2 - (pos1[v*3+2] - pos0[v*3+2]);
        sse = d0*d0 + d1*d1 + d2*d2;
    }
    for (int off = 32; off > 0; off >>= 1) sse += __shfl_down(sse, off, 64);
    __shared__ float red[4];
    if ((threadIdx.x & 63) == 0) red[threadIdx.x >> 6] = sse;
    __syncthreads();
    if (threadIdx.x == 0){
        float tot = red[0] + red[1] + red[2] + red[3];
        atomicAdd(out, tot * (1.0f/150000.0f));
    }
}

extern "C" void kernel_launch(void* const* d_in, const int* in_sizes, int n_in,
                              void* d_out, int out_size, void* d_ws, size_t ws_size,
                              hipStream_t stream)
{
    const float* pos0  = (const float*)d_in[0];
    const float* pos1  = (const float*)d_in[1];
    const float* z     = (const float*)d_in[2];
    const float* t     = (const float*)d_in[3];
    const int*   ei    = (const int*)d_in[4];
    const int*   batch = (const int*)d_in[5];
    const float* te_w1 = (const float*)d_in[6];
    const float* te_b1 = (const float*)d_in[7];
    const float* te_w2 = (const float*)d_in[8];
    const float* te_b2 = (const float*)d_in[9];
    const float* cp_w  = (const float*)d_in[10];
    const float* cp_b  = (const float*)d_in[11];
    const float* ew1   = (const float*)d_in[12];
    const float* eb1   = (const float*)d_in[13];
    const float* ew2   = (const float*)d_in[14];
    const float* eb2   = (const float*)d_in[15];
    const float* nw1   = (const float*)d_in[16];
    const float* nb1   = (const float*)d_in[17];
    const float* nw2   = (const float*)d_in[18];
    const float* nb2   = (const float*)d_in[19];
    const float* ln_g  = (const float*)d_in[20];
    const float* ln_b  = (const float*)d_in[21];
    const float* op_w  = (const float*)d_in[22];
    const float* op_b  = (const float*)d_in[23];

    float* ws     = (float*)d_ws;
    float* tconst = ws;                        // 128
    float* zcp    = ws + 128;                  // 1024
    float* xt     = ws + 1152;                 // 150016 (NV*3 padded)
    float* h      = ws + 151168;               // NV*NH fp32
    float* agg    = h + (size_t)NV*NH;         // NV*NH fp32
    int*   ibase  = (int*)(agg + (size_t)NV*NH);
    int*   rowptr  = ibase;                    // 50016
    int*   cursor  = ibase + 50016;            // 50016
    int*   csr_eid = ibase + 100032;           // NE
    int*   csr_dst = csr_eid + NE;             // NE
    unsigned short* pre_di = (unsigned short*)(csr_dst + NE);   // NV*NH bf16
    unsigned short* pre_sj = pre_di + (size_t)NV*NH;            // NV*NH bf16
    unsigned short* wpk    = pre_sj + (size_t)NV*NH;            // 4*6*16384 bf16
    int*   bsum   = (int*)(wpk + 4*6*16384);                    // 256 ints

    const int* srcrow = ei;        // edge_index[0] = src j
    const int* dstrow = ei + NE;   // edge_index[1] = dst i

    hipMemsetAsync(cursor, 0, (size_t)NV*4, stream);
    k_setup<<<1, 128, 0, stream>>>(z, t, te_w1, te_b1, te_w2, te_b2, cp_w, cp_b, tconst, zcp);
    k_init<<<(NV*NH)/256, 256, 0, stream>>>(batch, zcp, tconst, h);
    k_xt<<<(NV*3 + 255)/256, 256, 0, stream>>>(pos0, pos1, t, xt);
    k_hist<<<NE/256, 256, 0, stream>>>(dstrow, cursor);
    k_scan1<<<196, 256, 0, stream>>>(cursor, bsum);
    k_scan2<<<1, 256, 0, stream>>>(bsum);
    k_scan3<<<196, 256, 0, stream>>>(cursor, bsum, rowptr, cursor);
    k_scatter<<<NE/256, 256, 0, stream>>>(dstrow, cursor, csr_eid, csr_dst);
    k_pack_wpk<<<(4*6*16384)/256, 256, 0, stream>>>(ew1, ew2, nw1, nw2, wpk);

    for (int l = 0; l < NL; l++){
        const float* ew1l = ew1 + (size_t)l*259*128;
        const unsigned short* wpk_l = wpk + (size_t)l*6*16384;
        k_pre_mfma<<<(NV + 63)/64, 256, 0, stream>>>(h, xt, wpk_l,
                                                     ew1l + 256*128, eb1 + l*128,
                                                     pre_di, pre_sj);
        hipMemsetAsync(agg, 0, (size_t)NV*NH*4, stream);
        k_edge_mfma<<<NE/128, 256, 0, stream>>>(pre_di, pre_sj, csr_eid, csr_dst, srcrow, rowptr,
                                                wpk_l + 2*16384, eb2 + l*128, agg);
        k_node_mfma<<<(NV + 63)/64, 256, 0, stream>>>(h, agg, wpk_l + 3*16384,
                                                      nb1 + l*128, nb2 + l*128,
                                                      ln_g + l*128, ln_b + l*128);
    }

    hipMemsetAsync(d_out, 0, 4, stream);
    k_out<<<(NV + 255)/256, 256, 0, stream>>>(h, op_w, op_b, pos0, pos1, (float*)d_out);
}

// Round 8
// 942.008 us; speedup vs baseline: 6.2175x; 1.0875x over previous
//
#include <hip/hip_runtime.h>

#define NV 50000
#define NE 800000
#define NB 8
#define NH 128
#define NLAT 64
#define NTD 16
#define NL 4
#define SK 136   // LDS row stride (bf16 elems) for MFMA A tiles
#define MT2 132  // LDS stride (bf16 elems) for transposed m tile

typedef __attribute__((ext_vector_type(8))) short short8;
typedef __attribute__((ext_vector_type(4))) float f32x4;

__device__ __forceinline__ float silu_f(float x){
    float e = __expf(-x);
    return x * __builtin_amdgcn_rcpf(1.0f + e);
}

// HW packed f32->bf16 convert (RNE): lo = cvt(a), hi = cvt(b)
__device__ __forceinline__ unsigned cvtpk(float a, float b){
    unsigned r;
    asm("v_cvt_pk_bf16_f32 %0, %1, %2" : "=v"(r) : "v"(a), "v"(b));
    return r;
}
__device__ __forceinline__ unsigned short f2bf_fast(float x){
    return (unsigned short)cvtpk(x, x);
}
// bit-twiddle fallback used only in one-shot pack kernel
__device__ __forceinline__ unsigned short f2bf(float x){
    unsigned u = __float_as_uint(x);
    unsigned r = (u >> 16) & 1;
    u += 0x7fffu + r;
    return (unsigned short)(u >> 16);
}
__device__ __forceinline__ float bflo(unsigned u){ return __uint_as_float(u << 16); }
__device__ __forceinline__ float bfhi(unsigned u){ return __uint_as_float(u & 0xffff0000u); }

// ---------------- setup ----------------
__global__ void k_setup(const float* __restrict__ z, const float* __restrict__ t,
                        const float* __restrict__ te_w1, const float* __restrict__ te_b1,
                        const float* __restrict__ te_w2, const float* __restrict__ te_b2,
                        const float* __restrict__ cp_w, const float* __restrict__ cp_b,
                        float* __restrict__ tconst, float* __restrict__ zcp)
{
    __shared__ float hid[NTD];
    __shared__ float emb[NTD];
    int tid = threadIdx.x;
    float ts = t[0];
    if (tid < NTD) hid[tid] = silu_f(ts * te_w1[tid] + te_b1[tid]);
    __syncthreads();
    if (tid < NTD){
        float a = te_b2[tid];
        for (int j = 0; j < NTD; j++) a += hid[j] * te_w2[j*NTD + tid];
        emb[tid] = a;
    }
    __syncthreads();
    float tc = cp_b[tid];
    for (int j = 0; j < NTD; j++) tc += emb[j] * cp_w[(NLAT + j)*NH + tid];
    tconst[tid] = tc;
    for (int b = 0; b < NB; b++){
        float a = 0.f;
        for (int k = 0; k < NLAT; k++) a += z[b*NLAT + k] * cp_w[k*NH + tid];
        zcp[b*NH + tid] = a;
    }
}

__global__ void k_init(const int* __restrict__ batch, const float* __restrict__ zcp,
                       const float* __restrict__ tconst, float* __restrict__ h)
{
    int idx = blockIdx.x*256 + threadIdx.x;
    int v = idx >> 7, d = idx & 127;
    h[idx] = zcp[batch[v]*NH + d] + tconst[d];
}

__global__ void k_xt(const float* __restrict__ pos0, const float* __restrict__ pos1,
                     const float* __restrict__ t, float* __restrict__ xt)
{
    int idx = blockIdx.x*256 + threadIdx.x;
    if (idx < NV*3){
        float ts = t[0];
        xt[idx] = (1.f - ts)*pos0[idx] + ts*pos1[idx];
    }
}

// ---------------- CSR build ----------------
__global__ void k_hist(const int* __restrict__ dst, int* __restrict__ cnt)
{
    int e = blockIdx.x*256 + threadIdx.x;
    if (e < NE) atomicAdd(&cnt[dst[e]], 1);
}

__global__ void k_scan1(const int* __restrict__ deg, int* __restrict__ bsum)
{
    __shared__ int s[256];
    int tid = threadIdx.x;
    int idx = blockIdx.x*256 + tid;
    s[tid] = (idx < NV) ? deg[idx] : 0;
    __syncthreads();
    for (int off = 128; off > 0; off >>= 1){
        if (tid < off) s[tid] += s[tid + off];
        __syncthreads();
    }
    if (tid == 0) bsum[blockIdx.x] = s[0];
}

__global__ void k_scan2(int* __restrict__ bsum)
{
    __shared__ int s[256];
    int tid = threadIdx.x;
    int v = (tid < 196) ? bsum[tid] : 0;
    s[tid] = v;
    __syncthreads();
    for (int off = 1; off < 256; off <<= 1){
        int a = s[tid];
        int b = (tid >= off) ? s[tid - off] : 0;
        __syncthreads();
        s[tid] = a + b;
        __syncthreads();
    }
    if (tid < 196) bsum[tid] = (tid == 0) ? 0 : s[tid - 1];
}

__global__ void k_scan3(const int* deg, const int* __restrict__ bsum,
                        int* __restrict__ rowptr, int* cursor)
{
    __shared__ int s[256];
    int tid = threadIdx.x;
    int idx = blockIdx.x*256 + tid;
    int v = (idx < NV) ? deg[idx] : 0;
    s[tid] = v;
    __syncthreads();
    for (int off = 1; off < 256; off <<= 1){
        int a = s[tid];
        int b = (tid >= off) ? s[tid - off] : 0;
        __syncthreads();
        s[tid] = a + b;
        __syncthreads();
    }
    int excl = bsum[blockIdx.x] + ((tid == 0) ? 0 : s[tid - 1]);
    if (idx < NV){
        rowptr[idx] = excl;
        cursor[idx] = excl;
    }
    if (idx == NV - 1) rowptr[NV] = NE;
}

__global__ void k_scatter(const int* __restrict__ dst, int* __restrict__ cursor,
                          int* __restrict__ csr_eid, int* __restrict__ csr_dst)
{
    int e = blockIdx.x*256 + threadIdx.x;
    if (e < NE){
        int i = dst[e];
        int p = atomicAdd(&cursor[i], 1);
        csr_eid[p] = e;
        csr_dst[p] = i;
    }
}

// ---------------- pack weights -> bf16 [l][{eWd,eWs,eW2,nW1d,nW1a,nW2}][n][k] ----------------
__global__ void k_pack_wpk(const float* __restrict__ ew1, const float* __restrict__ ew2,
                           const float* __restrict__ nw1, const float* __restrict__ nw2,
                           unsigned short* __restrict__ wpk)
{
    int idx = blockIdx.x*256 + threadIdx.x;
    int lm = idx >> 14;
    int l = lm / 6, m = lm % 6;
    int r = idx & 16383;
    int n = r >> 7, k = r & 127;
    float v;
    if (m < 2)       v = ew1[l*33152 + (m*128 + k)*128 + n];
    else if (m == 2) v = ew2[l*16384 + k*128 + n];
    else if (m < 5)  v = nw1[l*32768 + ((m-3)*128 + k)*128 + n];
    else             v = nw2[l*16384 + k*128 + n];
    wpk[idx] = f2bf(v);
}

// ---------------- layer-0 pre-projection (MFMA, both branches, bf16 out) ----------------
__global__ __launch_bounds__(256) void k_pre_mfma(
    const float* __restrict__ h, const float* __restrict__ xt,
    const unsigned short* __restrict__ wpk_l,   // Wd at +0, Ws at +16384
    const float* __restrict__ w1c, const float* __restrict__ b1,
    unsigned short* __restrict__ pre_di, unsigned short* __restrict__ pre_sj)
{
    __shared__ __align__(16) unsigned short asd[64*SK];    // A tile; reused as d-out tile
    __shared__ __align__(16) unsigned short obuf[64*SK];   // s-out tile
    __shared__ float xts[64*4];
    int tid = threadIdx.x;
    int tile0 = blockIdx.x*64;

    {
        int r = tid >> 2, dq = tid & 3;
        int node = tile0 + r;
        bool valid = node < NV;
        const float4* hrow = (const float4*)(h + (size_t)node*NH + dq*32);
        #pragma unroll
        for (int c = 0; c < 4; c++){
            float4 v0 = valid ? hrow[c*2]     : make_float4(0.f,0.f,0.f,0.f);
            float4 v1 = valid ? hrow[c*2 + 1] : make_float4(0.f,0.f,0.f,0.f);
            uint4 o;
            o.x = cvtpk(v0.x, v0.y);
            o.y = cvtpk(v0.z, v0.w);
            o.z = cvtpk(v1.x, v1.y);
            o.w = cvtpk(v1.z, v1.w);
            *(uint4*)&asd[r*SK + dq*32 + c*8] = o;
        }
    }
    if (tid < 64){
        int node = tile0 + tid;
        bool valid = node < NV;
        xts[tid*4+0] = valid ? xt[node*3+0] : 0.f;
        xts[tid*4+1] = valid ? xt[node*3+1] : 0.f;
        xts[tid*4+2] = valid ? xt[node*3+2] : 0.f;
        xts[tid*4+3] = 0.f;
    }

    int w = tid >> 6, l = tid & 63;
    int lr = l & 15, lq = l >> 4;

    f32x4 accd[4][2], accs[4][2];
    #pragma unroll
    for (int mt = 0; mt < 4; mt++)
        #pragma unroll
        for (int nt = 0; nt < 2; nt++){
            accd[mt][nt] = (f32x4){0.f,0.f,0.f,0.f};
            accs[mt][nt] = (f32x4){0.f,0.f,0.f,0.f};
        }

    short8 bfr[2][4];
    #pragma unroll
    for (int nt = 0; nt < 2; nt++)
        #pragma unroll
        for (int kc = 0; kc < 4; kc++)
            bfr[nt][kc] = *(const short8*)(wpk_l + (w*32 + nt*16 + lr)*128 + kc*32 + lq*8);

    __syncthreads();

    #pragma unroll
    for (int kc = 0; kc < 4; kc++)
        #pragma unroll
        for (int mt = 0; mt < 4; mt++){
            short8 af = *(const short8*)&asd[(mt*16 + lr)*SK + kc*32 + lq*8];
            #pragma unroll
            for (int nt = 0; nt < 2; nt++)
                accd[mt][nt] = __builtin_amdgcn_mfma_f32_16x16x32_bf16(af, bfr[nt][kc], accd[mt][nt], 0, 0, 0);
        }

    #pragma unroll
    for (int nt = 0; nt < 2; nt++)
        #pragma unroll
        for (int kc = 0; kc < 4; kc++)
            bfr[nt][kc] = *(const short8*)(wpk_l + 16384 + (w*32 + nt*16 + lr)*128 + kc*32 + lq*8);

    #pragma unroll
    for (int kc = 0; kc < 4; kc++)
        #pragma unroll
        for (int mt = 0; mt < 4; mt++){
            short8 af = *(const short8*)&asd[(mt*16 + lr)*SK + kc*32 + lq*8];
            #pragma unroll
            for (int nt = 0; nt < 2; nt++)
                accs[mt][nt] = __builtin_amdgcn_mfma_f32_16x16x32_bf16(af, bfr[nt][kc], accs[mt][nt], 0, 0, 0);
        }
    __syncthreads();

    #pragma unroll
    for (int nt = 0; nt < 2; nt++){
        int col = w*32 + nt*16 + lr;
        float c0 = w1c[col], c1 = w1c[128 + col], c2 = w1c[256 + col];
        float bb = b1[col];
        #pragma unroll
        for (int mt = 0; mt < 4; mt++){
            #pragma unroll
            for (int r = 0; r < 4; r++){
                int row = mt*16 + lq*4 + r;
                float qv = xts[row*4+0]*c0 + xts[row*4+1]*c1 + xts[row*4+2]*c2;
                asd [row*SK + col] = f2bf_fast(accd[mt][nt][r] + qv + bb);
                obuf[row*SK + col] = f2bf_fast(accs[mt][nt][r] - qv);
            }
        }
    }
    __syncthreads();

    {
        int r = tid >> 2, dq = tid & 3;
        int node = tile0 + r;
        if (node < NV){
            #pragma unroll
            for (int c = 0; c < 4; c++){
                uint4 vd = *(const uint4*)&asd [r*SK + dq*32 + c*8];
                uint4 vs = *(const uint4*)&obuf[r*SK + dq*32 + c*8];
                *(uint4*)(pre_di + (size_t)node*NH + dq*32 + c*8) = vd;
                *(uint4*)(pre_sj + (size_t)node*NH + dq*32 + c*8) = vs;
            }
        }
    }
}

// ---------------- fused edge kernel: 128-edge tiles ----------------
__global__ __launch_bounds__(256) void k_edge_mfma(
    const unsigned short* __restrict__ pre_di, const unsigned short* __restrict__ pre_sj,
    const int* __restrict__ csr_eid, const int* __restrict__ csr_dst,
    const int* __restrict__ srcrow, const int* __restrict__ rowptr,
    const unsigned short* __restrict__ w2t,   // [n][k] bf16
    const float* __restrict__ b2,
    float* __restrict__ agg)
{
    __shared__ __align__(16) unsigned short hids[128*SK];
    __shared__ int nid[128];
    __shared__ int flagL, flagR;
    __shared__ unsigned long long brk0_s, brk1_s;
    int tid = threadIdx.x;

    int b = blockIdx.x;
    int mapped = (b < 6248) ? ((b & 7)*781 + (b >> 3)) : b;
    int p0 = mapped * 128;

    if (tid == 0){
        flagL = (rowptr[csr_dst[p0]] < p0) ? 1 : 0;
        flagR = (rowptr[csr_dst[p0 + 127] + 1] > p0 + 128) ? 1 : 0;
    }

    // hid phase
    #pragma unroll
    for (int sub = 0; sub < 2; sub++){
        int el = sub*64 + (tid >> 2), q = tid & 3;
        int p = p0 + el;
        int eid = csr_eid[p];
        int iN  = csr_dst[p];
        int jN  = srcrow[eid];
        if (q == 0) nid[el] = iN;
        const uint4* gd = (const uint4*)(pre_di + (size_t)iN*NH + q*32);
        const uint4* gs = (const uint4*)(pre_sj + (size_t)jN*NH + q*32);
        #pragma unroll
        for (int c = 0; c < 4; c++){
            uint4 a = gd[c], bb = gs[c];
            unsigned au[4] = {a.x, a.y, a.z, a.w};
            unsigned bu[4] = {bb.x, bb.y, bb.z, bb.w};
            unsigned ov[4];
            #pragma unroll
            for (int g = 0; g < 4; g++){
                float lo = silu_f(bflo(au[g]) + bflo(bu[g]));
                float hi = silu_f(bfhi(au[g]) + bfhi(bu[g]));
                ov[g] = cvtpk(lo, hi);
            }
            uint4 o; o.x = ov[0]; o.y = ov[1]; o.z = ov[2]; o.w = ov[3];
            *(uint4*)&hids[el*SK + q*32 + c*8] = o;
        }
    }

    int w = tid >> 6, l = tid & 63;
    int lr = l & 15, lq = l >> 4;
    short8 bfr[2][4];
    #pragma unroll
    for (int nt = 0; nt < 2; nt++)
        #pragma unroll
        for (int kc = 0; kc < 4; kc++)
            bfr[nt][kc] = *(const short8*)(w2t + (w*32 + nt*16 + lr)*128 + kc*32 + lq*8);

    __syncthreads();

    if (tid < 64){
        bool bb = (tid > 0) && (nid[tid] != nid[tid - 1]);
        unsigned long long mask = __ballot(bb);
        if (tid == 0) brk0_s = mask;
    } else if (tid < 128){
        int lane = tid - 64;
        bool bb = (nid[64 + lane] != nid[63 + lane]);
        unsigned long long mask = __ballot(bb);
        if (lane == 0) brk1_s = mask;
    }

    f32x4 acc[8][2];
    #pragma unroll
    for (int mt = 0; mt < 8; mt++)
        #pragma unroll
        for (int nt = 0; nt < 2; nt++) acc[mt][nt] = (f32x4){0.f,0.f,0.f,0.f};
    #pragma unroll
    for (int kc = 0; kc < 4; kc++){
        #pragma unroll
        for (int mt = 0; mt < 8; mt++){
            short8 af = *(const short8*)&hids[(mt*16 + lr)*SK + kc*32 + lq*8];
            #pragma unroll
            for (int nt = 0; nt < 2; nt++)
                acc[mt][nt] = __builtin_amdgcn_mfma_f32_16x16x32_bf16(af, bfr[nt][kc], acc[mt][nt], 0, 0, 0);
        }
    }
    __syncthreads();

    unsigned short* m_t = hids;
    #pragma unroll
    for (int nt = 0; nt < 2; nt++){
        int col = w*32 + nt*16 + lr;
        float bv = b2[col];
        #pragma unroll
        for (int mt = 0; mt < 8; mt++){
            float v0 = silu_f(acc[mt][nt][0] + bv);
            float v1 = silu_f(acc[mt][nt][1] + bv);
            float v2 = silu_f(acc[mt][nt][2] + bv);
            float v3 = silu_f(acc[mt][nt][3] + bv);
            uint2 pk;
            pk.x = cvtpk(v0, v1);
            pk.y = cvtpk(v2, v3);
            *(uint2*)&m_t[col*MT2 + mt*16 + lq*4] = pk;
        }
    }
    __syncthreads();

    {
        int half = tid >> 7, d = tid & 127;
        int r0 = half * 64;
        bool junc = !((brk1_s) & 1ull);
        unsigned long long m2 = half ? (brk1_s & ~1ull) : brk0_s;
        bool leftCont  = half ? junc : (flagL != 0);
        bool rightCont = half ? (flagR != 0) : junc;

        float run = 0.f;
        int curn = nid[r0];
        bool firstRun = true;
        const unsigned short* mrow = m_t + d*MT2;

        #pragma unroll
        for (int g = 0; g < 16; g++){
            int row = r0 + g*4;
            uint2 v = *(const uint2*)&mrow[row];
            float f0 = bflo(v.x), f1 = bfhi(v.x);
            float f2 = bflo(v.y), f3 = bfhi(v.y);
            unsigned gm = (unsigned)((m2 >> (g*4)) & 0xFull);
            if (gm == 0u){
                run += (f0 + f1) + (f2 + f3);
            } else {
                float fv[4] = {f0, f1, f2, f3};
                #pragma unroll
                for (int r = 0; r < 4; r++){
                    if (gm & (1u << r)){
                        bool at = firstRun && leftCont;
                        if (at) atomicAdd(&agg[(size_t)curn*NH + d], run);
                        else    agg[(size_t)curn*NH + d] = run;
                        firstRun = false;
                        run = 0.f;
                        curn = nid[row + r];
                    }
                    run += fv[r];
                }
            }
        }
        bool at = (firstRun && leftCont) || rightCont;
        if (at) atomicAdd(&agg[(size_t)curn*NH + d], run);
        else    agg[(size_t)curn*NH + d] = run;
    }
}

// ---------------- fused node kernel: LN(h + MLP([h|agg])) then next-layer pre-projection ----------------
__global__ __launch_bounds__(256) void k_node_fused(
    float* __restrict__ h, const float* __restrict__ agg,
    const unsigned short* __restrict__ wn,   // node weights: W1d, W1a, W2
    const float* __restrict__ b1, const float* __restrict__ b2,
    const float* __restrict__ g, const float* __restrict__ bta,
    const float* __restrict__ xt,
    const unsigned short* __restrict__ wpk_next,   // next-layer eWd at +0, eWs at +16384
    const float* __restrict__ w1c_next, const float* __restrict__ b1_next,
    unsigned short* __restrict__ pre_di, unsigned short* __restrict__ pre_sj,
    int do_pre)
{
    __shared__ __align__(16) unsigned short abuf[2*64*SK];
    __shared__ float ps[64][4], pq[64][4];
    __shared__ float mu_s[64], rs_s[64];
    __shared__ float xts[64*4];
    int tid = threadIdx.x;
    int tile0 = blockIdx.x*64;
    unsigned short* a1 = abuf;
    unsigned short* a2 = abuf + 64*SK;

    {
        int r = tid >> 2, dq = tid & 3;
        int node = tile0 + r;
        bool valid = node < NV;
        const float4* hrow = (const float4*)(h   + (size_t)node*NH + dq*32);
        const float4* arow = (const float4*)(agg + (size_t)node*NH + dq*32);
        #pragma unroll
        for (int c = 0; c < 4; c++){
            float4 v0 = valid ? hrow[c*2]     : make_float4(0.f,0.f,0.f,0.f);
            float4 v1 = valid ? hrow[c*2 + 1] : make_float4(0.f,0.f,0.f,0.f);
            float4 u0 = valid ? arow[c*2]     : make_float4(0.f,0.f,0.f,0.f);
            float4 u1 = valid ? arow[c*2 + 1] : make_float4(0.f,0.f,0.f,0.f);
            uint4 o;
            o.x = cvtpk(v0.x, v0.y); o.y = cvtpk(v0.z, v0.w);
            o.z = cvtpk(v1.x, v1.y); o.w = cvtpk(v1.z, v1.w);
            *(uint4*)&a1[r*SK + dq*32 + c*8] = o;
            uint4 p;
            p.x = cvtpk(u0.x, u0.y); p.y = cvtpk(u0.z, u0.w);
            p.z = cvtpk(u1.x, u1.y); p.w = cvtpk(u1.z, u1.w);
            *(uint4*)&a2[r*SK + dq*32 + c*8] = p;
        }
    }
    if (tid < 64){
        int node = tile0 + tid;
        bool valid = node < NV;
        xts[tid*4+0] = valid ? xt[node*3+0] : 0.f;
        xts[tid*4+1] = valid ? xt[node*3+1] : 0.f;
        xts[tid*4+2] = valid ? xt[node*3+2] : 0.f;
        xts[tid*4+3] = 0.f;
    }

    int w = tid >> 6, l = tid & 63;
    int lr = l & 15, lq = l >> 4;
    int colb = w*32;

    __syncthreads();

    f32x4 acc[4][2];
    #pragma unroll
    for (int mt = 0; mt < 4; mt++)
        #pragma unroll
        for (int nt = 0; nt < 2; nt++) acc[mt][nt] = (f32x4){0.f,0.f,0.f,0.f};

    {
        short8 bfr[2][4];
        #pragma unroll
        for (int nt = 0; nt < 2; nt++)
            #pragma unroll
            for (int kc = 0; kc < 4; kc++)
                bfr[nt][kc] = *(const short8*)(wn + (colb + nt*16 + lr)*128 + kc*32 + lq*8);
        #pragma unroll
        for (int kc = 0; kc < 4; kc++)
            #pragma unroll
            for (int mt = 0; mt < 4; mt++){
                short8 af = *(const short8*)&a1[(mt*16 + lr)*SK + kc*32 + lq*8];
                #pragma unroll
                for (int nt = 0; nt < 2; nt++)
                    acc[mt][nt] = __builtin_amdgcn_mfma_f32_16x16x32_bf16(af, bfr[nt][kc], acc[mt][nt], 0, 0, 0);
            }
    }
    {
        short8 bfr[2][4];
        #pragma unroll
        for (int nt = 0; nt < 2; nt++)
            #pragma unroll
            for (int kc = 0; kc < 4; kc++)
                bfr[nt][kc] = *(const short8*)(wn + 16384 + (colb + nt*16 + lr)*128 + kc*32 + lq*8);
        #pragma unroll
        for (int kc = 0; kc < 4; kc++)
            #pragma unroll
            for (int mt = 0; mt < 4; mt++){
                short8 af = *(const short8*)&a2[(mt*16 + lr)*SK + kc*32 + lq*8];
                #pragma unroll
                for (int nt = 0; nt < 2; nt++)
                    acc[mt][nt] = __builtin_amdgcn_mfma_f32_16x16x32_bf16(af, bfr[nt][kc], acc[mt][nt], 0, 0, 0);
            }
    }
    __syncthreads();

    // t1 = silu(acc + b1) -> a1
    #pragma unroll
    for (int nt = 0; nt < 2; nt++){
        int col = colb + nt*16 + lr;
        float bv = b1[col];
        #pragma unroll
        for (int mt = 0; mt < 4; mt++)
            #pragma unroll
            for (int r = 0; r < 4; r++){
                int row = mt*16 + lq*4 + r;
                a1[row*SK + col] = f2bf_fast(silu_f(acc[mt][nt][r] + bv));
            }
    }
    __syncthreads();

    f32x4 acc2[4][2];
    #pragma unroll
    for (int mt = 0; mt < 4; mt++)
        #pragma unroll
        for (int nt = 0; nt < 2; nt++) acc2[mt][nt] = (f32x4){0.f,0.f,0.f,0.f};
    {
        short8 bfr[2][4];
        #pragma unroll
        for (int nt = 0; nt < 2; nt++)
            #pragma unroll
            for (int kc = 0; kc < 4; kc++)
                bfr[nt][kc] = *(const short8*)(wn + 2*16384 + (colb + nt*16 + lr)*128 + kc*32 + lq*8);
        #pragma unroll
        for (int kc = 0; kc < 4; kc++)
            #pragma unroll
            for (int mt = 0; mt < 4; mt++){
                short8 af = *(const short8*)&a1[(mt*16 + lr)*SK + kc*32 + lq*8];
                #pragma unroll
                for (int nt = 0; nt < 2; nt++)
                    acc2[mt][nt] = __builtin_amdgcn_mfma_f32_16x16x32_bf16(af, bfr[nt][kc], acc2[mt][nt], 0, 0, 0);
            }
    }
    __syncthreads();

    // x = h + acc2 + b2 -> fp32 LDS (stride 132, overlays abuf)
    float* xls = (float*)abuf;
    #pragma unroll
    for (int nt = 0; nt < 2; nt++){
        int col = colb + nt*16 + lr;
        float bv = b2[col];
        #pragma unroll
        for (int mt = 0; mt < 4; mt++)
            #pragma unroll
            for (int r = 0; r < 4; r++){
                int row = mt*16 + lq*4 + r;
                int node = tile0 + row;
                float hv = (node < NV) ? h[(size_t)node*NH + col] : 0.f;
                xls[row*132 + col] = hv + acc2[mt][nt][r] + bv;
            }
    }
    __syncthreads();

    {
        int r = tid >> 2, part = tid & 3;
        float s = 0.f, q = 0.f;
        #pragma unroll 8
        for (int i = 0; i < 32; i++){
            float x = xls[r*132 + part*32 + i];
            s += x; q += x*x;
        }
        ps[r][part] = s; pq[r][part] = q;
    }
    __syncthreads();
    if (tid < 64){
        float s = ps[tid][0] + ps[tid][1] + ps[tid][2] + ps[tid][3];
        float q = pq[tid][0] + pq[tid][1] + pq[tid][2] + pq[tid][3];
        float mu = s * (1.f/128.f);
        float var = q * (1.f/128.f) - mu*mu;
        mu_s[tid] = mu;
        rs_s[tid] = rsqrtf(var + 1e-5f);
    }
    __syncthreads();

    // LN output: write h global + keep in regs
    float ovals[32];
    {
        int r = tid >> 2, part = tid & 3;
        int node = tile0 + r;
        float mu = mu_s[r], rs = rs_s[r];
        #pragma unroll
        for (int c = 0; c < 8; c++){
            int d = part*32 + c*4;
            float4 o;
            o.x = g[d+0]*(xls[r*132 + d+0] - mu)*rs + bta[d+0];
            o.y = g[d+1]*(xls[r*132 + d+1] - mu)*rs + bta[d+1];
            o.z = g[d+2]*(xls[r*132 + d+2] - mu)*rs + bta[d+2];
            o.w = g[d+3]*(xls[r*132 + d+3] - mu)*rs + bta[d+3];
            ovals[c*4+0] = o.x; ovals[c*4+1] = o.y;
            ovals[c*4+2] = o.z; ovals[c*4+3] = o.w;
            if (node < NV) *(float4*)(h + (size_t)node*NH + d) = o;
        }
    }

    if (!do_pre) return;

    __syncthreads();   // all xls reads done -> abuf reusable
    // pack LN result -> a1 (bf16 A-tile)
    {
        int r = tid >> 2, part = tid & 3;
        #pragma unroll
        for (int c = 0; c < 4; c++){
            uint4 o;
            o.x = cvtpk(ovals[c*8+0], ovals[c*8+1]);
            o.y = cvtpk(ovals[c*8+2], ovals[c*8+3]);
            o.z = cvtpk(ovals[c*8+4], ovals[c*8+5]);
            o.w = cvtpk(ovals[c*8+6], ovals[c*8+7]);
            *(uint4*)&a1[r*SK + part*32 + c*8] = o;
        }
    }
    __syncthreads();

    // ---- next-layer pre: branch d ----
    f32x4 accp[4][2];
    {
        short8 bfr[2][4];
        #pragma unroll
        for (int nt = 0; nt < 2; nt++)
            #pragma unroll
            for (int kc = 0; kc < 4; kc++)
                bfr[nt][kc] = *(const short8*)(wpk_next + (colb + nt*16 + lr)*128 + kc*32 + lq*8);
        #pragma unroll
        for (int mt = 0; mt < 4; mt++)
            #pragma unroll
            for (int nt = 0; nt < 2; nt++) accp[mt][nt] = (f32x4){0.f,0.f,0.f,0.f};
        #pragma unroll
        for (int kc = 0; kc < 4; kc++)
            #pragma unroll
            for (int mt = 0; mt < 4; mt++){
                short8 af = *(const short8*)&a1[(mt*16 + lr)*SK + kc*32 + lq*8];
                #pragma unroll
                for (int nt = 0; nt < 2; nt++)
                    accp[mt][nt] = __builtin_amdgcn_mfma_f32_16x16x32_bf16(af, bfr[nt][kc], accp[mt][nt], 0, 0, 0);
            }
    }
    #pragma unroll
    for (int nt = 0; nt < 2; nt++){
        int col = colb + nt*16 + lr;
        float c0 = w1c_next[col], c1 = w1c_next[128 + col], c2 = w1c_next[256 + col];
        float bb = b1_next[col];
        #pragma unroll
        for (int mt = 0; mt < 4; mt++)
            #pragma unroll
            for (int r = 0; r < 4; r++){
                int row = mt*16 + lq*4 + r;
                float qv = xts[row*4+0]*c0 + xts[row*4+1]*c1 + xts[row*4+2]*c2;
                a2[row*SK + col] = f2bf_fast(accp[mt][nt][r] + qv + bb);
            }
    }
    __syncthreads();
    {
        int r = tid >> 2, dq = tid & 3;
        int node = tile0 + r;
        if (node < NV){
            #pragma unroll
            for (int c = 0; c < 4; c++){
                uint4 vv = *(const uint4*)&a2[r*SK + dq*32 + c*8];
                *(uint4*)(pre_di + (size_t)node*NH + dq*32 + c*8) = vv;
            }
        }
    }
    __syncthreads();

    // ---- next-layer pre: branch s ----
    {
        short8 bfr[2][4];
        #pragma unroll
        for (int nt = 0; nt < 2; nt++)
            #pragma unroll
            for (int kc = 0; kc < 4; kc++)
                bfr[nt][kc] = *(const short8*)(wpk_next + 16384 + (colb + nt*16 + lr)*128 + kc*32 + lq*8);
        #pragma unroll
        for (int mt = 0; mt < 4; mt++)
            #pragma unroll
            for (int nt = 0; nt < 2; nt++) accp[mt][nt] = (f32x4){0.f,0.f,0.f,0.f};
        #pragma unroll
        for (int kc = 0; kc < 4; kc++)
            #pragma unroll
            for (int mt = 0; mt < 4; mt++){
                short8 af = *(const short8*)&a1[(mt*16 + lr)*SK + kc*32 + lq*8];
                #pragma unroll
                for (int nt = 0; nt < 2; nt++)
                    accp[mt][nt] = __builtin_amdgcn_mfma_f32_16x16x32_bf16(af, bfr[nt][kc], accp[mt][nt], 0, 0, 0);
            }
    }
    #pragma unroll
    for (int nt = 0; nt < 2; nt++){
        int col = colb + nt*16 + lr;
        float c0 = w1c_next[col], c1 = w1c_next[128 + col], c2 = w1c_next[256 + col];
        #pragma unroll
        for (int mt = 0; mt < 4; mt++)
            #pragma unroll
            for (int r = 0; r < 4; r++){
                int row = mt*16 + lq*4 + r;
                float qv = xts[row*4+0]*c0 + xts[row*4+1]*c1 + xts[row*4+2]*c2;
                a2[row*SK + col] = f2bf_fast(accp[mt][nt][r] - qv);
            }
    }
    __syncthreads();
    {
        int r = tid >> 2, dq = tid & 3;
        int node = tile0 + r;
        if (node < NV){
            #pragma unroll
            for (int c = 0; c < 4; c++){
                uint4 vv = *(const uint4*)&a2[r*SK + dq*32 + c*8];
                *(uint4*)(pre_sj + (size_t)node*NH + dq*32 + c*8) = vv;
            }
        }
    }
}

// ---------------- output projection + MSE ----------------
__global__ __launch_bounds__(256) void k_out(const float* __restrict__ h,
                                             const float* __restrict__ opw, const float* __restrict__ opb,
                                             const float* __restrict__ pos0, const float* __restrict__ pos1,
                                             float* __restrict__ out)
{
    int v = blockIdx.x*256 + threadIdx.x;
    float sse = 0.f;
    if (v < NV){
        float v0 = opb[0], v1 = opb[1], v2 = opb[2];
        const float* hr = h + (size_t)v*NH;
        for (int k = 0; k < 128; k += 4){
            float4 hv = *(const float4*)(hr + k);
            v0 += hv.x*opw[(k+0)*3+0] + hv.y*opw[(k+1)*3+0] + hv.z*opw[(k+2)*3+0] + hv.w*opw[(k+3)*3+0];
            v1 += hv.x*opw[(k+0)*3+1] + hv.y*opw[(k+1)*3+1] + hv.z*opw[(k+2)*3+1] + hv.w*opw[(k+3)*3+1];
            v2 += hv.x*opw[(k+0)*3+2] + hv.y*opw[(k+1)*3+2] + hv.z*opw[(k+2)*3+2] + hv.w*opw[(k+3)*3+2];
        }
        float d0 = v0 - (pos1[v*3+0] - pos0[v*3+0]);
        float d1 = v1 - (pos1[v*3+1] - pos0[v*3+1]);
        float d2 = v2 - (pos1[v*3+2] - pos0[v*3+2]);
        sse = d0*d0 + d1*d1 + d2*d2;
    }
    for (int off = 32; off > 0; off >>= 1) sse += __shfl_down(sse, off, 64);
    __shared__ float red[4];
    if ((threadIdx.x & 63) == 0) red[threadIdx.x >> 6] = sse;
    __syncthreads();
    if (threadIdx.x == 0){
        float tot = red[0] + red[1] + red[2] + red[3];
        atomicAdd(out, tot * (1.0f/150000.0f));
    }
}

extern "C" void kernel_launch(void* const* d_in, const int* in_sizes, int n_in,
                              void* d_out, int out_size, void* d_ws, size_t ws_size,
                              hipStream_t stream)
{
    const float* pos0  = (const float*)d_in[0];
    const float* pos1  = (const float*)d_in[1];
    const float* z     = (const float*)d_in[2];
    const float* t     = (const float*)d_in[3];
    const int*   ei    = (const int*)d_in[4];
    const int*   batch = (const int*)d_in[5];
    const float* te_w1 = (const float*)d_in[6];
    const float* te_b1 = (const float*)d_in[7];
    const float* te_w2 = (const float*)d_in[8];
    const float* te_b2 = (const float*)d_in[9];
    const float* cp_w  = (const float*)d_in[10];
    const float* cp_b  = (const float*)d_in[11];
    const float* ew1   = (const float*)d_in[12];
    const float* eb1   = (const float*)d_in[13];
    const float* ew2   = (const float*)d_in[14];
    const float* eb2   = (const float*)d_in[15];
    const float* nw1   = (const float*)d_in[16];
    const float* nb1   = (const float*)d_in[17];
    const float* nw2   = (const float*)d_in[18];
    const float* nb2   = (const float*)d_in[19];
    const float* ln_g  = (const float*)d_in[20];
    const float* ln_b  = (const float*)d_in[21];
    const float* op_w  = (const float*)d_in[22];
    const float* op_b  = (const float*)d_in[23];

    float* ws     = (float*)d_ws;
    float* tconst = ws;                        // 128
    float* zcp    = ws + 128;                  // 1024
    float* xt     = ws + 1152;                 // 150016 (NV*3 padded)
    float* h      = ws + 151168;               // NV*NH fp32
    float* agg    = h + (size_t)NV*NH;         // NV*NH fp32
    int*   ibase  = (int*)(agg + (size_t)NV*NH);
    int*   rowptr  = ibase;                    // 50016
    int*   cursor  = ibase + 50016;            // 50016
    int*   csr_eid = ibase + 100032;           // NE
    int*   csr_dst = csr_eid + NE;             // NE
    unsigned short* pre_di = (unsigned short*)(csr_dst + NE);   // NV*NH bf16
    unsigned short* pre_sj = pre_di + (size_t)NV*NH;            // NV*NH bf16
    unsigned short* wpk    = pre_sj + (size_t)NV*NH;            // 4*6*16384 bf16
    int*   bsum   = (int*)(wpk + 4*6*16384);                    // 256 ints

    const int* srcrow = ei;        // edge_index[0] = src j
    const int* dstrow = ei + NE;   // edge_index[1] = dst i

    hipMemsetAsync(cursor, 0, (size_t)NV*4, stream);
    k_setup<<<1, 128, 0, stream>>>(z, t, te_w1, te_b1, te_w2, te_b2, cp_w, cp_b, tconst, zcp);
    k_init<<<(NV*NH)/256, 256, 0, stream>>>(batch, zcp, tconst, h);
    k_xt<<<(NV*3 + 255)/256, 256, 0, stream>>>(pos0, pos1, t, xt);
    k_hist<<<NE/256, 256, 0, stream>>>(dstrow, cursor);
    k_scan1<<<196, 256, 0, stream>>>(cursor, bsum);
    k_scan2<<<1, 256, 0, stream>>>(bsum);
    k_scan3<<<196, 256, 0, stream>>>(cursor, bsum, rowptr, cursor);
    k_scatter<<<NE/256, 256, 0, stream>>>(dstrow, cursor, csr_eid, csr_dst);
    k_pack_wpk<<<(4*6*16384)/256, 256, 0, stream>>>(ew1, ew2, nw1, nw2, wpk);

    for (int l = 0; l < NL; l++){
        const unsigned short* wpk_l = wpk + (size_t)l*6*16384;
        if (l == 0){
            const float* ew1l = ew1;
            k_pre_mfma<<<(NV + 63)/64, 256, 0, stream>>>(h, xt, wpk_l,
                                                         ew1l + 256*128, eb1,
                                                         pre_di, pre_sj);
        }
        hipMemsetAsync(agg, 0, (size_t)NV*NH*4, stream);
        k_edge_mfma<<<NE/128, 256, 0, stream>>>(pre_di, pre_sj, csr_eid, csr_dst, srcrow, rowptr,
                                                wpk_l + 2*16384, eb2 + l*128, agg);
        int ln = (l + 1) % NL;
        const unsigned short* wpk_n = wpk + (size_t)ln*6*16384;
        const float* ew1n = ew1 + (size_t)ln*259*128;
        k_node_fused<<<(NV + 63)/64, 256, 0, stream>>>(h, agg, wpk_l + 3*16384,
                                                       nb1 + l*128, nb2 + l*128,
                                                       ln_g + l*128, ln_b + l*128,
                                                       xt, wpk_n, ew1n + 256*128, eb1 + ln*128,
                                                       pre_di, pre_sj, (l < NL-1) ? 1 : 0);
    }

    hipMemsetAsync(d_out, 0, 4, stream);
    k_out<<<(NV + 255)/256, 256, 0, stream>>>(h, op_w, op_b, pos0, pos1, (float*)d_out);
}